// Round 2
// baseline (12196.719 us; speedup 1.0000x reference)
//
#include <hip/hip_runtime.h>
#include <hip/hip_bf16.h>
#include <cstdint>

#define B_   4
#define NTOK 6264
#define NPAD 6400
#define D_   512
#define NH   8
#define NLM  256
#define N0   6170
#define PADF (NPAD - NTOK)   // 136

// ---------------------------------------------------------------- GEMM ----
struct GP {
  const void* A; const void* Bm; void* C; const float* bias;
  int M, N, K, lda, ldb, ldc;
  long long aSO, aSI; int aIn, abf;
  long long bSO, bSI; int bIn, bbf;
  long long cSO, cSI; int cIn, cbf;
  float alpha, beta; int relu, ksp, klen;
};

__device__ __forceinline__ float gload(const void* p, int bf, long long i){
  return bf ? __bfloat162float(((const __hip_bfloat16*)p)[i]) : ((const float*)p)[i];
}

__device__ __forceinline__ void atomicMaxF(float* a, float v){
  atomicMax((int*)a, __float_as_int(v));   // values strictly positive
}

// C = beta*(A@B) [+ alpha*I] [+bias] [relu].  A: MxK rm, B: KxN rm.
__global__ __launch_bounds__(256) void gemm_nn(GP p){
  int zz = blockIdx.z;
  int z = zz / p.ksp, ks = zz % p.ksp;
  int k0 = ks * p.klen;
  int k1 = (k0 + p.klen < p.K) ? (k0 + p.klen) : p.K;
  long long aOff = (long long)(z / p.aIn) * p.aSO + (long long)(z % p.aIn) * p.aSI;
  long long bOff = (long long)(z / p.bIn) * p.bSO + (long long)(z % p.bIn) * p.bSI;
  long long cOff = (long long)(z / p.cIn) * p.cSO + (long long)(z % p.cIn) * p.cSI;
  int rowBase = blockIdx.y * 64, colBase = blockIdx.x * 64;
  int t = threadIdx.x, tr = t >> 4, tc = t & 15;
  __shared__ __align__(16) float As[16][68];
  __shared__ __align__(16) float Bs[16][68];
  float acc[4][4] = {};
  for (int kb = k0; kb < k1; kb += 16){
    #pragma unroll
    for (int q = 0; q < 4; q++){
      int flat = t + 256*q;
      int kk = flat & 15, r = flat >> 4;
      int gr = rowBase + r;
      As[kk][r] = (gr < p.M) ? gload(p.A, p.abf, aOff + (long long)gr * p.lda + kb + kk) : 0.f;
    }
    #pragma unroll
    for (int q = 0; q < 4; q++){
      int flat = t + 256*q;
      int cc = flat & 63, kk = flat >> 6;
      int gc = colBase + cc;
      Bs[kk][cc] = (gc < p.N) ? gload(p.Bm, p.bbf, bOff + (long long)(kb + kk) * p.ldb + gc) : 0.f;
    }
    __syncthreads();
    #pragma unroll
    for (int kk = 0; kk < 16; kk++){
      float4 av = *reinterpret_cast<const float4*>(&As[kk][tr*4]);
      float4 bv = *reinterpret_cast<const float4*>(&Bs[kk][tc*4]);
      float a4[4] = {av.x, av.y, av.z, av.w};
      float b4[4] = {bv.x, bv.y, bv.z, bv.w};
      #pragma unroll
      for (int i = 0; i < 4; i++)
        #pragma unroll
        for (int j = 0; j < 4; j++)
          acc[i][j] += a4[i] * b4[j];
    }
    __syncthreads();
  }
  #pragma unroll
  for (int i = 0; i < 4; i++){
    int r = rowBase + tr*4 + i;
    if (r >= p.M) continue;
    #pragma unroll
    for (int j = 0; j < 4; j++){
      int c = colBase + tc*4 + j;
      if (c >= p.N) continue;
      float v = p.beta * acc[i][j];
      long long ci = cOff + (long long)r * p.ldc + c;
      if (p.ksp > 1){
        atomicAdd(&((float*)p.C)[ci], v);
      } else {
        if (p.alpha != 0.f && r == c) v += p.alpha;
        if (p.bias) v += p.bias[c];
        if (p.relu) v = fmaxf(v, 0.f);
        if (p.cbf) ((__hip_bfloat16*)p.C)[ci] = __float2bfloat16(v);
        else       ((float*)p.C)[ci] = v;
      }
    }
  }
}

// C = beta*(A@B^T).  A: MxK rm, B: NxK rm.
__global__ __launch_bounds__(256) void gemm_nt(GP p){
  int z = blockIdx.z;
  long long aOff = (long long)(z / p.aIn) * p.aSO + (long long)(z % p.aIn) * p.aSI;
  long long bOff = (long long)(z / p.bIn) * p.bSO + (long long)(z % p.bIn) * p.bSI;
  long long cOff = (long long)(z / p.cIn) * p.cSO + (long long)(z % p.cIn) * p.cSI;
  int rowBase = blockIdx.y * 64, colBase = blockIdx.x * 64;
  int t = threadIdx.x, tr = t >> 4, tc = t & 15;
  __shared__ __align__(16) float As[16][68];
  __shared__ __align__(16) float Bs[16][68];
  float acc[4][4] = {};
  for (int kb = 0; kb < p.K; kb += 16){
    #pragma unroll
    for (int q = 0; q < 4; q++){
      int flat = t + 256*q;
      int kk = flat & 15, r = flat >> 4;
      int gr = rowBase + r;
      As[kk][r] = (gr < p.M) ? gload(p.A, p.abf, aOff + (long long)gr * p.lda + kb + kk) : 0.f;
    }
    #pragma unroll
    for (int q = 0; q < 4; q++){
      int flat = t + 256*q;
      int kk = flat & 15, j = flat >> 4;
      int gc = colBase + j;
      Bs[kk][j] = (gc < p.N) ? gload(p.Bm, p.bbf, bOff + (long long)gc * p.ldb + kb + kk) : 0.f;
    }
    __syncthreads();
    #pragma unroll
    for (int kk = 0; kk < 16; kk++){
      float4 av = *reinterpret_cast<const float4*>(&As[kk][tr*4]);
      float4 bv = *reinterpret_cast<const float4*>(&Bs[kk][tc*4]);
      float a4[4] = {av.x, av.y, av.z, av.w};
      float b4[4] = {bv.x, bv.y, bv.z, bv.w};
      #pragma unroll
      for (int i = 0; i < 4; i++)
        #pragma unroll
        for (int j = 0; j < 4; j++)
          acc[i][j] += a4[i] * b4[j];
    }
    __syncthreads();
  }
  #pragma unroll
  for (int i = 0; i < 4; i++){
    int r = rowBase + tr*4 + i;
    if (r >= p.M) continue;
    #pragma unroll
    for (int j = 0; j < 4; j++){
      int c = colBase + tc*4 + j;
      if (c >= p.N) continue;
      ((float*)p.C)[cOff + (long long)r * p.ldc + c] = p.beta * acc[i][j];
    }
  }
}

// ------------------------------------------------------------ softmax ----
template<int LEN>
__global__ __launch_bounds__(256) void softmax_rows(float* S){
  constexpr int VPT = LEN / 256;
  long long row = blockIdx.x;
  float* p = S + row * LEN;
  int t = threadIdx.x;
  float v[VPT];
  float m = -1e30f;
  #pragma unroll
  for (int q = 0; q < VPT; q++){ v[q] = p[t + 256*q]; m = fmaxf(m, v[q]); }
  __shared__ float red[256];
  red[t] = m; __syncthreads();
  for (int s = 128; s; s >>= 1){ if (t < s) red[t] = fmaxf(red[t], red[t+s]); __syncthreads(); }
  m = red[0]; __syncthreads();
  float sum = 0.f;
  #pragma unroll
  for (int q = 0; q < VPT; q++){ v[q] = __expf(v[q] - m); sum += v[q]; }
  red[t] = sum; __syncthreads();
  for (int s = 128; s; s >>= 1){ if (t < s) red[t] += red[t+s]; __syncthreads(); }
  float inv = 1.f / red[0];
  #pragma unroll
  for (int q = 0; q < VPT; q++) p[t + 256*q] = v[q] * inv;
}

// --------------------------------------------------------- LN kernels ----
__global__ __launch_bounds__(256) void ln_pad(const float* H, float* X,
                                              const float* g, const float* bb){
  int p = blockIdx.x, b = blockIdx.y, t = threadIdx.x;
  float* xo = X + ((long long)b * NPAD + p) * D_;
  if (p < PADF){ xo[t] = 0.f; xo[t + 256] = 0.f; return; }
  const float* hi = H + ((long long)b * NTOK + (p - PADF)) * D_;
  float x0 = hi[t], x1 = hi[t + 256];
  __shared__ float r1[256], r2[256];
  r1[t] = x0 + x1; r2[t] = x0*x0 + x1*x1;
  __syncthreads();
  for (int s = 128; s; s >>= 1){ if (t < s){ r1[t] += r1[t+s]; r2[t] += r2[t+s]; } __syncthreads(); }
  float mu = r1[0] * (1.f / D_);
  float var = r2[0] * (1.f / D_) - mu*mu;
  float rs = rsqrtf(var + 1e-5f);
  xo[t]       = (x0 - mu) * rs * g[t]       + bb[t];
  xo[t + 256] = (x1 - mu) * rs * g[t + 256] + bb[t + 256];
}

__global__ __launch_bounds__(256) void final_ln(const float* H, const float* g,
                                                const float* bb, float* out){
  int b = blockIdx.x, t = threadIdx.x;
  const float* hi = H + (long long)b * NTOK * D_;   // token 0 (cls)
  float x0 = hi[t], x1 = hi[t + 256];
  __shared__ float r1[256], r2[256];
  r1[t] = x0 + x1; r2[t] = x0*x0 + x1*x1;
  __syncthreads();
  for (int s = 128; s; s >>= 1){ if (t < s){ r1[t] += r1[t+s]; r2[t] += r2[t+s]; } __syncthreads(); }
  float mu = r1[0] * (1.f / D_);
  float var = r2[0] * (1.f / D_) - mu*mu;
  float rs = rsqrtf(var + 1e-5f);
  out[b*D_ + t]       = (x0 - mu) * rs * g[t]       + bb[t];
  out[b*D_ + t + 256] = (x1 - mu) * rs * g[t + 256] + bb[t + 256];
}

// -------------------------------------------------------- misc kernels ----
__global__ __launch_bounds__(256) void build_h(const float* h0, const float* cls, float* H){
  int tpos = blockIdx.x, b = blockIdx.y, t = threadIdx.x;
  float* dst = H + ((long long)b * NTOK + tpos) * D_;
  if (tpos == 0){ dst[t] = cls[t]; dst[t + 256] = cls[t + 256]; return; }
  int i = tpos - 1, src;
  if (i < 10)        src = i;
  else if (i < 179){ int j = i - 10;  src = 10  + (j < 160  ? j : j - 160);  }
  else             { int j = i - 179; src = 170 + (j < 6000 ? j : j - 6000); }
  const float* s = h0 + ((long long)b * N0 + src) * D_;
  dst[t] = s[t]; dst[t + 256] = s[t + 256];
}

// landmark means (q scaled by 1/8); QKV is bf16
__global__ __launch_bounds__(64) void landmarks(const __hip_bfloat16* QKV, float* QL, float* KL){
  int j = blockIdx.x, z = blockIdx.y, d = threadIdx.x;
  int b = z >> 3, h = z & 7;
  const __hip_bfloat16* base = QKV + ((long long)b * NPAD + j*25) * 1536 + h*64 + d;
  float q = 0.f, k = 0.f;
  #pragma unroll 1
  for (int i = 0; i < 25; i++){
    q += __bfloat162float(base[(long long)i*1536]);
    k += __bfloat162float(base[(long long)i*1536 + 512]);
  }
  QL[((long long)z * NLM + j) * 64 + d] = q * (1.f/25.f) * 0.125f;
  KL[((long long)z * NLM + j) * 64 + d] = k * (1.f/25.f);
}

__global__ void init_sc(float* sc){ sc[0] = 0.f; sc[1] = 0.f; }

__global__ __launch_bounds__(256) void fillz(float* p, int n){
  int i = blockIdx.x*256 + threadIdx.x; if (i < n) p[i] = 0.f;
}

__global__ __launch_bounds__(256) void colsum_max(const float* A2, float* sc){
  int z = blockIdx.x, t = threadIdx.x;
  const float* a = A2 + (long long)z * 65536;
  float s = 0.f;
  for (int i = 0; i < 256; i++) s += fabsf(a[i*256 + t]);
  __shared__ float red[256];
  red[t] = s; __syncthreads();
  for (int st = 128; st; st >>= 1){ if (t < st) red[t] = fmaxf(red[t], red[t+st]); __syncthreads(); }
  if (t == 0) atomicMaxF(sc + 0, red[0]);
}

__global__ __launch_bounds__(256) void rowsum_max(const float* A2, float* sc){
  int z = blockIdx.x, t = threadIdx.x, w = t >> 6, l = t & 63;
  const float* a = A2 + (long long)z * 65536;
  float mx = 0.f;
  for (int i = w*64; i < (w+1)*64; i++){
    float s = fabsf(a[i*256 + l]) + fabsf(a[i*256 + l + 64])
            + fabsf(a[i*256 + l + 128]) + fabsf(a[i*256 + l + 192]);
    for (int m = 32; m; m >>= 1) s += __shfl_xor(s, m);
    mx = fmaxf(mx, s);
  }
  __shared__ float red[4];
  if (l == 0) red[w] = mx;
  __syncthreads();
  if (t == 0){
    float m2 = fmaxf(fmaxf(red[0], red[1]), fmaxf(red[2], red[3]));
    atomicMaxF(sc + 1, m2);
  }
}

__global__ __launch_bounds__(256) void zinit(const float* A2, float* Z, const float* sc){
  int j = blockIdx.x, z = blockIdx.y, i = threadIdx.x;
  float inv = 1.f / (sc[0] * sc[1]);
  Z[(long long)z*65536 + j*256 + i] = A2[(long long)z*65536 + i*256 + j] * inv;
}

__global__ __launch_bounds__(256) void diag7(const float* AZ, float* W1){
  int r = blockIdx.x, z = blockIdx.y, j = threadIdx.x;
  float v = -AZ[(long long)z*65536 + r*256 + j];
  if (r == j) v += 7.f;
  W1[(long long)z*65536 + r*256 + j] = v;
}

// OUT1 += depthwise conv of V over sequence dim (kernel 33, pad 16); V bf16
__global__ __launch_bounds__(512) void dwconv_add(const __hip_bfloat16* QKV, const float* rw, float* OUT1){
  int n = blockIdx.x, b = blockIdx.y, t = threadIdx.x;
  int h = t >> 6;
  float acc = 0.f;
  #pragma unroll 1
  for (int k = 0; k < 33; k++){
    int nn = n + k - 16;
    if (nn >= 0 && nn < NPAD)
      acc += rw[h*33 + k] * __bfloat162float(QKV[((long long)b * NPAD + nn) * 1536 + 1024 + t]);
  }
  OUT1[((long long)b * NPAD + n) * D_ + t] += acc;
}

__global__ __launch_bounds__(512) void resid_add(float* H, const float* O2, const float* ob){
  int i = blockIdx.x, b = blockIdx.y, t = threadIdx.x;
  H[((long long)b * NTOK + i) * D_ + t] +=
      O2[((long long)b * NPAD + i + PADF) * D_ + t] + ob[t];
}

__global__ __launch_bounds__(256) void ppeg_k(const float* H, float* P,
    const float* w7, const float* b7, const float* w5, const float* b5,
    const float* w3, const float* b3, int base, int W){
  int pos = blockIdx.x, b = blockIdx.y, t = threadIdx.x;
  int y = pos / W, x = pos - y*W;
  for (int cc = 0; cc < 2; cc++){
    int c = t + 256*cc;
    const float* hb = H + ((long long)b * NTOK + base) * D_ + c;
    float acc = hb[(long long)pos * D_] + b7[c] + b5[c] + b3[c];
    const float* k7 = w7 + c*49;
    for (int ky = 0; ky < 7; ky++){
      int yy = y + ky - 3; if (yy < 0 || yy >= W) continue;
      for (int kx = 0; kx < 7; kx++){
        int xx = x + kx - 3; if (xx < 0 || xx >= W) continue;
        acc += k7[ky*7 + kx] * hb[(long long)(yy*W + xx) * D_];
      }
    }
    const float* k5 = w5 + c*25;
    for (int ky = 0; ky < 5; ky++){
      int yy = y + ky - 2; if (yy < 0 || yy >= W) continue;
      for (int kx = 0; kx < 5; kx++){
        int xx = x + kx - 2; if (xx < 0 || xx >= W) continue;
        acc += k5[ky*5 + kx] * hb[(long long)(yy*W + xx) * D_];
      }
    }
    const float* k3 = w3 + c*9;
    for (int ky = 0; ky < 3; ky++){
      int yy = y + ky - 1; if (yy < 0 || yy >= W) continue;
      for (int kx = 0; kx < 3; kx++){
        int xx = x + kx - 1; if (xx < 0 || xx >= W) continue;
        acc += k3[ky*3 + kx] * hb[(long long)(yy*W + xx) * D_];
      }
    }
    P[((long long)b * W * W + pos) * D_ + c] = acc;
  }
}

__global__ __launch_bounds__(512) void ppeg_copy(float* H, const float* P, int base, int W){
  int pos = blockIdx.x, b = blockIdx.y, t = threadIdx.x;
  H[((long long)b * NTOK + base + pos) * D_ + t] = P[((long long)b * W * W + pos) * D_ + t];
}

// ---------------------------------------------------------------- host ----
static void gemm(hipStream_t st, bool nt,
                 const void* A, int lda, long long aSO, long long aSI, int aIn, int abf,
                 const void* Bm, int ldb, long long bSO, long long bSI, int bIn, int bbf,
                 void* C, int ldc, long long cSO, long long cSI, int cIn, int cbf,
                 int M, int N, int K, int batch,
                 const float* bias, float alpha, float beta, int relu,
                 int ksp = 1, int klen = 0){
  GP p;
  p.A = A; p.Bm = Bm; p.C = C; p.bias = bias;
  p.M = M; p.N = N; p.K = K; p.lda = lda; p.ldb = ldb; p.ldc = ldc;
  p.aSO = aSO; p.aSI = aSI; p.aIn = aIn; p.abf = abf;
  p.bSO = bSO; p.bSI = bSI; p.bIn = bIn; p.bbf = bbf;
  p.cSO = cSO; p.cSI = cSI; p.cIn = cIn; p.cbf = cbf;
  p.alpha = alpha; p.beta = beta; p.relu = relu;
  p.ksp = ksp; p.klen = (klen > 0) ? klen : K;
  dim3 g((N + 63) / 64, (M + 63) / 64, batch * ksp), b(256);
  if (nt) gemm_nt<<<g, b, 0, st>>>(p);
  else    gemm_nn<<<g, b, 0, st>>>(p);
}

extern "C" void kernel_launch(void* const* d_in, const int* in_sizes, int n_in,
                              void* d_out, int out_size, void* d_ws, size_t ws_size,
                              hipStream_t stream){
  const float* x      = (const float*)d_in[0];
  const float* fc1_w  = (const float*)d_in[1];
  const float* fc1_b  = (const float*)d_in[2];
  const float* cls    = (const float*)d_in[3];
  const float* l1_ng  = (const float*)d_in[4];
  const float* l1_nb  = (const float*)d_in[5];
  const float* l1_qkv = (const float*)d_in[6];
  const float* l1_ow  = (const float*)d_in[7];
  const float* l1_ob  = (const float*)d_in[8];
  const float* l1_rw  = (const float*)d_in[9];
  const float* ct_w7  = (const float*)d_in[10];
  const float* ct_b7  = (const float*)d_in[11];
  const float* ct_w5  = (const float*)d_in[12];
  const float* ct_b5  = (const float*)d_in[13];
  const float* ct_w3  = (const float*)d_in[14];
  const float* ct_b3  = (const float*)d_in[15];
  const float* pt_w7  = (const float*)d_in[16];
  const float* pt_b7  = (const float*)d_in[17];
  const float* pt_w5  = (const float*)d_in[18];
  const float* pt_b5  = (const float*)d_in[19];
  const float* pt_w3  = (const float*)d_in[20];
  const float* pt_b3  = (const float*)d_in[21];
  const float* l2_ng  = (const float*)d_in[22];
  const float* l2_nb  = (const float*)d_in[23];
  const float* l2_qkv = (const float*)d_in[24];
  const float* l2_ow  = (const float*)d_in[25];
  const float* l2_ob  = (const float*)d_in[26];
  const float* l2_rw  = (const float*)d_in[27];
  const float* nrm_g  = (const float*)d_in[28];
  const float* nrm_b  = (const float*)d_in[29];
  float* out = (float*)d_out;

  // ---- workspace layout (float units); total ~205 MB ----
  float* ws   = (float*)d_ws;
  float* H    = ws;                    // 12,828,672
  float* BUF  = H + 12828672;          // 13,107,200 : h0 / XLN / pinv-scratch+QL / OUT1 / ppeg P
  float* QKVf = BUF + 13107200;        // 19,660,800 : 39,321,600 bf16 QKV; later PROJ (13,107,200 f32)
  float* SIMC = QKVf + 19660800;       //  6,553,600 : 4-bh chunk of sim1/sim3
  float* KL   = SIMC + 6553600;        //    524,288
  float* AV   = KL + 524288;           //    524,288
  float* ZV   = AV + 524288;           //    524,288
  float* SC   = ZV + 524288;           //          2

  // BUF sub-allocation (live only between qkv-GEMM and sim1-GEMM)
  float* A2 = BUF;
  float* Zb = BUF + 2097152;
  float* Z2 = BUF + 4194304;
  float* AZ = BUF + 6291456;
  float* W1 = BUF + 8388608;
  float* W2 = BUF + 10485760;
  float* QL = BUF + 12582912;          // ends exactly at BUF + 13,107,200

  __hip_bfloat16* QKV = (__hip_bfloat16*)QKVf;
  float* PROJ = QKVf;                  // aliases QKV after q/k/v are dead
  const long long QE = (long long)NPAD * 1536;   // bf16 elements per batch

  // ---- stage 1: fc1 + relu (into BUF), gather tokens into H
  gemm(stream, false, x, 768, 0,0,1,0, fc1_w, 512, 0,0,1,0, BUF, 512, 0,0,1,0,
       B_*N0, 512, 768, 1, fc1_b, 0.f, 1.f, 1);
  build_h<<<dim3(NTOK, B_), 256, 0, stream>>>(BUF, cls, H);

  auto attn_layer = [&](const float* ng, const float* nb, const float* qkvw,
                        const float* outw, const float* outb, const float* resw){
    // LN (+front zero-pad) into BUF, then qkv projection -> bf16 QKV
    ln_pad<<<dim3(NPAD, B_), 256, 0, stream>>>(H, BUF, ng, nb);
    gemm(stream, false, BUF, 512, 0,0,1,0, qkvw, 1536, 0,0,1,0, QKV, 1536, 0,0,1,1,
         B_*NPAD, 1536, 512, 1, nullptr, 0.f, 1.f, 0);
    landmarks<<<dim3(NLM, B_*NH), 64, 0, stream>>>(QKV, QL, KL);
    // a2 = softmax(q_l @ k_l^T), batch 32
    gemm(stream, true, QL, 64, 16384,0,1,0, KL, 64, 16384,0,1,0, A2, 256, 65536,0,1,0,
         256, 256, 64, 32, nullptr, 0.f, 1.f, 0);
    softmax_rows<256><<<B_*NH*NLM, 256, 0, stream>>>(A2);
    // pinv (Newton-Schulz, 6 iters) on 32x 256x256
    init_sc<<<1, 1, 0, stream>>>(SC);
    colsum_max<<<B_*NH, 256, 0, stream>>>(A2, SC);
    rowsum_max<<<B_*NH, 256, 0, stream>>>(A2, SC);
    zinit<<<dim3(256, B_*NH), 256, 0, stream>>>(A2, Zb, SC);
    float *Zc = Zb, *Zn = Z2;
    for (int it = 0; it < 6; it++){
      gemm(stream, false, A2, 256, 65536,0,1,0, Zc, 256, 65536,0,1,0, AZ, 256, 65536,0,1,0,
           256, 256, 256, 32, nullptr, 0.f, 1.f, 0);
      diag7<<<dim3(256, B_*NH), 256, 0, stream>>>(AZ, W1);
      gemm(stream, false, AZ, 256, 65536,0,1,0, W1, 256, 65536,0,1,0, W2, 256, 65536,0,1,0,
           256, 256, 256, 32, nullptr, 15.f, -1.f, 0);
      gemm(stream, false, AZ, 256, 65536,0,1,0, W2, 256, 65536,0,1,0, W1, 256, 65536,0,1,0,
           256, 256, 256, 32, nullptr, 13.f, -1.f, 0);
      gemm(stream, false, Zc, 256, 65536,0,1,0, W1, 256, 65536,0,1,0, Zn, 256, 65536,0,1,0,
           256, 256, 256, 32, nullptr, 0.f, 0.25f, 0);
      float* tmp = Zc; Zc = Zn; Zn = tmp;
    }
    // sim3 -> AV, chunked over 4-head groups (8 chunks)
    fillz<<<2048, 256, 0, stream>>>(AV, 524288);
    for (int c = 0; c < 8; c++){
      int b = c >> 1, hh = (c & 1) * 4;
      const __hip_bfloat16* Kp = QKV + (long long)b*QE + hh*64 + 512;
      const __hip_bfloat16* Vp = QKV + (long long)b*QE + hh*64 + 1024;
      gemm(stream, true, QL + (long long)4*c*16384, 64, 16384,0,1,0,
           Kp, 1536, 0,64,4,1,
           SIMC, NPAD, (long long)256*NPAD,0,1,0,
           256, NPAD, 64, 4, nullptr, 0.f, 1.f, 0);
      softmax_rows<NPAD><<<4*NLM, 256, 0, stream>>>(SIMC);
      gemm(stream, false, SIMC, NPAD, (long long)256*NPAD,0,1,0,
           Vp, 1536, 0,64,4,1,
           AV + (long long)4*c*16384, 64, 16384,0,1,0,
           256, 64, NPAD, 4, nullptr, 0.f, 1.f, 0, 25, 256);   // K-split + atomicAdd
    }
    // ZV = Z @ AV, batch 32
    gemm(stream, false, Zc, 256, 65536,0,1,0, AV, 64, 16384,0,1,0, ZV, 64, 16384,0,1,0,
         256, 64, 256, 32, nullptr, 0.f, 1.f, 0);
    // sim1 -> OUT1 (into BUF, layout (b,n,h*64+d)), chunked
    for (int c = 0; c < 8; c++){
      int b = c >> 1, hh = (c & 1) * 4;
      const __hip_bfloat16* Qp = QKV + (long long)b*QE + hh*64;
      gemm(stream, true, Qp, 1536, 0,64,4,1,
           KL + (long long)4*c*16384, 64, 16384,0,1,0,
           SIMC, 256, (long long)NPAD*256,0,1,0,
           NPAD, 256, 64, 4, nullptr, 0.f, 0.125f, 0);
      softmax_rows<256><<<4*NPAD, 256, 0, stream>>>(SIMC);
      gemm(stream, false, SIMC, 256, (long long)NPAD*256,0,1,0,
           ZV + (long long)4*c*16384, 64, 16384,0,1,0,
           BUF + (long long)b*NPAD*512 + hh*64, 512, 0,64,4,0,
           NPAD, 64, 256, 4, nullptr, 0.f, 1.f, 0);
    }
    // depthwise residual conv on v (accumulate into OUT1)
    dwconv_add<<<dim3(NPAD, B_), 512, 0, stream>>>(QKV, resw, BUF);
    // output projection (PROJ aliases dead QKV region) + residual add
    gemm(stream, false, BUF, 512, 0,0,1,0, outw, 512, 0,0,1,0, PROJ, 512, 0,0,1,0,
         B_*NPAD, 512, 512, 1, nullptr, 0.f, 1.f, 0);
    resid_add<<<dim3(NTOK, B_), 512, 0, stream>>>(H, PROJ, outb);
  };

  // ---- layer 1
  attn_layer(l1_ng, l1_nb, l1_qkv, l1_ow, l1_ob, l1_rw);

  // ---- PPEG (ct: base 11, 13x13; pth: base 180, 78x78) — BUF as scratch
  ppeg_k<<<dim3(169, B_), 256, 0, stream>>>(H, BUF, ct_w7, ct_b7, ct_w5, ct_b5, ct_w3, ct_b3, 11, 13);
  ppeg_copy<<<dim3(169, B_), 512, 0, stream>>>(H, BUF, 11, 13);
  ppeg_k<<<dim3(6084, B_), 256, 0, stream>>>(H, BUF, pt_w7, pt_b7, pt_w5, pt_b5, pt_w3, pt_b3, 180, 78);
  ppeg_copy<<<dim3(6084, B_), 512, 0, stream>>>(H, BUF, 180, 78);

  // ---- layer 2
  attn_layer(l2_ng, l2_nb, l2_qkv, l2_ow, l2_ob, l2_rw);

  // ---- final LN on cls token
  final_ln<<<B_, 256, 0, stream>>>(H, nrm_g, nrm_b, out);
}

// Round 3
// 9479.559 us; speedup vs baseline: 1.2866x; 1.2866x over previous
//
#include <hip/hip_runtime.h>
#include <hip/hip_bf16.h>
#include <cstdint>

#define B_   4
#define NTOK 6264
#define NPAD 6400
#define D_   512
#define NH   8
#define NLM  256
#define N0   6170
#define PADF (NPAD - NTOK)   // 136

typedef __attribute__((ext_vector_type(8))) short short8_t;
typedef __attribute__((ext_vector_type(4))) float float4_t;

__device__ __forceinline__ ushort f2b(float x){
  __hip_bfloat16 h = __float2bfloat16(x); return *(ushort*)&h;
}
__device__ __forceinline__ float b2f(ushort u){
  __hip_bfloat16 h = *(__hip_bfloat16*)&u; return __bfloat162float(h);
}
__device__ __forceinline__ float gload(const void* p, int bf, long long i){
  return bf ? __bfloat162float(((const __hip_bfloat16*)p)[i]) : ((const float*)p)[i];
}
__device__ __forceinline__ void atomicMaxF(float* a, float v){
  atomicMax((int*)a, __float_as_int(v));   // values strictly positive
}

// ------------------------------------------------------------- MFMA GEMM ----
// C = beta*(A@B or A@B^T) [+ alpha*I] [+bias] [relu]; optional K-split atomic.
// A: MxK rm (fp32 or bf16), B: KxN rm (bt=0) or NxK rm (bt=1).
// SPLIT=1: hi/lo bf16 decomposition of both operands (3 mfma/product) ~fp32 acc.
struct GP {
  const void* A; const void* Bm; void* C; const float* bias;
  int M, N, K, lda, ldb, ldc;
  long long aSO, aSI; int aIn, abf;
  long long bSO, bSI; int bIn, bbf, bt;
  long long cSO, cSI; int cIn, cbf;
  float alpha, beta; int relu, ksp, klen;
};

template<int SPLIT>
__global__ __launch_bounds__(256) void gemm_mfma(GP p){
  constexpr int LDW = 40;                    // padded k-stride (halfwords)
  constexpr int PL  = SPLIT ? 2 : 1;
  __shared__ __align__(16) ushort As[PL*64*LDW];
  __shared__ __align__(16) ushort Bs[PL*64*LDW];
  int zz = blockIdx.z;
  int z = zz / p.ksp, ks = zz - z*p.ksp;
  int k0 = ks * p.klen;
  int kend = k0 + p.klen; if (kend > p.K) kend = p.K;
  long long aOff = (long long)(z / p.aIn)*p.aSO + (long long)(z % p.aIn)*p.aSI;
  long long bOff = (long long)(z / p.bIn)*p.bSO + (long long)(z % p.bIn)*p.bSI;
  long long cOff = (long long)(z / p.cIn)*p.cSO + (long long)(z % p.cIn)*p.cSI;
  int rowBase = blockIdx.y * 64, colBase = blockIdx.x * 64;
  int t = threadIdx.x, wave = t >> 6, lane = t & 63;
  int lm = lane & 15, lq = lane >> 4;

  float4_t acc[4];
  #pragma unroll
  for (int nf = 0; nf < 4; nf++) acc[nf] = (float4_t)0.f;

  int smr = t >> 2;            // 0..63 : A row / B-NT row
  int skk = (t & 3) * 8;       // k octet base

  for (int kb = k0; kb < kend; kb += 32){
    // ---- stage A (64x32) ----
    {
      int gm = rowBase + smr;
      bool ok = gm < p.M;
      float v[8];
      #pragma unroll
      for (int j = 0; j < 8; j++)
        v[j] = ok ? gload(p.A, p.abf, aOff + (long long)gm*p.lda + kb + skk + j) : 0.f;
      short8_t hv, lv;
      #pragma unroll
      for (int j = 0; j < 8; j++){
        ushort h = f2b(v[j]); hv[j] = (short)h;
        if (SPLIT) lv[j] = (short)f2b(v[j] - b2f(h));
      }
      *(short8_t*)&As[smr*LDW + skk] = hv;
      if (SPLIT) *(short8_t*)&As[64*LDW + smr*LDW + skk] = lv;
    }
    // ---- stage B (64 cols x 32 k, stored [n][k]) ----
    if (p.bt){
      int gn = colBase + smr;
      bool ok = gn < p.N;
      float v[8];
      #pragma unroll
      for (int j = 0; j < 8; j++)
        v[j] = ok ? gload(p.Bm, p.bbf, bOff + (long long)gn*p.ldb + kb + skk + j) : 0.f;
      short8_t hv, lv;
      #pragma unroll
      for (int j = 0; j < 8; j++){
        ushort h = f2b(v[j]); hv[j] = (short)h;
        if (SPLIT) lv[j] = (short)f2b(v[j] - b2f(h));
      }
      *(short8_t*)&Bs[smr*LDW + skk] = hv;
      if (SPLIT) *(short8_t*)&Bs[64*LDW + smr*LDW + skk] = lv;
    } else {
      int bk = t >> 3;               // 0..31
      int n0 = (t & 7) * 8;
      #pragma unroll
      for (int j = 0; j < 8; j++){
        float v = gload(p.Bm, p.bbf, bOff + (long long)(kb + bk)*p.ldb + colBase + n0 + j);
        ushort h = f2b(v);
        Bs[(n0 + j)*LDW + bk] = h;
        if (SPLIT) Bs[64*LDW + (n0 + j)*LDW + bk] = f2b(v - b2f(h));
      }
    }
    __syncthreads();
    // ---- compute: wave handles rows [wave*16, wave*16+16) x 64 cols ----
    {
      short8_t a = *(const short8_t*)&As[(wave*16 + lm)*LDW + lq*8];
      short8_t al;
      if (SPLIT) al = *(const short8_t*)&As[64*LDW + (wave*16 + lm)*LDW + lq*8];
      #pragma unroll
      for (int nf = 0; nf < 4; nf++){
        short8_t b = *(const short8_t*)&Bs[(nf*16 + lm)*LDW + lq*8];
        acc[nf] = __builtin_amdgcn_mfma_f32_16x16x32_bf16(a, b, acc[nf], 0, 0, 0);
        if (SPLIT){
          short8_t bl = *(const short8_t*)&Bs[64*LDW + (nf*16 + lm)*LDW + lq*8];
          acc[nf] = __builtin_amdgcn_mfma_f32_16x16x32_bf16(a,  bl, acc[nf], 0, 0, 0);
          acc[nf] = __builtin_amdgcn_mfma_f32_16x16x32_bf16(al, b,  acc[nf], 0, 0, 0);
        }
      }
    }
    __syncthreads();
  }
  // ---- epilogue: C/D layout col=lane&15, row=(lane>>4)*4+reg ----
  #pragma unroll
  for (int nf = 0; nf < 4; nf++){
    int c = colBase + nf*16 + lm;
    if (c >= p.N) continue;
    #pragma unroll
    for (int r = 0; r < 4; r++){
      int m = rowBase + wave*16 + lq*4 + r;
      if (m >= p.M) continue;
      float v = p.beta * acc[nf][r];
      long long ci = cOff + (long long)m * p.ldc + c;
      if (p.ksp > 1){
        atomicAdd((float*)p.C + ci, v);
      } else {
        if (p.alpha != 0.f && m == c) v += p.alpha;
        if (p.bias) v += p.bias[c];
        if (p.relu) v = fmaxf(v, 0.f);
        if (p.cbf) ((__hip_bfloat16*)p.C)[ci] = __float2bfloat16(v);
        else       ((float*)p.C)[ci] = v;
      }
    }
  }
}

// ------------------------------------------------------------ softmax ----
template<int LEN>
__global__ __launch_bounds__(256) void softmax_rows(float* S){
  constexpr int VPT = LEN / 256;
  long long row = blockIdx.x;
  float* p = S + row * LEN;
  int t = threadIdx.x;
  float v[VPT];
  float m = -1e30f;
  #pragma unroll
  for (int q = 0; q < VPT; q++){ v[q] = p[t + 256*q]; m = fmaxf(m, v[q]); }
  __shared__ float red[256];
  red[t] = m; __syncthreads();
  for (int s = 128; s; s >>= 1){ if (t < s) red[t] = fmaxf(red[t], red[t+s]); __syncthreads(); }
  m = red[0]; __syncthreads();
  float sum = 0.f;
  #pragma unroll
  for (int q = 0; q < VPT; q++){ v[q] = __expf(v[q] - m); sum += v[q]; }
  red[t] = sum; __syncthreads();
  for (int s = 128; s; s >>= 1){ if (t < s) red[t] += red[t+s]; __syncthreads(); }
  float inv = 1.f / red[0];
  #pragma unroll
  for (int q = 0; q < VPT; q++) p[t + 256*q] = v[q] * inv;
}

// --------------------------------------------------------- LN kernels ----
__global__ __launch_bounds__(256) void ln_pad(const float* H, float* X,
                                              const float* g, const float* bb){
  int p = blockIdx.x, b = blockIdx.y, t = threadIdx.x;
  float* xo = X + ((long long)b * NPAD + p) * D_;
  if (p < PADF){ xo[t] = 0.f; xo[t + 256] = 0.f; return; }
  const float* hi = H + ((long long)b * NTOK + (p - PADF)) * D_;
  float x0 = hi[t], x1 = hi[t + 256];
  __shared__ float r1[256], r2[256];
  r1[t] = x0 + x1; r2[t] = x0*x0 + x1*x1;
  __syncthreads();
  for (int s = 128; s; s >>= 1){ if (t < s){ r1[t] += r1[t+s]; r2[t] += r2[t+s]; } __syncthreads(); }
  float mu = r1[0] * (1.f / D_);
  float var = r2[0] * (1.f / D_) - mu*mu;
  float rs = rsqrtf(var + 1e-5f);
  xo[t]       = (x0 - mu) * rs * g[t]       + bb[t];
  xo[t + 256] = (x1 - mu) * rs * g[t + 256] + bb[t + 256];
}

__global__ __launch_bounds__(256) void final_ln(const float* H, const float* g,
                                                const float* bb, float* out){
  int b = blockIdx.x, t = threadIdx.x;
  const float* hi = H + (long long)b * NTOK * D_;   // token 0 (cls)
  float x0 = hi[t], x1 = hi[t + 256];
  __shared__ float r1[256], r2[256];
  r1[t] = x0 + x1; r2[t] = x0*x0 + x1*x1;
  __syncthreads();
  for (int s = 128; s; s >>= 1){ if (t < s){ r1[t] += r1[t+s]; r2[t] += r2[t+s]; } __syncthreads(); }
  float mu = r1[0] * (1.f / D_);
  float var = r2[0] * (1.f / D_) - mu*mu;
  float rs = rsqrtf(var + 1e-5f);
  out[b*D_ + t]       = (x0 - mu) * rs * g[t]       + bb[t];
  out[b*D_ + t + 256] = (x1 - mu) * rs * g[t + 256] + bb[t + 256];
}

// -------------------------------------------------------- misc kernels ----
__global__ __launch_bounds__(256) void build_h(const float* h0, const float* cls, float* H){
  int tpos = blockIdx.x, b = blockIdx.y, t = threadIdx.x;
  float* dst = H + ((long long)b * NTOK + tpos) * D_;
  if (tpos == 0){ dst[t] = cls[t]; dst[t + 256] = cls[t + 256]; return; }
  int i = tpos - 1, src;
  if (i < 10)        src = i;
  else if (i < 179){ int j = i - 10;  src = 10  + (j < 160  ? j : j - 160);  }
  else             { int j = i - 179; src = 170 + (j < 6000 ? j : j - 6000); }
  const float* s = h0 + ((long long)b * N0 + src) * D_;
  dst[t] = s[t]; dst[t + 256] = s[t + 256];
}

__global__ __launch_bounds__(64) void landmarks(const __hip_bfloat16* QKV, float* QL, float* KL){
  int j = blockIdx.x, z = blockIdx.y, d = threadIdx.x;
  int b = z >> 3, h = z & 7;
  const __hip_bfloat16* base = QKV + ((long long)b * NPAD + j*25) * 1536 + h*64 + d;
  float q = 0.f, k = 0.f;
  #pragma unroll 1
  for (int i = 0; i < 25; i++){
    q += __bfloat162float(base[(long long)i*1536]);
    k += __bfloat162float(base[(long long)i*1536 + 512]);
  }
  QL[((long long)z * NLM + j) * 64 + d] = q * (1.f/25.f) * 0.125f;
  KL[((long long)z * NLM + j) * 64 + d] = k * (1.f/25.f);
}

__global__ void init_sc(float* sc){ sc[0] = 0.f; sc[1] = 0.f; }

__global__ __launch_bounds__(256) void fillz(float* p, int n){
  int i = blockIdx.x*256 + threadIdx.x; if (i < n) p[i] = 0.f;
}

__global__ __launch_bounds__(256) void colsum_max(const float* A2, float* sc){
  int z = blockIdx.x, t = threadIdx.x;
  const float* a = A2 + (long long)z * 65536;
  float s = 0.f;
  for (int i = 0; i < 256; i++) s += fabsf(a[i*256 + t]);
  __shared__ float red[256];
  red[t] = s; __syncthreads();
  for (int st = 128; st; st >>= 1){ if (t < st) red[t] = fmaxf(red[t], red[t+st]); __syncthreads(); }
  if (t == 0) atomicMaxF(sc + 0, red[0]);
}

__global__ __launch_bounds__(256) void rowsum_max(const float* A2, float* sc){
  int z = blockIdx.x, t = threadIdx.x, w = t >> 6, l = t & 63;
  const float* a = A2 + (long long)z * 65536;
  float mx = 0.f;
  for (int i = w*64; i < (w+1)*64; i++){
    float s = fabsf(a[i*256 + l]) + fabsf(a[i*256 + l + 64])
            + fabsf(a[i*256 + l + 128]) + fabsf(a[i*256 + l + 192]);
    for (int m = 32; m; m >>= 1) s += __shfl_xor(s, m);
    mx = fmaxf(mx, s);
  }
  __shared__ float red[4];
  if (l == 0) red[w] = mx;
  __syncthreads();
  if (t == 0){
    float m2 = fmaxf(fmaxf(red[0], red[1]), fmaxf(red[2], red[3]));
    atomicMaxF(sc + 1, m2);
  }
}

__global__ __launch_bounds__(256) void zinit(const float* A2, float* Z, const float* sc){
  int j = blockIdx.x, z = blockIdx.y, i = threadIdx.x;
  float inv = 1.f / (sc[0] * sc[1]);
  Z[(long long)z*65536 + j*256 + i] = A2[(long long)z*65536 + i*256 + j] * inv;
}

__global__ __launch_bounds__(256) void diag7(const float* AZ, float* W1){
  int r = blockIdx.x, z = blockIdx.y, j = threadIdx.x;
  float v = -AZ[(long long)z*65536 + r*256 + j];
  if (r == j) v += 7.f;
  W1[(long long)z*65536 + r*256 + j] = v;
}

__global__ __launch_bounds__(512) void dwconv_add(const __hip_bfloat16* QKV, const float* rw, float* OUT1){
  int n = blockIdx.x, b = blockIdx.y, t = threadIdx.x;
  int h = t >> 6;
  float acc = 0.f;
  #pragma unroll 1
  for (int k = 0; k < 33; k++){
    int nn = n + k - 16;
    if (nn >= 0 && nn < NPAD)
      acc += rw[h*33 + k] * __bfloat162float(QKV[((long long)b * NPAD + nn) * 1536 + 1024 + t]);
  }
  OUT1[((long long)b * NPAD + n) * D_ + t] += acc;
}

__global__ __launch_bounds__(512) void resid_add(float* H, const float* O2, const float* ob){
  int i = blockIdx.x, b = blockIdx.y, t = threadIdx.x;
  H[((long long)b * NTOK + i) * D_ + t] +=
      O2[((long long)b * NPAD + i + PADF) * D_ + t] + ob[t];
}

// weight transpose for PPEG: w[512][KK] -> wt[KK][512]
__global__ __launch_bounds__(256) void transpose_w(const float* w, float* wt, int KK){
  int i = blockIdx.x*256 + threadIdx.x;
  if (i < 512*KK){ int ch = i / KK, k = i - ch*KK; wt[(long long)k*512 + ch] = w[i]; }
}

// LDS-tiled PPEG: 8x8 spatial tile x 64-ch group; patch 14x14 in LDS.
__global__ __launch_bounds__(256) void ppeg_tiled(const float* H, float* P,
    const float* t7, const float* t5, const float* t3,
    const float* b7, const float* b5, const float* b3,
    int base, int W, int tilesX){
  __shared__ float smem[196*64];   // 50 KB
  int ty0 = (blockIdx.x / tilesX) * 8, tx0 = (blockIdx.x % tilesX) * 8;
  int c0 = blockIdx.y * 64, b = blockIdx.z;
  int t = threadIdx.x, ch = t & 63, pr = t >> 6;
  const float* Hb = H + ((long long)b * NTOK + base) * D_ + c0 + ch;
  for (int i = pr; i < 196; i += 4){
    int py = i / 14, px = i - py*14;
    int y = ty0 + py - 3, x = tx0 + px - 3;
    smem[i*64 + ch] = (y >= 0 && y < W && x >= 0 && x < W)
                      ? Hb[(long long)(y*W + x) * D_] : 0.f;
  }
  __syncthreads();
  float acc[16];
  float bsum = b7[c0+ch] + b5[c0+ch] + b3[c0+ch];
  #pragma unroll
  for (int o = 0; o < 16; o++){
    int y = o >> 1, x = pr + (o & 1)*4;
    acc[o] = smem[((y+3)*14 + (x+3))*64 + ch] + bsum;
  }
  for (int ky = 0; ky < 7; ky++)
    for (int kx = 0; kx < 7; kx++){
      float wv = t7[(ky*7 + kx)*512 + c0 + ch];
      #pragma unroll
      for (int o = 0; o < 16; o++){
        int y = o >> 1, x = pr + (o & 1)*4;
        acc[o] += wv * smem[((y+ky)*14 + (x+kx))*64 + ch];
      }
    }
  for (int ky = 0; ky < 5; ky++)
    for (int kx = 0; kx < 5; kx++){
      float wv = t5[(ky*5 + kx)*512 + c0 + ch];
      #pragma unroll
      for (int o = 0; o < 16; o++){
        int y = o >> 1, x = pr + (o & 1)*4;
        acc[o] += wv * smem[((y+1+ky)*14 + (x+1+kx))*64 + ch];
      }
    }
  for (int ky = 0; ky < 3; ky++)
    for (int kx = 0; kx < 3; kx++){
      float wv = t3[(ky*3 + kx)*512 + c0 + ch];
      #pragma unroll
      for (int o = 0; o < 16; o++){
        int y = o >> 1, x = pr + (o & 1)*4;
        acc[o] += wv * smem[((y+2+ky)*14 + (x+2+kx))*64 + ch];
      }
    }
  #pragma unroll
  for (int o = 0; o < 16; o++){
    int y = ty0 + (o >> 1), x = tx0 + pr + (o & 1)*4;
    if (y < W && x < W)
      P[((long long)b * W * W + y*W + x) * D_ + c0 + ch] = acc[o];
  }
}

__global__ __launch_bounds__(512) void ppeg_copy(float* H, const float* P, int base, int W){
  int pos = blockIdx.x, b = blockIdx.y, t = threadIdx.x;
  H[((long long)b * NTOK + base + pos) * D_ + t] = P[((long long)b * W * W + pos) * D_ + t];
}

// ---------------------------------------------------------------- host ----
static void gemm(hipStream_t st, int bt, int split,
                 const void* A, int lda, long long aSO, long long aSI, int aIn, int abf,
                 const void* Bm, int ldb, long long bSO, long long bSI, int bIn, int bbf,
                 void* C, int ldc, long long cSO, long long cSI, int cIn, int cbf,
                 int M, int N, int K, int batch,
                 const float* bias, float alpha, float beta, int relu,
                 int ksp = 1, int klen = 0){
  GP p;
  p.A = A; p.Bm = Bm; p.C = C; p.bias = bias;
  p.M = M; p.N = N; p.K = K; p.lda = lda; p.ldb = ldb; p.ldc = ldc;
  p.aSO = aSO; p.aSI = aSI; p.aIn = aIn; p.abf = abf;
  p.bSO = bSO; p.bSI = bSI; p.bIn = bIn; p.bbf = bbf; p.bt = bt;
  p.cSO = cSO; p.cSI = cSI; p.cIn = cIn; p.cbf = cbf;
  p.alpha = alpha; p.beta = beta; p.relu = relu;
  p.ksp = ksp; p.klen = (klen > 0) ? klen : K;
  dim3 g((N + 63)/64, (M + 63)/64, batch * ksp), b(256);
  if (split) gemm_mfma<1><<<g, b, 0, st>>>(p);
  else       gemm_mfma<0><<<g, b, 0, st>>>(p);
}

extern "C" void kernel_launch(void* const* d_in, const int* in_sizes, int n_in,
                              void* d_out, int out_size, void* d_ws, size_t ws_size,
                              hipStream_t stream){
  const float* x      = (const float*)d_in[0];
  const float* fc1_w  = (const float*)d_in[1];
  const float* fc1_b  = (const float*)d_in[2];
  const float* cls    = (const float*)d_in[3];
  const float* l1_ng  = (const float*)d_in[4];
  const float* l1_nb  = (const float*)d_in[5];
  const float* l1_qkv = (const float*)d_in[6];
  const float* l1_ow  = (const float*)d_in[7];
  const float* l1_ob  = (const float*)d_in[8];
  const float* l1_rw  = (const float*)d_in[9];
  const float* ct_w7  = (const float*)d_in[10];
  const float* ct_b7  = (const float*)d_in[11];
  const float* ct_w5  = (const float*)d_in[12];
  const float* ct_b5  = (const float*)d_in[13];
  const float* ct_w3  = (const float*)d_in[14];
  const float* ct_b3  = (const float*)d_in[15];
  const float* pt_w7  = (const float*)d_in[16];
  const float* pt_b7  = (const float*)d_in[17];
  const float* pt_w5  = (const float*)d_in[18];
  const float* pt_b5  = (const float*)d_in[19];
  const float* pt_w3  = (const float*)d_in[20];
  const float* pt_b3  = (const float*)d_in[21];
  const float* l2_ng  = (const float*)d_in[22];
  const float* l2_nb  = (const float*)d_in[23];
  const float* l2_qkv = (const float*)d_in[24];
  const float* l2_ow  = (const float*)d_in[25];
  const float* l2_ob  = (const float*)d_in[26];
  const float* l2_rw  = (const float*)d_in[27];
  const float* nrm_g  = (const float*)d_in[28];
  const float* nrm_b  = (const float*)d_in[29];
  float* out = (float*)d_out;

  // ---- workspace layout (float units); total ~215 MB ----
  float* ws   = (float*)d_ws;
  float* H    = ws;                    // 12,828,672
  float* BUF  = H + 12828672;          // 13,107,200 : h0 / XLN / pinv+QL / OUT1 / ppeg P
  float* QKVf = BUF + 13107200;        // 19,660,800 : bf16 QKV; later PROJ f32
  float* SIMC = QKVf + 19660800;       //  6,553,600
  float* KL   = SIMC + 6553600;        //    524,288
  float* AV   = KL + 524288;           //    524,288
  float* ZV   = AV + 524288;           //    524,288
  float* SC   = ZV + 524288;           //          2
  float* WT   = SC + 2;                //     84,992 : transposed ppeg weights
  float* tc7 = WT,        *tc5 = tc7 + 49*512, *tc3 = tc5 + 25*512;
  float* tp7 = tc3 + 9*512, *tp5 = tp7 + 49*512, *tp3 = tp5 + 25*512;

  // BUF sub-allocation (pinv window)
  float* A2 = BUF;
  float* Zb = BUF + 2097152;
  float* Z2 = BUF + 4194304;
  float* AZ = BUF + 6291456;
  float* W1 = BUF + 8388608;
  float* W2 = BUF + 10485760;
  float* QL = BUF + 12582912;

  __hip_bfloat16* QKV = (__hip_bfloat16*)QKVf;
  float* PROJ = QKVf;
  const long long QE = (long long)NPAD * 1536;

  // ---- ppeg weight transposes (once per launch)
  transpose_w<<<(512*49+255)/256, 256, 0, stream>>>(ct_w7, tc7, 49);
  transpose_w<<<(512*25+255)/256, 256, 0, stream>>>(ct_w5, tc5, 25);
  transpose_w<<<(512* 9+255)/256, 256, 0, stream>>>(ct_w3, tc3,  9);
  transpose_w<<<(512*49+255)/256, 256, 0, stream>>>(pt_w7, tp7, 49);
  transpose_w<<<(512*25+255)/256, 256, 0, stream>>>(pt_w5, tp5, 25);
  transpose_w<<<(512* 9+255)/256, 256, 0, stream>>>(pt_w3, tp3,  9);

  // ---- stage 1: fc1 + relu (into BUF), gather tokens into H
  gemm(stream, 0, 0, x, 768, 0,0,1,0, fc1_w, 512, 0,0,1,0, BUF, 512, 0,0,1,0,
       B_*N0, 512, 768, 1, fc1_b, 0.f, 1.f, 1);
  build_h<<<dim3(NTOK, B_), 256, 0, stream>>>(BUF, cls, H);

  auto attn_layer = [&](const float* ng, const float* nb, const float* qkvw,
                        const float* outw, const float* outb, const float* resw){
    ln_pad<<<dim3(NPAD, B_), 256, 0, stream>>>(H, BUF, ng, nb);
    gemm(stream, 0, 0, BUF, 512, 0,0,1,0, qkvw, 1536, 0,0,1,0, QKV, 1536, 0,0,1,1,
         B_*NPAD, 1536, 512, 1, nullptr, 0.f, 1.f, 0);
    landmarks<<<dim3(NLM, B_*NH), 64, 0, stream>>>(QKV, QL, KL);
    // a2 = softmax(q_l @ k_l^T), batch 32
    gemm(stream, 1, 0, QL, 64, 16384,0,1,0, KL, 64, 16384,0,1,0, A2, 256, 65536,0,1,0,
         256, 256, 64, 32, nullptr, 0.f, 1.f, 0);
    softmax_rows<256><<<B_*NH*NLM, 256, 0, stream>>>(A2);
    // pinv (Newton-Schulz, 6 iters), hi/lo-split mfma
    init_sc<<<1, 1, 0, stream>>>(SC);
    colsum_max<<<B_*NH, 256, 0, stream>>>(A2, SC);
    rowsum_max<<<B_*NH, 256, 0, stream>>>(A2, SC);
    zinit<<<dim3(256, B_*NH), 256, 0, stream>>>(A2, Zb, SC);
    float *Zc = Zb, *Zn = Z2;
    for (int it = 0; it < 6; it++){
      gemm(stream, 0, 1, A2, 256, 65536,0,1,0, Zc, 256, 65536,0,1,0, AZ, 256, 65536,0,1,0,
           256, 256, 256, 32, nullptr, 0.f, 1.f, 0);
      diag7<<<dim3(256, B_*NH), 256, 0, stream>>>(AZ, W1);
      gemm(stream, 0, 1, AZ, 256, 65536,0,1,0, W1, 256, 65536,0,1,0, W2, 256, 65536,0,1,0,
           256, 256, 256, 32, nullptr, 15.f, -1.f, 0);
      gemm(stream, 0, 1, AZ, 256, 65536,0,1,0, W2, 256, 65536,0,1,0, W1, 256, 65536,0,1,0,
           256, 256, 256, 32, nullptr, 13.f, -1.f, 0);
      gemm(stream, 0, 1, Zc, 256, 65536,0,1,0, W1, 256, 65536,0,1,0, Zn, 256, 65536,0,1,0,
           256, 256, 256, 32, nullptr, 0.f, 0.25f, 0);
      float* tmp = Zc; Zc = Zn; Zn = tmp;
    }
    // sim3 -> AV, chunked over 4 bh-groups
    fillz<<<2048, 256, 0, stream>>>(AV, 524288);
    for (int c = 0; c < 8; c++){
      int b = c >> 1, hh = (c & 1) * 4;
      const __hip_bfloat16* Kp = QKV + (long long)b*QE + hh*64 + 512;
      const __hip_bfloat16* Vp = QKV + (long long)b*QE + hh*64 + 1024;
      gemm(stream, 1, 0, QL + (long long)4*c*16384, 64, 16384,0,1,0,
           Kp, 1536, 0,64,4,1,
           SIMC, NPAD, (long long)256*NPAD,0,1,0,
           256, NPAD, 64, 4, nullptr, 0.f, 1.f, 0);
      softmax_rows<NPAD><<<4*NLM, 256, 0, stream>>>(SIMC);
      gemm(stream, 0, 0, SIMC, NPAD, (long long)256*NPAD,0,1,0,
           Vp, 1536, 0,64,4,1,
           AV + (long long)4*c*16384, 64, 16384,0,1,0,
           256, 64, NPAD, 4, nullptr, 0.f, 1.f, 0, 25, 256);   // K-split atomic
    }
    // ZV = Z @ AV, batch 32
    gemm(stream, 0, 0, Zc, 256, 65536,0,1,0, AV, 64, 16384,0,1,0, ZV, 64, 16384,0,1,0,
         256, 64, 256, 32, nullptr, 0.f, 1.f, 0);
    // sim1 -> OUT1 (into BUF, layout (b,n,h*64+d)), chunked
    for (int c = 0; c < 8; c++){
      int b = c >> 1, hh = (c & 1) * 4;
      const __hip_bfloat16* Qp = QKV + (long long)b*QE + hh*64;
      gemm(stream, 1, 0, Qp, 1536, 0,64,4,1,
           KL + (long long)4*c*16384, 64, 16384,0,1,0,
           SIMC, 256, (long long)NPAD*256,0,1,0,
           NPAD, 256, 64, 4, nullptr, 0.f, 0.125f, 0);
      softmax_rows<256><<<4*NPAD, 256, 0, stream>>>(SIMC);
      gemm(stream, 0, 0, SIMC, 256, (long long)NPAD*256,0,1,0,
           ZV + (long long)4*c*16384, 64, 16384,0,1,0,
           BUF + (long long)b*NPAD*512 + hh*64, 512, 0,64,4,0,
           NPAD, 64, 256, 4, nullptr, 0.f, 1.f, 0);
    }
    dwconv_add<<<dim3(NPAD, B_), 512, 0, stream>>>(QKV, resw, BUF);
    gemm(stream, 0, 0, BUF, 512, 0,0,1,0, outw, 512, 0,0,1,0, PROJ, 512, 0,0,1,0,
         B_*NPAD, 512, 512, 1, nullptr, 0.f, 1.f, 0);
    resid_add<<<dim3(NTOK, B_), 512, 0, stream>>>(H, PROJ, outb);
  };

  // ---- layer 1
  attn_layer(l1_ng, l1_nb, l1_qkv, l1_ow, l1_ob, l1_rw);

  // ---- PPEG (ct: base 11, 13x13 tiles 2x2; pth: base 180, 78x78 tiles 10x10)
  ppeg_tiled<<<dim3(4, 8, B_), 256, 0, stream>>>(H, BUF, tc7, tc5, tc3, ct_b7, ct_b5, ct_b3, 11, 13, 2);
  ppeg_copy<<<dim3(169, B_), 512, 0, stream>>>(H, BUF, 11, 13);
  ppeg_tiled<<<dim3(100, 8, B_), 256, 0, stream>>>(H, BUF, tp7, tp5, tp3, pt_b7, pt_b5, pt_b3, 180, 78, 10);
  ppeg_copy<<<dim3(6084, B_), 512, 0, stream>>>(H, BUF, 180, 78);

  // ---- layer 2
  attn_layer(l2_ng, l2_nb, l2_qkv, l2_ow, l2_ob, l2_rw);

  // ---- final LN on cls token
  final_ln<<<B_, 256, 0, stream>>>(H, nrm_g, nrm_b, out);
}

// Round 4
// 4857.247 us; speedup vs baseline: 2.5110x; 1.9516x over previous
//
#include <hip/hip_runtime.h>
#include <hip/hip_bf16.h>
#include <cstdint>

#define B_   4
#define NTOK 6264
#define NPAD 6400
#define D_   512
#define NH   8
#define NLM  256
#define N0   6170
#define PADF (NPAD - NTOK)   // 136
#define MFC1 24704           // B_*N0 padded to x128

typedef __attribute__((ext_vector_type(8))) short short8_t;
typedef __attribute__((ext_vector_type(4))) float float4_t;

__device__ __forceinline__ ushort f2b(float x){
  __hip_bfloat16 h = __float2bfloat16(x); return *(ushort*)&h;
}
__device__ __forceinline__ float b2f(ushort u){
  __hip_bfloat16 h = *(__hip_bfloat16*)&u; return __bfloat162float(h);
}
__device__ __forceinline__ float gload(const void* p, int bf, long long i){
  return bf ? __bfloat162float(((const __hip_bfloat16*)p)[i]) : ((const float*)p)[i];
}
__device__ __forceinline__ void atomicMaxF(float* a, float v){
  atomicMax((int*)a, __float_as_int(v));
}
__device__ __forceinline__ void gl_lds16(const void* g, void* l){
  __builtin_amdgcn_global_load_lds(
      (const __attribute__((address_space(1))) void*)g,
      (__attribute__((address_space(3))) void*)l, 16, 0, 0);
}

// ===================== fast bf16 NT GEMM (m97-style) ======================
// C = beta*(A@B^T) [+bias][relu]; A: MxK rm bf16, B: NxK rm bf16.
// Requires M%128==0, N%BN==0, K%64==0 (and klen%64==0 for K-split).
struct GB {
  const __hip_bfloat16* A; const __hip_bfloat16* Bm; void* C; const float* bias;
  int M, N, K, lda, ldb, ldc;
  long long aSO, aSI; int aIn;
  long long bSO, bSI; int bIn;
  long long cSO, cSI; int cIn;
  float beta; int cbf, relu, ksp, klen;
};

template<int BN>
__global__ __launch_bounds__(256) void gemm_bt(GB p){
  __shared__ __align__(16) __hip_bfloat16 As[128*64];
  __shared__ __align__(16) __hip_bfloat16 Bs[BN*64];
  int zz = blockIdx.z;
  int z = zz / p.ksp, ks = zz - z*p.ksp;
  int k0 = ks * p.klen;
  int kend = k0 + p.klen; if (kend > p.K) kend = p.K;
  const __hip_bfloat16* A  = p.A  + (long long)(z/p.aIn)*p.aSO + (long long)(z%p.aIn)*p.aSI;
  const __hip_bfloat16* Bm = p.Bm + (long long)(z/p.bIn)*p.bSO + (long long)(z%p.bIn)*p.bSI;
  long long cOff = (long long)(z/p.cIn)*p.cSO + (long long)(z%p.cIn)*p.cSI;
  int rowBase = blockIdx.y*128, colBase = blockIdx.x*BN;
  int t = threadIdx.x, lane = t & 63;
  int wv = __builtin_amdgcn_readfirstlane(t >> 6);
  int lm = lane & 15, lq = lane >> 4;
  int dr = lane >> 3, dc = lane & 7;          // DMA: row-in-group / chunk slot
  constexpr int NF = (BN == 128) ? 4 : 2;
  int wm = (wv >> 1) * 64;
  int wn = (BN == 128) ? (wv & 1) * 64 : (wv & 1) * 32;
  float4_t acc[4][NF];
  #pragma unroll
  for (int mi = 0; mi < 4; mi++)
    #pragma unroll
    for (int nf = 0; nf < NF; nf++) acc[mi][nf] = (float4_t)0.f;

  for (int kb = k0; kb < kend; kb += 64){
    // --- A: 16 wave-DMAs of 1KB (4 per wave); XOR-swizzled chunk fetch
    #pragma unroll
    for (int d = 0; d < 4; d++){
      int rg = wv*4 + d;                       // row-group 0..15
      int row = rg*8 + dr;
      int cc = dc ^ (row & 7);
      gl_lds16(A + (long long)(rowBase + row)*p.lda + kb + cc*8, &As[rg*8*64]);
    }
    // --- B: BN/8 row-groups
    #pragma unroll
    for (int d = 0; d < BN/32; d++){
      int rg = wv*(BN/32) + d;
      int row = rg*8 + dr;
      int cc = dc ^ (row & 7);
      gl_lds16(Bm + (long long)(colBase + row)*p.ldb + kb + cc*8, &Bs[rg*8*64]);
    }
    __syncthreads();
    short8_t af[2][4]; short8_t bfv[2][NF];
    #pragma unroll
    for (int ks2 = 0; ks2 < 2; ks2++){
      #pragma unroll
      for (int mi = 0; mi < 4; mi++){
        int r = wm + mi*16 + lm;
        int s = (ks2*4 + lq) ^ (r & 7);
        af[ks2][mi] = *(const short8_t*)&As[r*64 + s*8];
      }
      #pragma unroll
      for (int nf = 0; nf < NF; nf++){
        int r = wn + nf*16 + lm;
        int s = (ks2*4 + lq) ^ (r & 7);
        bfv[ks2][nf] = *(const short8_t*)&Bs[r*64 + s*8];
      }
    }
    #pragma unroll
    for (int ks2 = 0; ks2 < 2; ks2++)
      #pragma unroll
      for (int mi = 0; mi < 4; mi++)
        #pragma unroll
        for (int nf = 0; nf < NF; nf++)
          acc[mi][nf] = __builtin_amdgcn_mfma_f32_16x16x32_bf16(af[ks2][mi], bfv[ks2][nf], acc[mi][nf], 0, 0, 0);
    __syncthreads();
  }
  #pragma unroll
  for (int mi = 0; mi < 4; mi++){
    #pragma unroll
    for (int nf = 0; nf < NF; nf++){
      int c = colBase + wn + nf*16 + lm;
      #pragma unroll
      for (int r = 0; r < 4; r++){
        int m = rowBase + wm + mi*16 + lq*4 + r;
        if (m >= p.M) continue;
        float v = p.beta * acc[mi][nf][r];
        long long ci = cOff + (long long)m*p.ldc + c;
        if (p.ksp > 1){
          atomicAdd((float*)p.C + ci, v);
        } else {
          if (p.bias) v += p.bias[c];
          if (p.relu) v = fmaxf(v, 0.f);
          if (p.cbf) ((__hip_bfloat16*)p.C)[ci] = __float2bfloat16(v);
          else       ((float*)p.C)[ci] = v;
        }
      }
    }
  }
}

// ================= r3 split-MFMA GEMM (pinv only; fp32 io) =================
struct GP {
  const void* A; const void* Bm; void* C; const float* bias;
  int M, N, K, lda, ldb, ldc;
  long long aSO, aSI; int aIn, abf;
  long long bSO, bSI; int bIn, bbf, bt;
  long long cSO, cSI; int cIn, cbf;
  float alpha, beta; int relu, ksp, klen;
};

__global__ __launch_bounds__(256) void gemm_mfma_split(GP p){
  constexpr int LDW = 40;
  __shared__ __align__(16) ushort As[2*64*LDW];
  __shared__ __align__(16) ushort Bs[2*64*LDW];
  int z = blockIdx.z;
  long long aOff = (long long)(z/p.aIn)*p.aSO + (long long)(z%p.aIn)*p.aSI;
  long long bOff = (long long)(z/p.bIn)*p.bSO + (long long)(z%p.bIn)*p.bSI;
  long long cOff = (long long)(z/p.cIn)*p.cSO + (long long)(z%p.cIn)*p.cSI;
  int rowBase = blockIdx.y * 64, colBase = blockIdx.x * 64;
  int t = threadIdx.x, wave = t >> 6, lane = t & 63;
  int lm = lane & 15, lq = lane >> 4;
  float4_t acc[4];
  #pragma unroll
  for (int nf = 0; nf < 4; nf++) acc[nf] = (float4_t)0.f;
  int smr = t >> 2, skk = (t & 3) * 8;
  for (int kb = 0; kb < p.K; kb += 32){
    {
      int gm = rowBase + smr;
      bool ok = gm < p.M;
      float v[8];
      #pragma unroll
      for (int j = 0; j < 8; j++)
        v[j] = ok ? gload(p.A, p.abf, aOff + (long long)gm*p.lda + kb + skk + j) : 0.f;
      short8_t hv, lv;
      #pragma unroll
      for (int j = 0; j < 8; j++){
        ushort h = f2b(v[j]); hv[j] = (short)h; lv[j] = (short)f2b(v[j] - b2f(h));
      }
      *(short8_t*)&As[smr*LDW + skk] = hv;
      *(short8_t*)&As[64*LDW + smr*LDW + skk] = lv;
    }
    {
      int bk = t >> 3, n0 = (t & 7) * 8;
      #pragma unroll
      for (int j = 0; j < 8; j++){
        float v = gload(p.Bm, p.bbf, bOff + (long long)(kb + bk)*p.ldb + colBase + n0 + j);
        ushort h = f2b(v);
        Bs[(n0 + j)*LDW + bk] = h;
        Bs[64*LDW + (n0 + j)*LDW + bk] = f2b(v - b2f(h));
      }
    }
    __syncthreads();
    {
      short8_t a  = *(const short8_t*)&As[(wave*16 + lm)*LDW + lq*8];
      short8_t al = *(const short8_t*)&As[64*LDW + (wave*16 + lm)*LDW + lq*8];
      #pragma unroll
      for (int nf = 0; nf < 4; nf++){
        short8_t b  = *(const short8_t*)&Bs[(nf*16 + lm)*LDW + lq*8];
        short8_t bl = *(const short8_t*)&Bs[64*LDW + (nf*16 + lm)*LDW + lq*8];
        acc[nf] = __builtin_amdgcn_mfma_f32_16x16x32_bf16(a,  b,  acc[nf], 0, 0, 0);
        acc[nf] = __builtin_amdgcn_mfma_f32_16x16x32_bf16(a,  bl, acc[nf], 0, 0, 0);
        acc[nf] = __builtin_amdgcn_mfma_f32_16x16x32_bf16(al, b,  acc[nf], 0, 0, 0);
      }
    }
    __syncthreads();
  }
  #pragma unroll
  for (int nf = 0; nf < 4; nf++){
    int c = colBase + nf*16 + lm;
    if (c >= p.N) continue;
    #pragma unroll
    for (int r = 0; r < 4; r++){
      int m = rowBase + wave*16 + lq*4 + r;
      if (m >= p.M) continue;
      float v = p.beta * acc[nf][r];
      if (p.alpha != 0.f && m == c) v += p.alpha;
      ((float*)p.C)[cOff + (long long)m * p.ldc + c] = v;
    }
  }
}

// ============================= softmax ====================================
template<int LEN>
__global__ __launch_bounds__(256) void softmax_rows(float* S){
  constexpr int VPT = LEN / 256;
  float* p = S + (long long)blockIdx.x * LEN;
  int t = threadIdx.x;
  float v[VPT]; float m = -1e30f;
  #pragma unroll
  for (int q = 0; q < VPT; q++){ v[q] = p[t + 256*q]; m = fmaxf(m, v[q]); }
  __shared__ float red[256];
  red[t] = m; __syncthreads();
  for (int s = 128; s; s >>= 1){ if (t < s) red[t] = fmaxf(red[t], red[t+s]); __syncthreads(); }
  m = red[0]; __syncthreads();
  float sum = 0.f;
  #pragma unroll
  for (int q = 0; q < VPT; q++){ v[q] = __expf(v[q] - m); sum += v[q]; }
  red[t] = sum; __syncthreads();
  for (int s = 128; s; s >>= 1){ if (t < s) red[t] += red[t+s]; __syncthreads(); }
  float inv = 1.f / red[0];
  #pragma unroll
  for (int q = 0; q < VPT; q++) p[t + 256*q] = v[q] * inv;
}

template<int LEN>
__global__ __launch_bounds__(256) void softmax_rows_b(__hip_bfloat16* S){
  constexpr int VPT = LEN / 256;
  __hip_bfloat16* p = S + (long long)blockIdx.x * LEN;
  int t = threadIdx.x;
  float v[VPT]; float m = -1e30f;
  #pragma unroll
  for (int q = 0; q < VPT; q++){ v[q] = __bfloat162float(p[t + 256*q]); m = fmaxf(m, v[q]); }
  __shared__ float red[256];
  red[t] = m; __syncthreads();
  for (int s = 128; s; s >>= 1){ if (t < s) red[t] = fmaxf(red[t], red[t+s]); __syncthreads(); }
  m = red[0]; __syncthreads();
  float sum = 0.f;
  #pragma unroll
  for (int q = 0; q < VPT; q++){ v[q] = __expf(v[q] - m); sum += v[q]; }
  red[t] = sum; __syncthreads();
  for (int s = 128; s; s >>= 1){ if (t < s) red[t] += red[t+s]; __syncthreads(); }
  float inv = 1.f / red[0];
  #pragma unroll
  for (int q = 0; q < VPT; q++) p[t + 256*q] = __float2bfloat16(v[q] * inv);
}

// ============================ LN / misc ===================================
__global__ __launch_bounds__(256) void ln_pad(const float* H, __hip_bfloat16* X,
                                              const float* g, const float* bb){
  int p = blockIdx.x, b = blockIdx.y, t = threadIdx.x;
  __hip_bfloat16* xo = X + ((long long)b * NPAD + p) * D_;
  if (p < PADF){ xo[t] = __float2bfloat16(0.f); xo[t + 256] = __float2bfloat16(0.f); return; }
  const float* hi = H + ((long long)b * NTOK + (p - PADF)) * D_;
  float x0 = hi[t], x1 = hi[t + 256];
  __shared__ float r1[256], r2[256];
  r1[t] = x0 + x1; r2[t] = x0*x0 + x1*x1;
  __syncthreads();
  for (int s = 128; s; s >>= 1){ if (t < s){ r1[t] += r1[t+s]; r2[t] += r2[t+s]; } __syncthreads(); }
  float mu = r1[0] * (1.f / D_);
  float var = r2[0] * (1.f / D_) - mu*mu;
  float rs = rsqrtf(var + 1e-5f);
  xo[t]       = __float2bfloat16((x0 - mu) * rs * g[t]       + bb[t]);
  xo[t + 256] = __float2bfloat16((x1 - mu) * rs * g[t + 256] + bb[t + 256]);
}

__global__ __launch_bounds__(256) void final_ln(const float* H, const float* g,
                                                const float* bb, float* out){
  int b = blockIdx.x, t = threadIdx.x;
  const float* hi = H + (long long)b * NTOK * D_;
  float x0 = hi[t], x1 = hi[t + 256];
  __shared__ float r1[256], r2[256];
  r1[t] = x0 + x1; r2[t] = x0*x0 + x1*x1;
  __syncthreads();
  for (int s = 128; s; s >>= 1){ if (t < s){ r1[t] += r1[t+s]; r2[t] += r2[t+s]; } __syncthreads(); }
  float mu = r1[0] * (1.f / D_);
  float var = r2[0] * (1.f / D_) - mu*mu;
  float rs = rsqrtf(var + 1e-5f);
  out[b*D_ + t]       = (x0 - mu) * rs * g[t]       + bb[t];
  out[b*D_ + t + 256] = (x1 - mu) * rs * g[t + 256] + bb[t + 256];
}

__global__ __launch_bounds__(256) void build_h(const float* h0, const float* cls, float* H){
  int tpos = blockIdx.x, b = blockIdx.y, t = threadIdx.x;
  float* dst = H + ((long long)b * NTOK + tpos) * D_;
  if (tpos == 0){ dst[t] = cls[t]; dst[t + 256] = cls[t + 256]; return; }
  int i = tpos - 1, src;
  if (i < 10)        src = i;
  else if (i < 179){ int j = i - 10;  src = 10  + (j < 160  ? j : j - 160);  }
  else             { int j = i - 179; src = 170 + (j < 6000 ? j : j - 6000); }
  const float* s = h0 + ((long long)b * N0 + src) * D_;
  dst[t] = s[t]; dst[t + 256] = s[t + 256];
}

// x fp32 [24680][768] -> bf16 [24704][768], pad rows zero
__global__ __launch_bounds__(256) void cvt_pad_x(const float* x, __hip_bfloat16* Xb){
  int row = blockIdx.x, t = threadIdx.x;
  __hip_bfloat16* o = Xb + (long long)row * 768;
  if (row >= B_*N0){ o[t] = __float2bfloat16(0.f); o[t+256] = __float2bfloat16(0.f); o[t+512] = __float2bfloat16(0.f); return; }
  const float* s = x + (long long)row * 768;
  o[t]     = __float2bfloat16(s[t]);
  o[t+256] = __float2bfloat16(s[t+256]);
  o[t+512] = __float2bfloat16(s[t+512]);
}

__global__ __launch_bounds__(256) void cvt_f2bk(const float* in, __hip_bfloat16* o, int n){
  int i = blockIdx.x*256 + threadIdx.x; if (i < n) o[i] = __float2bfloat16(in[i]);
}

// generic transpose+cvt: in[z][R][C] (ld=ldin, fp32 or bf16, head-view strides)
// -> out bf16 [z][C][R]
__global__ __launch_bounds__(256) void tr_cvt(const void* in, int inbf, int ldin,
    long long iSO, long long iSI, int iIn, __hip_bfloat16* outp, long long oSO,
    int R, int C){
  __shared__ float sm[32][33];
  int z = blockIdx.z;
  long long ib = (long long)(z/iIn)*iSO + (long long)(z%iIn)*iSI;
  int r0 = blockIdx.y*32, c0 = blockIdx.x*32;
  int tx = threadIdx.x & 31, ty = threadIdx.x >> 5;
  for (int rr = ty; rr < 32; rr += 8)
    sm[rr][tx] = gload(in, inbf, ib + (long long)(r0+rr)*ldin + c0 + tx);
  __syncthreads();
  for (int cc = ty; cc < 32; cc += 8)
    outp[z*oSO + (long long)(c0+cc)*R + r0 + tx] = __float2bfloat16(sm[tx][cc]);
}

__global__ __launch_bounds__(64) void landmarks(const __hip_bfloat16* QKV,
                                                __hip_bfloat16* QL, __hip_bfloat16* KL){
  int j = blockIdx.x, z = blockIdx.y, d = threadIdx.x;
  int b = z >> 3, h = z & 7;
  const __hip_bfloat16* base = QKV + ((long long)b * NPAD + j*25) * 1536 + h*64 + d;
  float q = 0.f, k = 0.f;
  #pragma unroll 1
  for (int i = 0; i < 25; i++){
    q += __bfloat162float(base[(long long)i*1536]);
    k += __bfloat162float(base[(long long)i*1536 + 512]);
  }
  QL[((long long)z * NLM + j) * 64 + d] = __float2bfloat16(q * (1.f/25.f) * 0.125f);
  KL[((long long)z * NLM + j) * 64 + d] = __float2bfloat16(k * (1.f/25.f));
}

__global__ void init_sc(float* sc){ sc[0] = 0.f; sc[1] = 0.f; }
__global__ __launch_bounds__(256) void fillz(float* p, int n){
  int i = blockIdx.x*256 + threadIdx.x; if (i < n) p[i] = 0.f;
}

__global__ __launch_bounds__(256) void colsum_max(const float* A2, float* sc){
  int z = blockIdx.x, t = threadIdx.x;
  const float* a = A2 + (long long)z * 65536;
  float s = 0.f;
  for (int i = 0; i < 256; i++) s += fabsf(a[i*256 + t]);
  __shared__ float red[256];
  red[t] = s; __syncthreads();
  for (int st = 128; st; st >>= 1){ if (t < st) red[t] = fmaxf(red[t], red[t+st]); __syncthreads(); }
  if (t == 0) atomicMaxF(sc + 0, red[0]);
}

__global__ __launch_bounds__(256) void rowsum_max(const float* A2, float* sc){
  int z = blockIdx.x, t = threadIdx.x, w = t >> 6, l = t & 63;
  const float* a = A2 + (long long)z * 65536;
  float mx = 0.f;
  for (int i = w*64; i < (w+1)*64; i++){
    float s = fabsf(a[i*256 + l]) + fabsf(a[i*256 + l + 64])
            + fabsf(a[i*256 + l + 128]) + fabsf(a[i*256 + l + 192]);
    for (int m = 32; m; m >>= 1) s += __shfl_xor(s, m);
    mx = fmaxf(mx, s);
  }
  __shared__ float red[4];
  if (l == 0) red[w] = mx;
  __syncthreads();
  if (t == 0) atomicMaxF(sc + 1, fmaxf(fmaxf(red[0], red[1]), fmaxf(red[2], red[3])));
}

__global__ __launch_bounds__(256) void zinit(const float* A2, float* Z, const float* sc){
  int j = blockIdx.x, z = blockIdx.y, i = threadIdx.x;
  float inv = 1.f / (sc[0] * sc[1]);
  Z[(long long)z*65536 + j*256 + i] = A2[(long long)z*65536 + i*256 + j] * inv;
}

__global__ __launch_bounds__(256) void diag7(const float* AZ, float* W1){
  int r = blockIdx.x, z = blockIdx.y, j = threadIdx.x;
  float v = -AZ[(long long)z*65536 + r*256 + j];
  if (r == j) v += 7.f;
  W1[(long long)z*65536 + r*256 + j] = v;
}

// OUT1 fp32 + depthwise conv of V -> OUT1b bf16
__global__ __launch_bounds__(512) void dwconv_cvt(const __hip_bfloat16* QKV, const float* rw,
                                                  const float* OUT1, __hip_bfloat16* OUT1b){
  int n = blockIdx.x, b = blockIdx.y, t = threadIdx.x;
  int h = t >> 6;
  float acc = 0.f;
  #pragma unroll 1
  for (int k = 0; k < 33; k++){
    int nn = n + k - 16;
    if (nn >= 0 && nn < NPAD)
      acc += rw[h*33 + k] * __bfloat162float(QKV[((long long)b * NPAD + nn) * 1536 + 1024 + t]);
  }
  long long idx = ((long long)b * NPAD + n) * D_ + t;
  OUT1b[idx] = __float2bfloat16(OUT1[idx] + acc);
}

__global__ __launch_bounds__(512) void resid_add(float* H, const float* O2, const float* ob){
  int i = blockIdx.x, b = blockIdx.y, t = threadIdx.x;
  H[((long long)b * NTOK + i) * D_ + t] +=
      O2[((long long)b * NPAD + i + PADF) * D_ + t] + ob[t];
}

// ------------------------------ PPEG (r3) ---------------------------------
__global__ __launch_bounds__(256) void transpose_w(const float* w, float* wt, int KK){
  int i = blockIdx.x*256 + threadIdx.x;
  if (i < 512*KK){ int ch = i / KK, k = i - ch*KK; wt[(long long)k*512 + ch] = w[i]; }
}

__global__ __launch_bounds__(256) void ppeg_tiled(const float* H, float* P,
    const float* t7, const float* t5, const float* t3,
    const float* b7, const float* b5, const float* b3,
    int base, int W, int tilesX){
  __shared__ float smem[196*64];
  int ty0 = (blockIdx.x / tilesX) * 8, tx0 = (blockIdx.x % tilesX) * 8;
  int c0 = blockIdx.y * 64, b = blockIdx.z;
  int t = threadIdx.x, ch = t & 63, pr = t >> 6;
  const float* Hb = H + ((long long)b * NTOK + base) * D_ + c0 + ch;
  for (int i = pr; i < 196; i += 4){
    int py = i / 14, px = i - py*14;
    int y = ty0 + py - 3, x = tx0 + px - 3;
    smem[i*64 + ch] = (y >= 0 && y < W && x >= 0 && x < W)
                      ? Hb[(long long)(y*W + x) * D_] : 0.f;
  }
  __syncthreads();
  float acc[16];
  float bsum = b7[c0+ch] + b5[c0+ch] + b3[c0+ch];
  #pragma unroll
  for (int o = 0; o < 16; o++){
    int y = o >> 1, x = pr + (o & 1)*4;
    acc[o] = smem[((y+3)*14 + (x+3))*64 + ch] + bsum;
  }
  for (int ky = 0; ky < 7; ky++)
    for (int kx = 0; kx < 7; kx++){
      float wv = t7[(ky*7 + kx)*512 + c0 + ch];
      #pragma unroll
      for (int o = 0; o < 16; o++){
        int y = o >> 1, x = pr + (o & 1)*4;
        acc[o] += wv * smem[((y+ky)*14 + (x+kx))*64 + ch];
      }
    }
  for (int ky = 0; ky < 5; ky++)
    for (int kx = 0; kx < 5; kx++){
      float wv = t5[(ky*5 + kx)*512 + c0 + ch];
      #pragma unroll
      for (int o = 0; o < 16; o++){
        int y = o >> 1, x = pr + (o & 1)*4;
        acc[o] += wv * smem[((y+1+ky)*14 + (x+1+kx))*64 + ch];
      }
    }
  for (int ky = 0; ky < 3; ky++)
    for (int kx = 0; kx < 3; kx++){
      float wv = t3[(ky*3 + kx)*512 + c0 + ch];
      #pragma unroll
      for (int o = 0; o < 16; o++){
        int y = o >> 1, x = pr + (o & 1)*4;
        acc[o] += wv * smem[((y+2+ky)*14 + (x+2+kx))*64 + ch];
      }
    }
  #pragma unroll
  for (int o = 0; o < 16; o++){
    int y = ty0 + (o >> 1), x = tx0 + pr + (o & 1)*4;
    if (y < W && x < W)
      P[((long long)b * W * W + y*W + x) * D_ + c0 + ch] = acc[o];
  }
}

__global__ __launch_bounds__(512) void ppeg_copy(float* H, const float* P, int base, int W){
  int pos = blockIdx.x, b = blockIdx.y, t = threadIdx.x;
  H[((long long)b * NTOK + base + pos) * D_ + t] = P[((long long)b * W * W + pos) * D_ + t];
}

// ============================== host side =================================
static void gemmB(hipStream_t st, int BN,
                  const __hip_bfloat16* A, int lda, long long aSO, long long aSI, int aIn,
                  const __hip_bfloat16* Bm, int ldb, long long bSO, long long bSI, int bIn,
                  void* C, int ldc, long long cSO, long long cSI, int cIn, int cbf,
                  int M, int N, int K, int batch,
                  const float* bias, float beta, int relu, int ksp = 1, int klen = 0){
  GB p;
  p.A = A; p.Bm = Bm; p.C = C; p.bias = bias;
  p.M = M; p.N = N; p.K = K; p.lda = lda; p.ldb = ldb; p.ldc = ldc;
  p.aSO = aSO; p.aSI = aSI; p.aIn = aIn;
  p.bSO = bSO; p.bSI = bSI; p.bIn = bIn;
  p.cSO = cSO; p.cSI = cSI; p.cIn = cIn; p.cbf = cbf;
  p.beta = beta; p.relu = relu; p.ksp = ksp; p.klen = (klen > 0) ? klen : K;
  dim3 g(N/BN, (M + 127)/128, batch * ksp), b(256);
  if (BN == 128) gemm_bt<128><<<g, b, 0, st>>>(p);
  else           gemm_bt<64><<<g, b, 0, st>>>(p);
}

static void gemmP(hipStream_t st, const float* A, const float* Bm, float* C,
                  float alpha, float beta){
  GP p;
  p.A = A; p.Bm = Bm; p.C = C; p.bias = nullptr;
  p.M = 256; p.N = 256; p.K = 256; p.lda = 256; p.ldb = 256; p.ldc = 256;
  p.aSO = 65536; p.aSI = 0; p.aIn = 1; p.abf = 0;
  p.bSO = 65536; p.bSI = 0; p.bIn = 1; p.bbf = 0; p.bt = 0;
  p.cSO = 65536; p.cSI = 0; p.cIn = 1; p.cbf = 0;
  p.alpha = alpha; p.beta = beta; p.relu = 0; p.ksp = 1; p.klen = 256;
  dim3 g(4, 4, 32), b(256);
  gemm_mfma_split<<<g, b, 0, st>>>(p);
}

extern "C" void kernel_launch(void* const* d_in, const int* in_sizes, int n_in,
                              void* d_out, int out_size, void* d_ws, size_t ws_size,
                              hipStream_t stream){
  const float* x      = (const float*)d_in[0];
  const float* fc1_w  = (const float*)d_in[1];
  const float* fc1_b  = (const float*)d_in[2];
  const float* cls    = (const float*)d_in[3];
  const float* l1_ng  = (const float*)d_in[4];
  const float* l1_nb  = (const float*)d_in[5];
  const float* l1_qkv = (const float*)d_in[6];
  const float* l1_ow  = (const float*)d_in[7];
  const float* l1_ob  = (const float*)d_in[8];
  const float* l1_rw  = (const float*)d_in[9];
  const float* ct_w7  = (const float*)d_in[10];
  const float* ct_b7  = (const float*)d_in[11];
  const float* ct_w5  = (const float*)d_in[12];
  const float* ct_b5  = (const float*)d_in[13];
  const float* ct_w3  = (const float*)d_in[14];
  const float* ct_b3  = (const float*)d_in[15];
  const float* pt_w7  = (const float*)d_in[16];
  const float* pt_b7  = (const float*)d_in[17];
  const float* pt_w5  = (const float*)d_in[18];
  const float* pt_b5  = (const float*)d_in[19];
  const float* pt_w3  = (const float*)d_in[20];
  const float* pt_b3  = (const float*)d_in[21];
  const float* l2_ng  = (const float*)d_in[22];
  const float* l2_nb  = (const float*)d_in[23];
  const float* l2_qkv = (const float*)d_in[24];
  const float* l2_ow  = (const float*)d_in[25];
  const float* l2_ob  = (const float*)d_in[26];
  const float* l2_rw  = (const float*)d_in[27];
  const float* nrm_g  = (const float*)d_in[28];
  const float* nrm_b  = (const float*)d_in[29];
  float* out = (float*)d_out;

  // ---- workspace layout (float units); total ~224 MB ----
  float* ws    = (float*)d_ws;
  float* H     = ws;                      // 12,828,672
  float* BUF   = H + 12828672;            // 13,107,200 : h0 f32 / XLNb bf16 / pinv f32 / VT bf16 / OUT1 f32
  float* QKVr  = BUF + 13107200;          // 19,660,800 : Xb bf16 / QKV bf16 / PROJ f32
  float* SIMCf = QKVr + 19660800;         //  6,553,600 : SIMCb bf16 chunks / OUT1b bf16
  float* QLf   = SIMCf + 6553600;         //    262,144 : QLb bf16 (32x256x64)
  float* KLf   = QLf + 262144;            //    262,144 : KLb bf16
  float* AV    = KLf + 262144;            //    524,288 : f32
  float* AVTf  = AV + 524288;             //    262,144 : AVT bf16
  float* ZVf   = AVTf + 262144;           //    262,144 : Zv bf16 (32x256x64)
  float* ZVTf  = ZVf + 262144;            //    262,144 : ZVT bf16
  float* ZCf   = ZVTf + 262144;           //  1,048,576 : Zcb bf16 (32x256x256)
  float* WQf   = ZCf + 1048576;           //    393,216 : qkvT bf16 [1536][512]
  float* WFf   = WQf + 393216;            //    196,608 : fc1T bf16 [512][768]
  float* WOf   = WFf + 196608;            //    131,072 : outT bf16 [512][512]
  float* PWT   = WOf + 131072;            //     84,992 : ppeg transposed f32
  float* SC    = PWT + 84992;             //          2
  float* tc7 = PWT, *tc5 = tc7 + 49*512, *tc3 = tc5 + 25*512;
  float* tp7 = tc3 + 9*512, *tp5 = tp7 + 49*512, *tp3 = tp5 + 25*512;

  // pinv scratch inside BUF
  float* A2 = BUF;
  float* Zb = BUF + 2097152;
  float* Z2 = BUF + 4194304;
  float* AZ = BUF + 6291456;
  float* W1 = BUF + 8388608;
  float* W2 = BUF + 10485760;

  __hip_bfloat16* Xb    = (__hip_bfloat16*)QKVr;     // [24704][768]
  __hip_bfloat16* QKV   = (__hip_bfloat16*)QKVr;     // [25600][1536]
  float*          PROJ  = QKVr;                      // f32 after qkv dead
  __hip_bfloat16* XLNb  = (__hip_bfloat16*)BUF;      // [25600][512]
  __hip_bfloat16* VT    = (__hip_bfloat16*)BUF;      // [32][64][6400] (pinv dead)
  __hip_bfloat16* SIMCb = (__hip_bfloat16*)SIMCf;    // 4bh x 256x6400 / OUT1b [25600][512]
  __hip_bfloat16* OUT1b = (__hip_bfloat16*)SIMCf;
  __hip_bfloat16* QLb   = (__hip_bfloat16*)QLf;
  __hip_bfloat16* KLb   = (__hip_bfloat16*)KLf;
  __hip_bfloat16* AVT   = (__hip_bfloat16*)AVTf;
  __hip_bfloat16* Zvb   = (__hip_bfloat16*)ZVf;
  __hip_bfloat16* ZVT   = (__hip_bfloat16*)ZVTf;
  __hip_bfloat16* Zcb   = (__hip_bfloat16*)ZCf;
  __hip_bfloat16* WqkvT = (__hip_bfloat16*)WQf;
  __hip_bfloat16* Wfc1T = (__hip_bfloat16*)WFf;
  __hip_bfloat16* WoutT = (__hip_bfloat16*)WOf;

  const long long QE = (long long)NPAD * 1536;

  // ---- one-time weight prep
  transpose_w<<<(512*49+255)/256, 256, 0, stream>>>(ct_w7, tc7, 49);
  transpose_w<<<(512*25+255)/256, 256, 0, stream>>>(ct_w5, tc5, 25);
  transpose_w<<<(512* 9+255)/256, 256, 0, stream>>>(ct_w3, tc3,  9);
  transpose_w<<<(512*49+255)/256, 256, 0, stream>>>(pt_w7, tp7, 49);
  transpose_w<<<(512*25+255)/256, 256, 0, stream>>>(pt_w5, tp5, 25);
  transpose_w<<<(512* 9+255)/256, 256, 0, stream>>>(pt_w3, tp3,  9);
  tr_cvt<<<dim3(512/32, 768/32, 1), 256, 0, stream>>>(fc1_w, 0, 512, 0,0,1, Wfc1T, 0, 768, 512);

  // ---- fc1 + relu -> h0 (BUF f32); gather into H
  cvt_pad_x<<<MFC1, 256, 0, stream>>>(x, Xb);
  gemmB(stream, 128, Xb, 768, 0,0,1, Wfc1T, 768, 0,0,1, BUF, 512, 0,0,1,0,
        MFC1, 512, 768, 1, fc1_b, 1.f, 1);
  build_h<<<dim3(NTOK, B_), 256, 0, stream>>>(BUF, cls, H);

  auto attn_layer = [&](const float* ng, const float* nb, const float* qkvw,
                        const float* outw, const float* outb, const float* resw){
    // per-layer weight prep
    tr_cvt<<<dim3(1536/32, 512/32, 1), 256, 0, stream>>>(qkvw, 0, 1536, 0,0,1, WqkvT, 0, 512, 1536);
    tr_cvt<<<dim3(512/32, 512/32, 1), 256, 0, stream>>>(outw, 0, 512, 0,0,1, WoutT, 0, 512, 512);
    // LN -> bf16, qkv -> bf16 QKV
    ln_pad<<<dim3(NPAD, B_), 256, 0, stream>>>(H, XLNb, ng, nb);
    gemmB(stream, 128, XLNb, 512, 0,0,1, WqkvT, 512, 0,0,1, QKV, 1536, 0,0,1,1,
          B_*NPAD, 1536, 512, 1, nullptr, 1.f, 0);
    landmarks<<<dim3(NLM, B_*NH), 64, 0, stream>>>(QKV, QLb, KLb);
    // a2 = softmax(q_l @ k_l^T) f32
    gemmB(stream, 128, QLb, 64, 16384,0,1, KLb, 64, 16384,0,1, A2, 256, 65536,0,1,0,
          256, 256, 64, 32, nullptr, 1.f, 0);
    softmax_rows<256><<<B_*NH*NLM, 256, 0, stream>>>(A2);
    // pinv (fp32-accurate split MFMA)
    init_sc<<<1, 1, 0, stream>>>(SC);
    colsum_max<<<B_*NH, 256, 0, stream>>>(A2, SC);
    rowsum_max<<<B_*NH, 256, 0, stream>>>(A2, SC);
    zinit<<<dim3(256, B_*NH), 256, 0, stream>>>(A2, Zb, SC);
    float *Zc = Zb, *Zn = Z2;
    for (int it = 0; it < 6; it++){
      gemmP(stream, A2, Zc, AZ, 0.f, 1.f);
      diag7<<<dim3(256, B_*NH), 256, 0, stream>>>(AZ, W1);
      gemmP(stream, AZ, W1, W2, 15.f, -1.f);
      gemmP(stream, AZ, W2, W1, 13.f, -1.f);
      gemmP(stream, Zc, W1, Zn, 0.f, 0.25f);
      float* tmp = Zc; Zc = Zn; Zn = tmp;
    }
    cvt_f2bk<<<8192, 256, 0, stream>>>(Zc, Zcb, 2097152);
    // V^T per head into BUF (pinv scratch dead)
    tr_cvt<<<dim3(64/32, NPAD/32, 32), 256, 0, stream>>>(QKV + 1024, 1, 1536,
          QE, 64, 8, VT, (long long)64*NPAD, NPAD, 64);
    fillz<<<2048, 256, 0, stream>>>(AV, 524288);
    // sim3 -> softmax -> AV, chunked over 4 bh-groups
    for (int c = 0; c < 8; c++){
      int b = c >> 1, hh = (c & 1) * 4;
      const __hip_bfloat16* Kp = QKV + (long long)b*QE + hh*64 + 512;
      gemmB(stream, 128, QLb + (long long)4*c*16384, 64, 16384,0,1,
            Kp, 1536, 0,64,4,
            SIMCb, NPAD, (long long)256*NPAD,0,1,1,
            256, NPAD, 64, 4, nullptr, 1.f, 0);
      softmax_rows_b<NPAD><<<4*NLM, 256, 0, stream>>>(SIMCb);
      gemmB(stream, 64, SIMCb, NPAD, (long long)256*NPAD,0,1,
            VT + (long long)4*c*64*NPAD, NPAD, (long long)64*NPAD,0,1,
            AV + (long long)4*c*16384, 64, 16384,0,1,0,
            256, 64, NPAD, 4, nullptr, 1.f, 0, 10, 640);     // K-split atomic
    }
    // AV^T, ZV = Zc@AV (bf16 out), ZV^T
    tr_cvt<<<dim3(64/32, 256/32, 32), 256, 0, stream>>>(AV, 0, 64, 16384,0,1,
          AVT, 16384, 256, 64);
    gemmB(stream, 64, Zcb, 256, 65536,0,1, AVT, 256, 16384,0,1,
          Zvb, 64, 16384,0,1,1, 256, 64, 256, 32, nullptr, 1.f, 0);
    tr_cvt<<<dim3(64/32, 256/32, 32), 256, 0, stream>>>(Zvb, 1, 64, 16384,0,1,
          ZVT, 16384, 256, 64);
    // sim1 -> softmax -> OUT1 (f32 into BUF), chunked
    for (int c = 0; c < 8; c++){
      int b = c >> 1, hh = (c & 1) * 4;
      const __hip_bfloat16* Qp = QKV + (long long)b*QE + hh*64;
      gemmB(stream, 128, Qp, 1536, 0,64,4,
            KLb + (long long)4*c*16384, 64, 16384,0,1,
            SIMCb, 256, (long long)NPAD*256,0,1,1,
            NPAD, 256, 64, 4, nullptr, 0.125f, 0);
      softmax_rows_b<256><<<4*NPAD, 256, 0, stream>>>(SIMCb);
      gemmB(stream, 64, SIMCb, 256, (long long)NPAD*256,0,1,
            ZVT + (long long)4*c*16384, 256, 16384,0,1,
            BUF + (long long)b*NPAD*512 + hh*64, 512, 0,64,4,0,
            NPAD, 64, 256, 4, nullptr, 1.f, 0);
    }
    // + depthwise conv residual -> bf16, projection, residual add
    dwconv_cvt<<<dim3(NPAD, B_), 512, 0, stream>>>(QKV, resw, BUF, OUT1b);
    gemmB(stream, 128, OUT1b, 512, 0,0,1, WoutT, 512, 0,0,1, PROJ, 512, 0,0,1,0,
          B_*NPAD, 512, 512, 1, nullptr, 1.f, 0);
    resid_add<<<dim3(NTOK, B_), 512, 0, stream>>>(H, PROJ, outb);
  };

  // ---- layer 1
  attn_layer(l1_ng, l1_nb, l1_qkv, l1_ow, l1_ob, l1_rw);

  // ---- PPEG
  ppeg_tiled<<<dim3(4, 8, B_), 256, 0, stream>>>(H, BUF, tc7, tc5, tc3, ct_b7, ct_b5, ct_b3, 11, 13, 2);
  ppeg_copy<<<dim3(169, B_), 512, 0, stream>>>(H, BUF, 11, 13);
  ppeg_tiled<<<dim3(100, 8, B_), 256, 0, stream>>>(H, BUF, tp7, tp5, tp3, pt_b7, pt_b5, pt_b3, 180, 78, 10);
  ppeg_copy<<<dim3(6084, B_), 512, 0, stream>>>(H, BUF, 180, 78);

  // ---- layer 2
  attn_layer(l2_ng, l2_nb, l2_qkv, l2_ow, l2_ob, l2_rw);

  // ---- final LN on cls token
  final_ln<<<B_, 256, 0, stream>>>(H, nrm_g, nrm_b, out);
}

// Round 5
// 3581.594 us; speedup vs baseline: 3.4054x; 1.3562x over previous
//
#include <hip/hip_runtime.h>
#include <hip/hip_bf16.h>
#include <cstdint>

#define B_   4
#define NTOK 6264
#define NPAD 6400
#define D_   512
#define NH   8
#define NLM  256
#define N0   6170
#define PADF (NPAD - NTOK)   // 136
#define MFC1 24704           // B_*N0 padded to x128

typedef __attribute__((ext_vector_type(8))) short short8_t;
typedef __attribute__((ext_vector_type(4))) float float4_t;

__device__ __forceinline__ ushort f2b(float x){
  __hip_bfloat16 h = __float2bfloat16(x); return *(ushort*)&h;
}
__device__ __forceinline__ float b2f(ushort u){
  __hip_bfloat16 h = *(__hip_bfloat16*)&u; return __bfloat162float(h);
}
__device__ __forceinline__ float gload(const void* p, int bf, long long i){
  return bf ? __bfloat162float(((const __hip_bfloat16*)p)[i]) : ((const float*)p)[i];
}
__device__ __forceinline__ void atomicMaxF(float* a, float v){
  atomicMax((int*)a, __float_as_int(v));
}
__device__ __forceinline__ void gl_lds16(const void* g, void* l){
  __builtin_amdgcn_global_load_lds(
      (const __attribute__((address_space(1))) void*)g,
      (__attribute__((address_space(3))) void*)l, 16, 0, 0);
}

// ===================== fast bf16 NT GEMM (m97-style) ======================
// C = beta*(A@B^T) [+bias][relu]; A: MxK rm bf16, B: NxK rm bf16.
// Requires M%128==0, N%BN==0, K%64==0 (and klen%64==0 for K-split).
struct GB {
  const __hip_bfloat16* A; const __hip_bfloat16* Bm; void* C; const float* bias;
  int M, N, K, lda, ldb, ldc;
  long long aSO, aSI; int aIn;
  long long bSO, bSI; int bIn;
  long long cSO, cSI; int cIn;
  float beta; int cbf, relu, ksp, klen;
};

template<int BN>
__global__ __launch_bounds__(256) void gemm_bt(GB p){
  __shared__ __align__(16) __hip_bfloat16 As[128*64];
  __shared__ __align__(16) __hip_bfloat16 Bs[BN*64];
  int zz = blockIdx.z;
  int z = zz / p.ksp, ks = zz - z*p.ksp;
  int k0 = ks * p.klen;
  int kend = k0 + p.klen; if (kend > p.K) kend = p.K;
  const __hip_bfloat16* A  = p.A  + (long long)(z/p.aIn)*p.aSO + (long long)(z%p.aIn)*p.aSI;
  const __hip_bfloat16* Bm = p.Bm + (long long)(z/p.bIn)*p.bSO + (long long)(z%p.bIn)*p.bSI;
  long long cOff = (long long)(z/p.cIn)*p.cSO + (long long)(z%p.cIn)*p.cSI;
  int rowBase = blockIdx.y*128, colBase = blockIdx.x*BN;
  int t = threadIdx.x, lane = t & 63;
  int wv = __builtin_amdgcn_readfirstlane(t >> 6);
  int lm = lane & 15, lq = lane >> 4;
  int dr = lane >> 3, dc = lane & 7;
  constexpr int NF = (BN == 128) ? 4 : 2;
  int wm = (wv >> 1) * 64;
  int wn = (BN == 128) ? (wv & 1) * 64 : (wv & 1) * 32;
  float4_t acc[4][NF];
  #pragma unroll
  for (int mi = 0; mi < 4; mi++)
    #pragma unroll
    for (int nf = 0; nf < NF; nf++) acc[mi][nf] = (float4_t)0.f;

  for (int kb = k0; kb < kend; kb += 64){
    #pragma unroll
    for (int d = 0; d < 4; d++){
      int rg = wv*4 + d;
      int row = rg*8 + dr;
      int cc = dc ^ (row & 7);
      gl_lds16(A + (long long)(rowBase + row)*p.lda + kb + cc*8, &As[rg*8*64]);
    }
    #pragma unroll
    for (int d = 0; d < BN/32; d++){
      int rg = wv*(BN/32) + d;
      int row = rg*8 + dr;
      int cc = dc ^ (row & 7);
      gl_lds16(Bm + (long long)(colBase + row)*p.ldb + kb + cc*8, &Bs[rg*8*64]);
    }
    __syncthreads();
    short8_t af[2][4]; short8_t bfv[2][NF];
    #pragma unroll
    for (int ks2 = 0; ks2 < 2; ks2++){
      #pragma unroll
      for (int mi = 0; mi < 4; mi++){
        int r = wm + mi*16 + lm;
        int s = (ks2*4 + lq) ^ (r & 7);
        af[ks2][mi] = *(const short8_t*)&As[r*64 + s*8];
      }
      #pragma unroll
      for (int nf = 0; nf < NF; nf++){
        int r = wn + nf*16 + lm;
        int s = (ks2*4 + lq) ^ (r & 7);
        bfv[ks2][nf] = *(const short8_t*)&Bs[r*64 + s*8];
      }
    }
    #pragma unroll
    for (int ks2 = 0; ks2 < 2; ks2++)
      #pragma unroll
      for (int mi = 0; mi < 4; mi++)
        #pragma unroll
        for (int nf = 0; nf < NF; nf++)
          acc[mi][nf] = __builtin_amdgcn_mfma_f32_16x16x32_bf16(af[ks2][mi], bfv[ks2][nf], acc[mi][nf], 0, 0, 0);
    __syncthreads();
  }
  #pragma unroll
  for (int mi = 0; mi < 4; mi++){
    #pragma unroll
    for (int nf = 0; nf < NF; nf++){
      int c = colBase + wn + nf*16 + lm;
      #pragma unroll
      for (int r = 0; r < 4; r++){
        int m = rowBase + wm + mi*16 + lq*4 + r;
        if (m >= p.M) continue;
        float v = p.beta * acc[mi][nf][r];
        long long ci = cOff + (long long)m*p.ldc + c;
        if (p.ksp > 1){
          atomicAdd((float*)p.C + ci, v);
        } else {
          if (p.bias) v += p.bias[c];
          if (p.relu) v = fmaxf(v, 0.f);
          if (p.cbf) ((__hip_bfloat16*)p.C)[ci] = __float2bfloat16(v);
          else       ((float*)p.C)[ci] = v;
        }
      }
    }
  }
}

// ============== fast split (hi/lo) GEMM for pinv: 256x256x256, batch 32 ====
// A,B: bf16 hi plane + lo plane at +PS; B already transposed ([n][k]).
// outN (may be null): hi/lo planes of scale*acc at [m][c].
// outT (may be null): hi/lo planes of alphaT*(m==c) + sT*scale*acc at [c][m].
struct GS {
  const __hip_bfloat16* A; const __hip_bfloat16* B;
  __hip_bfloat16* outN; __hip_bfloat16* outT;
  long long PS;
  float scale, alphaT, sT;
};

__global__ __launch_bounds__(256) void gemm_bts(GS p){
  __shared__ __align__(16) __hip_bfloat16 Ah[128*64];
  __shared__ __align__(16) __hip_bfloat16 Al[128*64];
  __shared__ __align__(16) __hip_bfloat16 Bh[64*64];
  __shared__ __align__(16) __hip_bfloat16 Bl[64*64];
  int z = blockIdx.z;
  long long zo = (long long)z * 65536;
  const __hip_bfloat16* A = p.A + zo;
  const __hip_bfloat16* B = p.B + zo;
  int rowBase = blockIdx.y*128, colBase = blockIdx.x*64;
  int t = threadIdx.x, lane = t & 63;
  int wv = __builtin_amdgcn_readfirstlane(t >> 6);
  int lm = lane & 15, lq = lane >> 4;
  int dr = lane >> 3, dc = lane & 7;
  int wm = (wv >> 1) * 64, wn = (wv & 1) * 32;
  float4_t acc[4][2];
  #pragma unroll
  for (int mi = 0; mi < 4; mi++){ acc[mi][0] = (float4_t)0.f; acc[mi][1] = (float4_t)0.f; }

  for (int kb = 0; kb < 256; kb += 64){
    #pragma unroll
    for (int d = 0; d < 4; d++){
      int rg = wv*4 + d;
      int row = rg*8 + dr;
      int cc = dc ^ (row & 7);
      gl_lds16(A +        (long long)(rowBase + row)*256 + kb + cc*8, &Ah[rg*8*64]);
      gl_lds16(A + p.PS + (long long)(rowBase + row)*256 + kb + cc*8, &Al[rg*8*64]);
    }
    #pragma unroll
    for (int d = 0; d < 2; d++){
      int rg = wv*2 + d;
      int row = rg*8 + dr;
      int cc = dc ^ (row & 7);
      gl_lds16(B +        (long long)(colBase + row)*256 + kb + cc*8, &Bh[rg*8*64]);
      gl_lds16(B + p.PS + (long long)(colBase + row)*256 + kb + cc*8, &Bl[rg*8*64]);
    }
    __syncthreads();
    #pragma unroll
    for (int ks2 = 0; ks2 < 2; ks2++){
      short8_t ah[4], al[4], bh[2], bl[2];
      #pragma unroll
      for (int mi = 0; mi < 4; mi++){
        int r = wm + mi*16 + lm;
        int s = (ks2*4 + lq) ^ (r & 7);
        ah[mi] = *(const short8_t*)&Ah[r*64 + s*8];
        al[mi] = *(const short8_t*)&Al[r*64 + s*8];
      }
      #pragma unroll
      for (int nf = 0; nf < 2; nf++){
        int r = wn + nf*16 + lm;
        int s = (ks2*4 + lq) ^ (r & 7);
        bh[nf] = *(const short8_t*)&Bh[r*64 + s*8];
        bl[nf] = *(const short8_t*)&Bl[r*64 + s*8];
      }
      #pragma unroll
      for (int mi = 0; mi < 4; mi++)
        #pragma unroll
        for (int nf = 0; nf < 2; nf++){
          acc[mi][nf] = __builtin_amdgcn_mfma_f32_16x16x32_bf16(ah[mi], bh[nf], acc[mi][nf], 0, 0, 0);
          acc[mi][nf] = __builtin_amdgcn_mfma_f32_16x16x32_bf16(ah[mi], bl[nf], acc[mi][nf], 0, 0, 0);
          acc[mi][nf] = __builtin_amdgcn_mfma_f32_16x16x32_bf16(al[mi], bh[nf], acc[mi][nf], 0, 0, 0);
        }
    }
    __syncthreads();
  }
  #pragma unroll
  for (int mi = 0; mi < 4; mi++){
    #pragma unroll
    for (int nf = 0; nf < 2; nf++){
      int c = colBase + wn + nf*16 + lm;
      #pragma unroll
      for (int r = 0; r < 4; r++){
        int m = rowBase + wm + mi*16 + lq*4 + r;
        float v = p.scale * acc[mi][nf][r];
        if (p.outN){
          __hip_bfloat16 hi = __float2bfloat16(v);
          p.outN[zo + (long long)m*256 + c] = hi;
          p.outN[p.PS + zo + (long long)m*256 + c] = __float2bfloat16(v - __bfloat162float(hi));
        }
        if (p.outT){
          float w = p.alphaT * (m == c ? 1.f : 0.f) + p.sT * v;
          __hip_bfloat16 hi = __float2bfloat16(w);
          p.outT[zo + (long long)c*256 + m] = hi;
          p.outT[p.PS + zo + (long long)c*256 + m] = __float2bfloat16(w - __bfloat162float(hi));
        }
      }
    }
  }
}

// ============================= softmax ====================================
template<int LEN>
__global__ __launch_bounds__(256) void softmax_rows_b(__hip_bfloat16* S){
  constexpr int VPT = LEN / 256;
  __hip_bfloat16* p = S + (long long)blockIdx.x * LEN;
  int t = threadIdx.x;
  float v[VPT]; float m = -1e30f;
  #pragma unroll
  for (int q = 0; q < VPT; q++){ v[q] = __bfloat162float(p[t + 256*q]); m = fmaxf(m, v[q]); }
  __shared__ float red[256];
  red[t] = m; __syncthreads();
  for (int s = 128; s; s >>= 1){ if (t < s) red[t] = fmaxf(red[t], red[t+s]); __syncthreads(); }
  m = red[0]; __syncthreads();
  float sum = 0.f;
  #pragma unroll
  for (int q = 0; q < VPT; q++){ v[q] = __expf(v[q] - m); sum += v[q]; }
  red[t] = sum; __syncthreads();
  for (int s = 128; s; s >>= 1){ if (t < s) red[t] += red[t+s]; __syncthreads(); }
  float inv = 1.f / red[0];
  #pragma unroll
  for (int q = 0; q < VPT; q++) p[t + 256*q] = __float2bfloat16(v[q] * inv);
}

// softmax on f32 rows of 256, also emitting hi/lo bf16 planes
__global__ __launch_bounds__(256) void softmax256_split(float* S, __hip_bfloat16* P, long long PS){
  long long row = blockIdx.x;
  float* p = S + row * 256;
  int t = threadIdx.x;
  float v = p[t];
  __shared__ float red[256];
  red[t] = v; __syncthreads();
  for (int s = 128; s; s >>= 1){ if (t < s) red[t] = fmaxf(red[t], red[t+s]); __syncthreads(); }
  float m = red[0]; __syncthreads();
  float e = __expf(v - m);
  red[t] = e; __syncthreads();
  for (int s = 128; s; s >>= 1){ if (t < s) red[t] += red[t+s]; __syncthreads(); }
  float r = e / red[0];
  p[t] = r;
  __hip_bfloat16 hi = __float2bfloat16(r);
  P[row*256 + t] = hi;
  P[PS + row*256 + t] = __float2bfloat16(r - __bfloat162float(hi));
}

// ============================ LN / misc ===================================
__global__ __launch_bounds__(256) void ln_pad(const float* H, __hip_bfloat16* X,
                                              const float* g, const float* bb){
  int p = blockIdx.x, b = blockIdx.y, t = threadIdx.x;
  __hip_bfloat16* xo = X + ((long long)b * NPAD + p) * D_;
  if (p < PADF){ xo[t] = __float2bfloat16(0.f); xo[t + 256] = __float2bfloat16(0.f); return; }
  const float* hi = H + ((long long)b * NTOK + (p - PADF)) * D_;
  float x0 = hi[t], x1 = hi[t + 256];
  __shared__ float r1[256], r2[256];
  r1[t] = x0 + x1; r2[t] = x0*x0 + x1*x1;
  __syncthreads();
  for (int s = 128; s; s >>= 1){ if (t < s){ r1[t] += r1[t+s]; r2[t] += r2[t+s]; } __syncthreads(); }
  float mu = r1[0] * (1.f / D_);
  float var = r2[0] * (1.f / D_) - mu*mu;
  float rs = rsqrtf(var + 1e-5f);
  xo[t]       = __float2bfloat16((x0 - mu) * rs * g[t]       + bb[t]);
  xo[t + 256] = __float2bfloat16((x1 - mu) * rs * g[t + 256] + bb[t + 256]);
}

__global__ __launch_bounds__(256) void final_ln(const float* H, const float* g,
                                                const float* bb, float* out){
  int b = blockIdx.x, t = threadIdx.x;
  const float* hi = H + (long long)b * NTOK * D_;
  float x0 = hi[t], x1 = hi[t + 256];
  __shared__ float r1[256], r2[256];
  r1[t] = x0 + x1; r2[t] = x0*x0 + x1*x1;
  __syncthreads();
  for (int s = 128; s; s >>= 1){ if (t < s){ r1[t] += r1[t+s]; r2[t] += r2[t+s]; } __syncthreads(); }
  float mu = r1[0] * (1.f / D_);
  float var = r2[0] * (1.f / D_) - mu*mu;
  float rs = rsqrtf(var + 1e-5f);
  out[b*D_ + t]       = (x0 - mu) * rs * g[t]       + bb[t];
  out[b*D_ + t + 256] = (x1 - mu) * rs * g[t + 256] + bb[t + 256];
}

__global__ __launch_bounds__(256) void build_h(const float* h0, const float* cls, float* H){
  int tpos = blockIdx.x, b = blockIdx.y, t = threadIdx.x;
  float* dst = H + ((long long)b * NTOK + tpos) * D_;
  if (tpos == 0){ dst[t] = cls[t]; dst[t + 256] = cls[t + 256]; return; }
  int i = tpos - 1, src;
  if (i < 10)        src = i;
  else if (i < 179){ int j = i - 10;  src = 10  + (j < 160  ? j : j - 160);  }
  else             { int j = i - 179; src = 170 + (j < 6000 ? j : j - 6000); }
  const float* s = h0 + ((long long)b * N0 + src) * D_;
  dst[t] = s[t]; dst[t + 256] = s[t + 256];
}

__global__ __launch_bounds__(256) void cvt_pad_x(const float* x, __hip_bfloat16* Xb){
  int row = blockIdx.x, t = threadIdx.x;
  __hip_bfloat16* o = Xb + (long long)row * 768;
  if (row >= B_*N0){ o[t] = __float2bfloat16(0.f); o[t+256] = __float2bfloat16(0.f); o[t+512] = __float2bfloat16(0.f); return; }
  const float* s = x + (long long)row * 768;
  o[t]     = __float2bfloat16(s[t]);
  o[t+256] = __float2bfloat16(s[t+256]);
  o[t+512] = __float2bfloat16(s[t+512]);
}

// generic transpose+cvt: in[z][R][C] -> out bf16 [z][C][R]
__global__ __launch_bounds__(256) void tr_cvt(const void* in, int inbf, int ldin,
    long long iSO, long long iSI, int iIn, __hip_bfloat16* outp, long long oSO,
    int R, int C){
  __shared__ float sm[32][33];
  int z = blockIdx.z;
  long long ib = (long long)(z/iIn)*iSO + (long long)(z%iIn)*iSI;
  int r0 = blockIdx.y*32, c0 = blockIdx.x*32;
  int tx = threadIdx.x & 31, ty = threadIdx.x >> 5;
  for (int rr = ty; rr < 32; rr += 8)
    sm[rr][tx] = gload(in, inbf, ib + (long long)(r0+rr)*ldin + c0 + tx);
  __syncthreads();
  for (int cc = ty; cc < 32; cc += 8)
    outp[z*oSO + (long long)(c0+cc)*R + r0 + tx] = __float2bfloat16(sm[tx][cc]);
}

// coalesced landmark means: one block per (landmark j, batch b)
__global__ __launch_bounds__(256) void landmarks2(const __hip_bfloat16* QKV,
                                                  __hip_bfloat16* QL, __hip_bfloat16* KL){
  int j = blockIdx.x, b = blockIdx.y, t = threadIdx.x;
  const __hip_bfloat16* base = QKV + ((long long)b * NPAD + j*25) * 1536;
  float q0 = 0.f, q1 = 0.f, k0 = 0.f, k1 = 0.f;
  #pragma unroll 5
  for (int i = 0; i < 25; i++){
    const __hip_bfloat16* row = base + (long long)i*1536;
    q0 += __bfloat162float(row[t]);
    q1 += __bfloat162float(row[t + 256]);
    k0 += __bfloat162float(row[512 + t]);
    k1 += __bfloat162float(row[512 + t + 256]);
  }
  int h0 = t >> 6, d0 = t & 63;
  int h1 = (t + 256) >> 6, d1 = (t + 256) & 63;
  QL[((long long)(b*8 + h0) * NLM + j) * 64 + d0] = __float2bfloat16(q0 * 0.005f);
  QL[((long long)(b*8 + h1) * NLM + j) * 64 + d1] = __float2bfloat16(q1 * 0.005f);
  KL[((long long)(b*8 + h0) * NLM + j) * 64 + d0] = __float2bfloat16(k0 * 0.04f);
  KL[((long long)(b*8 + h1) * NLM + j) * 64 + d1] = __float2bfloat16(k1 * 0.04f);
}

__global__ void init_sc(float* sc){ sc[0] = 0.f; sc[1] = 0.f; }
__global__ __launch_bounds__(256) void fillz(float* p, int n){
  int i = blockIdx.x*256 + threadIdx.x; if (i < n) p[i] = 0.f;
}

__global__ __launch_bounds__(256) void colsum_max(const float* A2, float* sc){
  int z = blockIdx.x, t = threadIdx.x;
  const float* a = A2 + (long long)z * 65536;
  float s = 0.f;
  for (int i = 0; i < 256; i++) s += fabsf(a[i*256 + t]);
  __shared__ float red[256];
  red[t] = s; __syncthreads();
  for (int st = 128; st; st >>= 1){ if (t < st) red[t] = fmaxf(red[t], red[t+st]); __syncthreads(); }
  if (t == 0) atomicMaxF(sc + 0, red[0]);
}

__global__ __launch_bounds__(256) void rowsum_max(const float* A2, float* sc){
  int z = blockIdx.x, t = threadIdx.x, w = t >> 6, l = t & 63;
  const float* a = A2 + (long long)z * 65536;
  float mx = 0.f;
  for (int i = w*64; i < (w+1)*64; i++){
    float s = fabsf(a[i*256 + l]) + fabsf(a[i*256 + l + 64])
            + fabsf(a[i*256 + l + 128]) + fabsf(a[i*256 + l + 192]);
    for (int m = 32; m; m >>= 1) s += __shfl_xor(s, m);
    mx = fmaxf(mx, s);
  }
  __shared__ float red[4];
  if (l == 0) red[w] = mx;
  __syncthreads();
  if (t == 0) atomicMaxF(sc + 1, fmaxf(fmaxf(red[0], red[1]), fmaxf(red[2], red[3])));
}

// Z = A2^T/(c*r): write ZN (=[j][i]) and ZT (=[i][j]) hi/lo planes
__global__ __launch_bounds__(256) void zinit_split(const float* A2,
    __hip_bfloat16* ZN, __hip_bfloat16* ZT, long long PS, const float* sc){
  int j = blockIdx.x, z = blockIdx.y, i = threadIdx.x;
  float inv = 1.f / (sc[0] * sc[1]);
  float v = A2[(long long)z*65536 + i*256 + j] * inv;
  __hip_bfloat16 hi = __float2bfloat16(v);
  __hip_bfloat16 lo = __float2bfloat16(v - __bfloat162float(hi));
  long long zo = (long long)z*65536;
  ZN[zo + j*256 + i] = hi; ZN[PS + zo + j*256 + i] = lo;
  ZT[zo + i*256 + j] = hi; ZT[PS + zo + i*256 + j] = lo;
}

// vectorized depthwise conv: 8 ch/thread, 4 positions/block
__global__ __launch_bounds__(256) void dwconv_cvt2(const __hip_bfloat16* QKV, const float* rw,
                                                   const float* OUT1, __hip_bfloat16* OUT1b){
  int t = threadIdx.x;
  int n = blockIdx.x*4 + (t >> 6);
  int b = blockIdx.y;
  int ch0 = (t & 63) * 8;
  int h = (t & 63) >> 3;
  float w[33];
  #pragma unroll
  for (int k = 0; k < 33; k++) w[k] = rw[h*33 + k];
  float acc[8] = {};
  const __hip_bfloat16* Vb = QKV + (long long)b * NPAD * 1536 + 1024 + ch0;
  #pragma unroll
  for (int k = 0; k < 33; k++){
    int nn = n + k - 16;
    if (nn < 0 || nn >= NPAD) continue;
    short8_t v8 = *(const short8_t*)(Vb + (long long)nn * 1536);
    #pragma unroll
    for (int j = 0; j < 8; j++) acc[j] += w[k] * b2f((ushort)v8[j]);
  }
  long long idx = ((long long)b * NPAD + n) * D_ + ch0;
  float4 o0 = *(const float4*)(OUT1 + idx);
  float4 o1 = *(const float4*)(OUT1 + idx + 4);
  short8_t o;
  o[0] = (short)f2b(o0.x + acc[0]); o[1] = (short)f2b(o0.y + acc[1]);
  o[2] = (short)f2b(o0.z + acc[2]); o[3] = (short)f2b(o0.w + acc[3]);
  o[4] = (short)f2b(o1.x + acc[4]); o[5] = (short)f2b(o1.y + acc[5]);
  o[6] = (short)f2b(o1.z + acc[6]); o[7] = (short)f2b(o1.w + acc[7]);
  *(short8_t*)((ushort*)OUT1b + idx) = o;
}

__global__ __launch_bounds__(512) void resid_add(float* H, const float* O2, const float* ob){
  int i = blockIdx.x, b = blockIdx.y, t = threadIdx.x;
  H[((long long)b * NTOK + i) * D_ + t] +=
      O2[((long long)b * NPAD + i + PADF) * D_ + t] + ob[t];
}

// ------------------------------ PPEG --------------------------------------
__global__ __launch_bounds__(256) void transpose_w(const float* w, float* wt, int KK){
  int i = blockIdx.x*256 + threadIdx.x;
  if (i < 512*KK){ int ch = i / KK, k = i - ch*KK; wt[(long long)k*512 + ch] = w[i]; }
}

__global__ __launch_bounds__(256) void ppeg_tiled(const float* H, float* P,
    const float* t7, const float* t5, const float* t3,
    const float* b7, const float* b5, const float* b3,
    int base, int W, int tilesX){
  __shared__ float smem[196*64];
  int ty0 = (blockIdx.x / tilesX) * 8, tx0 = (blockIdx.x % tilesX) * 8;
  int c0 = blockIdx.y * 64, b = blockIdx.z;
  int t = threadIdx.x, ch = t & 63, pr = t >> 6;
  const float* Hb = H + ((long long)b * NTOK + base) * D_ + c0 + ch;
  for (int i = pr; i < 196; i += 4){
    int py = i / 14, px = i - py*14;
    int y = ty0 + py - 3, x = tx0 + px - 3;
    smem[i*64 + ch] = (y >= 0 && y < W && x >= 0 && x < W)
                      ? Hb[(long long)(y*W + x) * D_] : 0.f;
  }
  __syncthreads();
  float acc[16];
  float bsum = b7[c0+ch] + b5[c0+ch] + b3[c0+ch];
  #pragma unroll
  for (int o = 0; o < 16; o++){
    int y = o >> 1, x = pr + (o & 1)*4;
    acc[o] = smem[((y+3)*14 + (x+3))*64 + ch] + bsum;
  }
  for (int ky = 0; ky < 7; ky++)
    for (int kx = 0; kx < 7; kx++){
      float wv = t7[(ky*7 + kx)*512 + c0 + ch];
      #pragma unroll
      for (int o = 0; o < 16; o++){
        int y = o >> 1, x = pr + (o & 1)*4;
        acc[o] += wv * smem[((y+ky)*14 + (x+kx))*64 + ch];
      }
    }
  for (int ky = 0; ky < 5; ky++)
    for (int kx = 0; kx < 5; kx++){
      float wv = t5[(ky*5 + kx)*512 + c0 + ch];
      #pragma unroll
      for (int o = 0; o < 16; o++){
        int y = o >> 1, x = pr + (o & 1)*4;
        acc[o] += wv * smem[((y+1+ky)*14 + (x+1+kx))*64 + ch];
      }
    }
  for (int ky = 0; ky < 3; ky++)
    for (int kx = 0; kx < 3; kx++){
      float wv = t3[(ky*3 + kx)*512 + c0 + ch];
      #pragma unroll
      for (int o = 0; o < 16; o++){
        int y = o >> 1, x = pr + (o & 1)*4;
        acc[o] += wv * smem[((y+2+ky)*14 + (x+2+kx))*64 + ch];
      }
    }
  #pragma unroll
  for (int o = 0; o < 16; o++){
    int y = ty0 + (o >> 1), x = tx0 + pr + (o & 1)*4;
    if (y < W && x < W)
      P[((long long)b * W * W + y*W + x) * D_ + c0 + ch] = acc[o];
  }
}

__global__ __launch_bounds__(512) void ppeg_copy(float* H, const float* P, int base, int W){
  int pos = blockIdx.x, b = blockIdx.y, t = threadIdx.x;
  H[((long long)b * NTOK + base + pos) * D_ + t] = P[((long long)b * W * W + pos) * D_ + t];
}

// ============================== host side =================================
static void gemmB(hipStream_t st, int BN,
                  const __hip_bfloat16* A, int lda, long long aSO, long long aSI, int aIn,
                  const __hip_bfloat16* Bm, int ldb, long long bSO, long long bSI, int bIn,
                  void* C, int ldc, long long cSO, long long cSI, int cIn, int cbf,
                  int M, int N, int K, int batch,
                  const float* bias, float beta, int relu, int ksp = 1, int klen = 0){
  GB p;
  p.A = A; p.Bm = Bm; p.C = C; p.bias = bias;
  p.M = M; p.N = N; p.K = K; p.lda = lda; p.ldb = ldb; p.ldc = ldc;
  p.aSO = aSO; p.aSI = aSI; p.aIn = aIn;
  p.bSO = bSO; p.bSI = bSI; p.bIn = bIn;
  p.cSO = cSO; p.cSI = cSI; p.cIn = cIn; p.cbf = cbf;
  p.beta = beta; p.relu = relu; p.ksp = ksp; p.klen = (klen > 0) ? klen : K;
  dim3 g(N/BN, (M + 127)/128, batch * ksp), b(256);
  if (BN == 128) gemm_bt<128><<<g, b, 0, st>>>(p);
  else           gemm_bt<64><<<g, b, 0, st>>>(p);
}

static void gemmS(hipStream_t st, const ushort* A, const ushort* B,
                  ushort* oN, ushort* oT, float scale, float alphaT, float sT){
  GS p;
  p.A = (const __hip_bfloat16*)A; p.B = (const __hip_bfloat16*)B;
  p.outN = (__hip_bfloat16*)oN; p.outT = (__hip_bfloat16*)oT;
  p.PS = 2097152; p.scale = scale; p.alphaT = alphaT; p.sT = sT;
  dim3 g(4, 2, 32), b(256);
  gemm_bts<<<g, b, 0, st>>>(p);
}

extern "C" void kernel_launch(void* const* d_in, const int* in_sizes, int n_in,
                              void* d_out, int out_size, void* d_ws, size_t ws_size,
                              hipStream_t stream){
  const float* x      = (const float*)d_in[0];
  const float* fc1_w  = (const float*)d_in[1];
  const float* fc1_b  = (const float*)d_in[2];
  const float* cls    = (const float*)d_in[3];
  const float* l1_ng  = (const float*)d_in[4];
  const float* l1_nb  = (const float*)d_in[5];
  const float* l1_qkv = (const float*)d_in[6];
  const float* l1_ow  = (const float*)d_in[7];
  const float* l1_ob  = (const float*)d_in[8];
  const float* l1_rw  = (const float*)d_in[9];
  const float* ct_w7  = (const float*)d_in[10];
  const float* ct_b7  = (const float*)d_in[11];
  const float* ct_w5  = (const float*)d_in[12];
  const float* ct_b5  = (const float*)d_in[13];
  const float* ct_w3  = (const float*)d_in[14];
  const float* ct_b3  = (const float*)d_in[15];
  const float* pt_w7  = (const float*)d_in[16];
  const float* pt_b7  = (const float*)d_in[17];
  const float* pt_w5  = (const float*)d_in[18];
  const float* pt_b5  = (const float*)d_in[19];
  const float* pt_w3  = (const float*)d_in[20];
  const float* pt_b3  = (const float*)d_in[21];
  const float* l2_ng  = (const float*)d_in[22];
  const float* l2_nb  = (const float*)d_in[23];
  const float* l2_qkv = (const float*)d_in[24];
  const float* l2_ow  = (const float*)d_in[25];
  const float* l2_ob  = (const float*)d_in[26];
  const float* l2_rw  = (const float*)d_in[27];
  const float* nrm_g  = (const float*)d_in[28];
  const float* nrm_b  = (const float*)d_in[29];
  float* out = (float*)d_out;

  // ---- workspace layout (float units); total ~218 MB ----
  float* ws    = (float*)d_ws;
  float* H     = ws;                      // 12,828,672
  float* BUF   = H + 12828672;            // 13,107,200
  float* QKVr  = BUF + 13107200;          // 19,660,800 : Xb/QKV bf16; later PROJ f32
  float* SIMCf = QKVr + 19660800;         //  6,553,600 : pinv T-planes / sim chunks / OUT1b
  float* QLf   = SIMCf + 6553600;         //    262,144
  float* KLf   = QLf + 262144;            //    262,144
  float* AV    = KLf + 262144;            //    524,288 : f32
  float* AVTf  = AV + 524288;             //    262,144
  float* ZVf   = AVTf + 262144;           //    262,144
  float* ZVTf  = ZVf + 262144;            //    262,144
  float* WQf   = ZVTf + 262144;           //    393,216
  float* WFf   = WQf + 393216;            //    196,608
  float* WOf   = WFf + 196608;            //    131,072
  float* PWT   = WOf + 131072;            //     84,992
  float* SC    = PWT + 84992;             //          2
  float* tc7 = PWT, *tc5 = tc7 + 49*512, *tc3 = tc5 + 25*512;
  float* tp7 = tc3 + 9*512, *tp5 = tp7 + 49*512, *tp3 = tp5 + 25*512;

  // pinv window inside BUF / SIMCf (all plane pairs are hi + lo at +PS=2,097,152 bf16)
  float*  A2   = BUF;                                   // f32 [32][256][256]
  ushort* a2P  = (ushort*)(BUF + 2097152);              // A2 hi/lo planes
  ushort* zn_N = (ushort*)(BUF + 4194304);              // set1
  ushort* zn_T = (ushort*)(BUF + 6291456);
  ushort* zc_N = (ushort*)(BUF + 8388608);              // set0 (final Z lands here)
  ushort* zc_T = (ushort*)(BUF + 10485760);
  ushort* azP  = (ushort*)(SIMCf);
  ushort* w1T  = (ushort*)(SIMCf + 2097152);
  ushort* w2T  = (ushort*)(SIMCf + 4194304);

  __hip_bfloat16* Xb    = (__hip_bfloat16*)QKVr;
  __hip_bfloat16* QKV   = (__hip_bfloat16*)QKVr;
  float*          PROJ  = QKVr;
  __hip_bfloat16* XLNb  = (__hip_bfloat16*)BUF;
  __hip_bfloat16* VT    = (__hip_bfloat16*)BUF;         // [32][64][6400], pinv dead
  __hip_bfloat16* SIMCb = (__hip_bfloat16*)SIMCf;
  __hip_bfloat16* OUT1b = (__hip_bfloat16*)SIMCf;
  __hip_bfloat16* QLb   = (__hip_bfloat16*)QLf;
  __hip_bfloat16* KLb   = (__hip_bfloat16*)KLf;
  __hip_bfloat16* AVT   = (__hip_bfloat16*)AVTf;
  __hip_bfloat16* Zvb   = (__hip_bfloat16*)ZVf;
  __hip_bfloat16* ZVT   = (__hip_bfloat16*)ZVTf;
  __hip_bfloat16* WqkvT = (__hip_bfloat16*)WQf;
  __hip_bfloat16* Wfc1T = (__hip_bfloat16*)WFf;
  __hip_bfloat16* WoutT = (__hip_bfloat16*)WOf;

  const long long QE = (long long)NPAD * 1536;

  // ---- one-time weight prep
  transpose_w<<<(512*49+255)/256, 256, 0, stream>>>(ct_w7, tc7, 49);
  transpose_w<<<(512*25+255)/256, 256, 0, stream>>>(ct_w5, tc5, 25);
  transpose_w<<<(512* 9+255)/256, 256, 0, stream>>>(ct_w3, tc3,  9);
  transpose_w<<<(512*49+255)/256, 256, 0, stream>>>(pt_w7, tp7, 49);
  transpose_w<<<(512*25+255)/256, 256, 0, stream>>>(pt_w5, tp5, 25);
  transpose_w<<<(512* 9+255)/256, 256, 0, stream>>>(pt_w3, tp3,  9);
  tr_cvt<<<dim3(512/32, 768/32, 1), 256, 0, stream>>>(fc1_w, 0, 512, 0,0,1, Wfc1T, 0, 768, 512);

  // ---- fc1 + relu -> h0 (BUF f32); gather into H
  cvt_pad_x<<<MFC1, 256, 0, stream>>>(x, Xb);
  gemmB(stream, 128, Xb, 768, 0,0,1, Wfc1T, 768, 0,0,1, BUF, 512, 0,0,1,0,
        MFC1, 512, 768, 1, fc1_b, 1.f, 1);
  build_h<<<dim3(NTOK, B_), 256, 0, stream>>>(BUF, cls, H);

  auto attn_layer = [&](const float* ng, const float* nb, const float* qkvw,
                        const float* outw, const float* outb, const float* resw){
    tr_cvt<<<dim3(1536/32, 512/32, 1), 256, 0, stream>>>(qkvw, 0, 1536, 0,0,1, WqkvT, 0, 512, 1536);
    tr_cvt<<<dim3(512/32, 512/32, 1), 256, 0, stream>>>(outw, 0, 512, 0,0,1, WoutT, 0, 512, 512);
    ln_pad<<<dim3(NPAD, B_), 256, 0, stream>>>(H, XLNb, ng, nb);
    gemmB(stream, 128, XLNb, 512, 0,0,1, WqkvT, 512, 0,0,1, QKV, 1536, 0,0,1,1,
          B_*NPAD, 1536, 512, 1, nullptr, 1.f, 0);
    landmarks2<<<dim3(NLM, B_), 256, 0, stream>>>(QKV, QLb, KLb);
    // a2 = softmax(q_l @ k_l^T): f32 + hi/lo planes
    gemmB(stream, 128, QLb, 64, 16384,0,1, KLb, 64, 16384,0,1, A2, 256, 65536,0,1,0,
          256, 256, 64, 32, nullptr, 1.f, 0);
    softmax256_split<<<B_*NH*NLM, 256, 0, stream>>>(A2, (__hip_bfloat16*)a2P, 2097152);
    // pinv (Newton-Schulz, 6 iters), fast split GEMMs with fused diag epilogues
    init_sc<<<1, 1, 0, stream>>>(SC);
    colsum_max<<<B_*NH, 256, 0, stream>>>(A2, SC);
    rowsum_max<<<B_*NH, 256, 0, stream>>>(A2, SC);
    zinit_split<<<dim3(256, 32), 256, 0, stream>>>(A2, (__hip_bfloat16*)zc_N,
          (__hip_bfloat16*)zc_T, 2097152, SC);
    ushort *cN = zc_N, *cT = zc_T, *nN = zn_N, *nT = zn_T;
    for (int it = 0; it < 6; it++){
      gemmS(stream, a2P, cT, azP, w1T, 1.f, 7.f, -1.f);    // AZ ; W1T = (7I-AZ)^T
      gemmS(stream, azP, w1T, nullptr, w2T, 1.f, 15.f, -1.f); // W2T = (15I-AZ@W1)^T
      gemmS(stream, azP, w2T, nullptr, w1T, 1.f, 13.f, -1.f); // W1T = (13I-AZ@W2)^T
      gemmS(stream, cN, w1T, nN, nT, 0.25f, 0.f, 1.f);     // Zn = .25*Zc@W1'
      ushort* s;
      s = cN; cN = nN; nN = s;
      s = cT; cT = nT; nT = s;
    }
    // final Z hi plane (normal layout) = bf16 Z for ZV gemm
    const __hip_bfloat16* Zcb = (const __hip_bfloat16*)cN;
    // V^T per head into BUF (pinv scratch mostly dead; final Z at BUF+8M survives)
    tr_cvt<<<dim3(64/32, NPAD/32, 32), 256, 0, stream>>>(QKV + 1024, 1, 1536,
          QE, 64, 8, VT, (long long)64*NPAD, NPAD, 64);
    fillz<<<2048, 256, 0, stream>>>(AV, 524288);
    // sim3 -> softmax -> AV, chunked over 4 bh-groups
    for (int c = 0; c < 8; c++){
      int b = c >> 1, hh = (c & 1) * 4;
      const __hip_bfloat16* Kp = QKV + (long long)b*QE + hh*64 + 512;
      gemmB(stream, 128, QLb + (long long)4*c*16384, 64, 16384,0,1,
            Kp, 1536, 0,64,4,
            SIMCb, NPAD, (long long)256*NPAD,0,1,1,
            256, NPAD, 64, 4, nullptr, 1.f, 0);
      softmax_rows_b<NPAD><<<4*NLM, 256, 0, stream>>>(SIMCb);
      gemmB(stream, 64, SIMCb, NPAD, (long long)256*NPAD,0,1,
            VT + (long long)4*c*64*NPAD, NPAD, (long long)64*NPAD,0,1,
            AV + (long long)4*c*16384, 64, 16384,0,1,0,
            256, 64, NPAD, 4, nullptr, 1.f, 0, 10, 640);
    }
    // AV^T, ZV = Zc@AV (bf16 out), ZV^T
    tr_cvt<<<dim3(64/32, 256/32, 32), 256, 0, stream>>>(AV, 0, 64, 16384,0,1,
          AVT, 16384, 256, 64);
    gemmB(stream, 64, Zcb, 256, 65536,0,1, AVT, 256, 16384,0,1,
          Zvb, 64, 16384,0,1,1, 256, 64, 256, 32, nullptr, 1.f, 0);
    tr_cvt<<<dim3(64/32, 256/32, 32), 256, 0, stream>>>(Zvb, 1, 64, 16384,0,1,
          ZVT, 16384, 256, 64);
    // sim1 -> softmax -> OUT1 (f32 into BUF), chunked
    for (int c = 0; c < 8; c++){
      int b = c >> 1, hh = (c & 1) * 4;
      const __hip_bfloat16* Qp = QKV + (long long)b*QE + hh*64;
      gemmB(stream, 128, Qp, 1536, 0,64,4,
            KLb + (long long)4*c*16384, 64, 16384,0,1,
            SIMCb, 256, (long long)NPAD*256,0,1,1,
            NPAD, 256, 64, 4, nullptr, 0.125f, 0);
      softmax_rows_b<256><<<4*NPAD, 256, 0, stream>>>(SIMCb);
      gemmB(stream, 64, SIMCb, 256, (long long)NPAD*256,0,1,
            ZVT + (long long)4*c*16384, 256, 16384,0,1,
            BUF + (long long)b*NPAD*512 + hh*64, 512, 0,64,4,0,
            NPAD, 64, 256, 4, nullptr, 1.f, 0);
    }
    // + depthwise conv residual -> bf16, projection, residual add
    dwconv_cvt2<<<dim3(NPAD/4, B_), 256, 0, stream>>>(QKV, resw, BUF, OUT1b);
    gemmB(stream, 128, OUT1b, 512, 0,0,1, WoutT, 512, 0,0,1, PROJ, 512, 0,0,1,0,
          B_*NPAD, 512, 512, 1, nullptr, 1.f, 0);
    resid_add<<<dim3(NTOK, B_), 512, 0, stream>>>(H, PROJ, outb);
  };

  // ---- layer 1
  attn_layer(l1_ng, l1_nb, l1_qkv, l1_ow, l1_ob, l1_rw);

  // ---- PPEG
  ppeg_tiled<<<dim3(4, 8, B_), 256, 0, stream>>>(H, BUF, tc7, tc5, tc3, ct_b7, ct_b5, ct_b3, 11, 13, 2);
  ppeg_copy<<<dim3(169, B_), 512, 0, stream>>>(H, BUF, 11, 13);
  ppeg_tiled<<<dim3(100, 8, B_), 256, 0, stream>>>(H, BUF, tp7, tp5, tp3, pt_b7, pt_b5, pt_b3, 180, 78, 10);
  ppeg_copy<<<dim3(6084, B_), 512, 0, stream>>>(H, BUF, 180, 78);

  // ---- layer 2
  attn_layer(l2_ng, l2_nb, l2_qkv, l2_ow, l2_ob, l2_rw);

  // ---- final LN on cls token
  final_ln<<<B_, 256, 0, stream>>>(H, nrm_g, nrm_b, out);
}

// Round 6
// 2666.164 us; speedup vs baseline: 4.5746x; 1.3434x over previous
//
#include <hip/hip_runtime.h>
#include <hip/hip_bf16.h>
#include <cstdint>

#define B_   4
#define NTOK 6264
#define NPAD 6400
#define D_   512
#define NH   8
#define NLM  256
#define N0   6170
#define PADF (NPAD - NTOK)   // 136
#define MFC1 24704           // B_*N0 padded to x128
#define QE   ((long long)NPAD * 1536)

typedef __attribute__((ext_vector_type(8))) short short8_t;
typedef __attribute__((ext_vector_type(4))) float float4_t;

__device__ __forceinline__ ushort f2b(float x){
  __hip_bfloat16 h = __float2bfloat16(x); return *(ushort*)&h;
}
__device__ __forceinline__ float b2f(ushort u){
  __hip_bfloat16 h = *(__hip_bfloat16*)&u; return __bfloat162float(h);
}
__device__ __forceinline__ float gload(const void* p, int bf, long long i){
  return bf ? __bfloat162float(((const __hip_bfloat16*)p)[i]) : ((const float*)p)[i];
}
__device__ __forceinline__ void atomicMaxF(float* a, float v){
  atomicMax((int*)a, __float_as_int(v));
}
__device__ __forceinline__ void gl_lds16(const void* g, void* l){
  __builtin_amdgcn_global_load_lds(
      (const __attribute__((address_space(1))) void*)g,
      (__attribute__((address_space(3))) void*)l, 16, 0, 0);
}

// ===================== fast bf16 NT GEMM (m97-style) ======================
struct GB {
  const __hip_bfloat16* A; const __hip_bfloat16* Bm; void* C; const float* bias;
  int M, N, K, lda, ldb, ldc;
  long long aSO, aSI; int aIn;
  long long bSO, bSI; int bIn;
  long long cSO, cSI; int cIn;
  float beta; int cbf, relu, ksp, klen;
};

template<int BN>
__global__ __launch_bounds__(256) void gemm_bt(GB p){
  __shared__ __align__(16) __hip_bfloat16 As[128*64];
  __shared__ __align__(16) __hip_bfloat16 Bs[BN*64];
  int zz = blockIdx.z;
  int z = zz / p.ksp, ks = zz - z*p.ksp;
  int k0 = ks * p.klen;
  int kend = k0 + p.klen; if (kend > p.K) kend = p.K;
  const __hip_bfloat16* A  = p.A  + (long long)(z/p.aIn)*p.aSO + (long long)(z%p.aIn)*p.aSI;
  const __hip_bfloat16* Bm = p.Bm + (long long)(z/p.bIn)*p.bSO + (long long)(z%p.bIn)*p.bSI;
  long long cOff = (long long)(z/p.cIn)*p.cSO + (long long)(z%p.cIn)*p.cSI;
  int rowBase = blockIdx.y*128, colBase = blockIdx.x*BN;
  int t = threadIdx.x, lane = t & 63;
  int wv = __builtin_amdgcn_readfirstlane(t >> 6);
  int lm = lane & 15, lq = lane >> 4;
  int dr = lane >> 3, dc = lane & 7;
  constexpr int NF = (BN == 128) ? 4 : 2;
  int wm = (wv >> 1) * 64;
  int wn = (BN == 128) ? (wv & 1) * 64 : (wv & 1) * 32;
  float4_t acc[4][NF];
  #pragma unroll
  for (int mi = 0; mi < 4; mi++)
    #pragma unroll
    for (int nf = 0; nf < NF; nf++) acc[mi][nf] = (float4_t)0.f;

  for (int kb = k0; kb < kend; kb += 64){
    #pragma unroll
    for (int d = 0; d < 4; d++){
      int rg = wv*4 + d;
      int row = rg*8 + dr;
      int cc = dc ^ (row & 7);
      gl_lds16(A + (long long)(rowBase + row)*p.lda + kb + cc*8, &As[rg*8*64]);
    }
    #pragma unroll
    for (int d = 0; d < BN/32; d++){
      int rg = wv*(BN/32) + d;
      int row = rg*8 + dr;
      int cc = dc ^ (row & 7);
      gl_lds16(Bm + (long long)(colBase + row)*p.ldb + kb + cc*8, &Bs[rg*8*64]);
    }
    __syncthreads();
    short8_t af[2][4]; short8_t bfv[2][NF];
    #pragma unroll
    for (int ks2 = 0; ks2 < 2; ks2++){
      #pragma unroll
      for (int mi = 0; mi < 4; mi++){
        int r = wm + mi*16 + lm;
        int s = (ks2*4 + lq) ^ (r & 7);
        af[ks2][mi] = *(const short8_t*)&As[r*64 + s*8];
      }
      #pragma unroll
      for (int nf = 0; nf < NF; nf++){
        int r = wn + nf*16 + lm;
        int s = (ks2*4 + lq) ^ (r & 7);
        bfv[ks2][nf] = *(const short8_t*)&Bs[r*64 + s*8];
      }
    }
    #pragma unroll
    for (int ks2 = 0; ks2 < 2; ks2++)
      #pragma unroll
      for (int mi = 0; mi < 4; mi++)
        #pragma unroll
        for (int nf = 0; nf < NF; nf++)
          acc[mi][nf] = __builtin_amdgcn_mfma_f32_16x16x32_bf16(af[ks2][mi], bfv[ks2][nf], acc[mi][nf], 0, 0, 0);
    __syncthreads();
  }
  #pragma unroll
  for (int mi = 0; mi < 4; mi++){
    #pragma unroll
    for (int nf = 0; nf < NF; nf++){
      int c = colBase + wn + nf*16 + lm;
      #pragma unroll
      for (int r = 0; r < 4; r++){
        int m = rowBase + wm + mi*16 + lq*4 + r;
        if (m >= p.M) continue;
        float v = p.beta * acc[mi][nf][r];
        long long ci = cOff + (long long)m*p.ldc + c;
        if (p.ksp > 1){
          atomicAdd((float*)p.C + ci, v);
        } else {
          if (p.bias) v += p.bias[c];
          if (p.relu) v = fmaxf(v, 0.f);
          if (p.cbf) ((__hip_bfloat16*)p.C)[ci] = __float2bfloat16(v);
          else       ((float*)p.C)[ci] = v;
        }
      }
    }
  }
}

// ============== fast split (hi/lo) GEMM for pinv: 256x256x256, batch 32 ====
struct GS {
  const __hip_bfloat16* A; const __hip_bfloat16* B;
  __hip_bfloat16* outN; __hip_bfloat16* outT;
  long long PS;
  float scale, alphaT, sT;
};

__global__ __launch_bounds__(256) void gemm_bts(GS p){
  __shared__ __align__(16) __hip_bfloat16 Ah[128*64];
  __shared__ __align__(16) __hip_bfloat16 Al[128*64];
  __shared__ __align__(16) __hip_bfloat16 Bh[64*64];
  __shared__ __align__(16) __hip_bfloat16 Bl[64*64];
  int z = blockIdx.z;
  long long zo = (long long)z * 65536;
  const __hip_bfloat16* A = p.A + zo;
  const __hip_bfloat16* B = p.B + zo;
  int rowBase = blockIdx.y*128, colBase = blockIdx.x*64;
  int t = threadIdx.x, lane = t & 63;
  int wv = __builtin_amdgcn_readfirstlane(t >> 6);
  int lm = lane & 15, lq = lane >> 4;
  int dr = lane >> 3, dc = lane & 7;
  int wm = (wv >> 1) * 64, wn = (wv & 1) * 32;
  float4_t acc[4][2];
  #pragma unroll
  for (int mi = 0; mi < 4; mi++){ acc[mi][0] = (float4_t)0.f; acc[mi][1] = (float4_t)0.f; }

  for (int kb = 0; kb < 256; kb += 64){
    #pragma unroll
    for (int d = 0; d < 4; d++){
      int rg = wv*4 + d;
      int row = rg*8 + dr;
      int cc = dc ^ (row & 7);
      gl_lds16(A +        (long long)(rowBase + row)*256 + kb + cc*8, &Ah[rg*8*64]);
      gl_lds16(A + p.PS + (long long)(rowBase + row)*256 + kb + cc*8, &Al[rg*8*64]);
    }
    #pragma unroll
    for (int d = 0; d < 2; d++){
      int rg = wv*2 + d;
      int row = rg*8 + dr;
      int cc = dc ^ (row & 7);
      gl_lds16(B +        (long long)(colBase + row)*256 + kb + cc*8, &Bh[rg*8*64]);
      gl_lds16(B + p.PS + (long long)(colBase + row)*256 + kb + cc*8, &Bl[rg*8*64]);
    }
    __syncthreads();
    #pragma unroll
    for (int ks2 = 0; ks2 < 2; ks2++){
      short8_t ah[4], al[4], bh[2], bl[2];
      #pragma unroll
      for (int mi = 0; mi < 4; mi++){
        int r = wm + mi*16 + lm;
        int s = (ks2*4 + lq) ^ (r & 7);
        ah[mi] = *(const short8_t*)&Ah[r*64 + s*8];
        al[mi] = *(const short8_t*)&Al[r*64 + s*8];
      }
      #pragma unroll
      for (int nf = 0; nf < 2; nf++){
        int r = wn + nf*16 + lm;
        int s = (ks2*4 + lq) ^ (r & 7);
        bh[nf] = *(const short8_t*)&Bh[r*64 + s*8];
        bl[nf] = *(const short8_t*)&Bl[r*64 + s*8];
      }
      #pragma unroll
      for (int mi = 0; mi < 4; mi++)
        #pragma unroll
        for (int nf = 0; nf < 2; nf++){
          acc[mi][nf] = __builtin_amdgcn_mfma_f32_16x16x32_bf16(ah[mi], bh[nf], acc[mi][nf], 0, 0, 0);
          acc[mi][nf] = __builtin_amdgcn_mfma_f32_16x16x32_bf16(ah[mi], bl[nf], acc[mi][nf], 0, 0, 0);
          acc[mi][nf] = __builtin_amdgcn_mfma_f32_16x16x32_bf16(al[mi], bh[nf], acc[mi][nf], 0, 0, 0);
        }
    }
    __syncthreads();
  }
  #pragma unroll
  for (int mi = 0; mi < 4; mi++){
    #pragma unroll
    for (int nf = 0; nf < 2; nf++){
      int c = colBase + wn + nf*16 + lm;
      #pragma unroll
      for (int r = 0; r < 4; r++){
        int m = rowBase + wm + mi*16 + lq*4 + r;
        float v = p.scale * acc[mi][nf][r];
        if (p.outN){
          __hip_bfloat16 hi = __float2bfloat16(v);
          p.outN[zo + (long long)m*256 + c] = hi;
          p.outN[p.PS + zo + (long long)m*256 + c] = __float2bfloat16(v - __bfloat162float(hi));
        }
        if (p.outT){
          float w = p.alphaT * (m == c ? 1.f : 0.f) + p.sT * v;
          __hip_bfloat16 hi = __float2bfloat16(w);
          p.outT[zo + (long long)c*256 + m] = hi;
          p.outT[p.PS + zo + (long long)c*256 + m] = __float2bfloat16(w - __bfloat162float(hi));
        }
      }
    }
  }
}

// ================= fused sim1: S=0.125*Q@KL^T, softmax, O=P@ZV ============
// grid (NPAD/64, 32). Per-wave 16 rows; softmax within wave (shfl over lm);
// P round-trips LDS (XOR-swizzled 8-elem chunks), same-wave -> no barrier.
__global__ __launch_bounds__(256) void sim1_fused(const __hip_bfloat16* QKV,
    const __hip_bfloat16* KL, const __hip_bfloat16* ZVT, float* OUT1){
  __shared__ __align__(16) __hip_bfloat16 Ps[64*256];
  int z = blockIdx.y, b = z >> 3, h = z & 7;
  int n0 = blockIdx.x * 64;
  int t = threadIdx.x, lane = t & 63;
  int wv = __builtin_amdgcn_readfirstlane(t >> 6);
  int lm = lane & 15, lq = lane >> 4;
  const __hip_bfloat16* Qb = QKV + (long long)b*QE + h*64;
  const __hip_bfloat16* Kb = KL + (long long)z*NLM*64;
  const __hip_bfloat16* Zb = ZVT + (long long)z*64*256;

  // ---- S = Q @ KL^T (per wave: rows wv*16..+16, all 256 landmark cols)
  float4_t sacc[16];
  #pragma unroll
  for (int nf = 0; nf < 16; nf++) sacc[nf] = (float4_t)0.f;
  int qrow = n0 + wv*16 + lm;
  #pragma unroll
  for (int ks = 0; ks < 2; ks++){
    short8_t a = *(const short8_t*)(Qb + (long long)qrow*1536 + ks*32 + lq*8);
    #pragma unroll
    for (int nf = 0; nf < 16; nf++){
      short8_t bb = *(const short8_t*)(Kb + (nf*16 + lm)*64 + ks*32 + lq*8);
      sacc[nf] = __builtin_amdgcn_mfma_f32_16x16x32_bf16(a, bb, sacc[nf], 0, 0, 0);
    }
  }
  // ---- softmax per row (row = wv*16 + lq*4 + reg; 256 vals over 16 nf x 16 lm)
  #pragma unroll
  for (int reg = 0; reg < 4; reg++){
    float mx = -1e30f;
    #pragma unroll
    for (int nf = 0; nf < 16; nf++){
      sacc[nf][reg] *= 0.125f;
      mx = fmaxf(mx, sacc[nf][reg]);
    }
    #pragma unroll
    for (int m = 1; m <= 8; m <<= 1) mx = fmaxf(mx, __shfl_xor(mx, m));
    float sum = 0.f;
    #pragma unroll
    for (int nf = 0; nf < 16; nf++){
      float e = __expf(sacc[nf][reg] - mx);
      sacc[nf][reg] = e; sum += e;
    }
    #pragma unroll
    for (int m = 1; m <= 8; m <<= 1) sum += __shfl_xor(sum, m);
    float inv = 1.f / sum;
    int row = wv*16 + lq*4 + reg;
    #pragma unroll
    for (int nf = 0; nf < 16; nf++){
      int col = nf*16 + lm;
      int chunk = (col >> 3) ^ (row & 7);
      Ps[row*256 + chunk*8 + (col & 7)] = __float2bfloat16(sacc[nf][reg] * inv);
    }
  }
  // ---- O = P @ ZV  (A from LDS, same-wave rows; B = ZVT [64][256] global)
  float4_t oacc[4];
  #pragma unroll
  for (int nf = 0; nf < 4; nf++) oacc[nf] = (float4_t)0.f;
  int prow = wv*16 + lm;
  #pragma unroll
  for (int ks = 0; ks < 8; ks++){
    int chunk = (ks*4 + lq) ^ (lm & 7);
    short8_t a = *(const short8_t*)&Ps[prow*256 + chunk*8];
    #pragma unroll
    for (int nf = 0; nf < 4; nf++){
      short8_t bb = *(const short8_t*)(Zb + (nf*16 + lm)*256 + ks*32 + lq*8);
      oacc[nf] = __builtin_amdgcn_mfma_f32_16x16x32_bf16(a, bb, oacc[nf], 0, 0, 0);
    }
  }
  #pragma unroll
  for (int nf = 0; nf < 4; nf++){
    #pragma unroll
    for (int reg = 0; reg < 4; reg++){
      int tok = n0 + wv*16 + lq*4 + reg;
      OUT1[((long long)b*NPAD + tok)*D_ + h*64 + nf*16 + lm] = oacc[nf][reg];
    }
  }
}

// ============================= softmax ====================================
template<int LEN>
__global__ __launch_bounds__(256) void softmax_rows_b(__hip_bfloat16* S){
  constexpr int VPT = LEN / 256;
  __hip_bfloat16* p = S + (long long)blockIdx.x * LEN;
  int t = threadIdx.x;
  float v[VPT]; float m = -1e30f;
  #pragma unroll
  for (int q = 0; q < VPT; q++){ v[q] = __bfloat162float(p[t + 256*q]); m = fmaxf(m, v[q]); }
  __shared__ float red[256];
  red[t] = m; __syncthreads();
  for (int s = 128; s; s >>= 1){ if (t < s) red[t] = fmaxf(red[t], red[t+s]); __syncthreads(); }
  m = red[0]; __syncthreads();
  float sum = 0.f;
  #pragma unroll
  for (int q = 0; q < VPT; q++){ v[q] = __expf(v[q] - m); sum += v[q]; }
  red[t] = sum; __syncthreads();
  for (int s = 128; s; s >>= 1){ if (t < s) red[t] += red[t+s]; __syncthreads(); }
  float inv = 1.f / red[0];
  #pragma unroll
  for (int q = 0; q < VPT; q++) p[t + 256*q] = __float2bfloat16(v[q] * inv);
}

__global__ __launch_bounds__(256) void softmax256_split(float* S, __hip_bfloat16* P, long long PS){
  long long row = blockIdx.x;
  float* p = S + row * 256;
  int t = threadIdx.x;
  float v = p[t];
  __shared__ float red[256];
  red[t] = v; __syncthreads();
  for (int s = 128; s; s >>= 1){ if (t < s) red[t] = fmaxf(red[t], red[t+s]); __syncthreads(); }
  float m = red[0]; __syncthreads();
  float e = __expf(v - m);
  red[t] = e; __syncthreads();
  for (int s = 128; s; s >>= 1){ if (t < s) red[t] += red[t+s]; __syncthreads(); }
  float r = e / red[0];
  p[t] = r;
  __hip_bfloat16 hi = __float2bfloat16(r);
  P[row*256 + t] = hi;
  P[PS + row*256 + t] = __float2bfloat16(r - __bfloat162float(hi));
}

// ============================ LN / misc ===================================
__global__ __launch_bounds__(256) void ln_pad(const float* H, __hip_bfloat16* X,
                                              const float* g, const float* bb){
  int p = blockIdx.x, b = blockIdx.y, t = threadIdx.x;
  __hip_bfloat16* xo = X + ((long long)b * NPAD + p) * D_;
  if (p < PADF){ xo[t] = __float2bfloat16(0.f); xo[t + 256] = __float2bfloat16(0.f); return; }
  const float* hi = H + ((long long)b * NTOK + (p - PADF)) * D_;
  float x0 = hi[t], x1 = hi[t + 256];
  __shared__ float r1[256], r2[256];
  r1[t] = x0 + x1; r2[t] = x0*x0 + x1*x1;
  __syncthreads();
  for (int s = 128; s; s >>= 1){ if (t < s){ r1[t] += r1[t+s]; r2[t] += r2[t+s]; } __syncthreads(); }
  float mu = r1[0] * (1.f / D_);
  float var = r2[0] * (1.f / D_) - mu*mu;
  float rs = rsqrtf(var + 1e-5f);
  xo[t]       = __float2bfloat16((x0 - mu) * rs * g[t]       + bb[t]);
  xo[t + 256] = __float2bfloat16((x1 - mu) * rs * g[t + 256] + bb[t + 256]);
}

__global__ __launch_bounds__(256) void final_ln(const float* H, const float* g,
                                                const float* bb, float* out){
  int b = blockIdx.x, t = threadIdx.x;
  const float* hi = H + (long long)b * NTOK * D_;
  float x0 = hi[t], x1 = hi[t + 256];
  __shared__ float r1[256], r2[256];
  r1[t] = x0 + x1; r2[t] = x0*x0 + x1*x1;
  __syncthreads();
  for (int s = 128; s; s >>= 1){ if (t < s){ r1[t] += r1[t+s]; r2[t] += r2[t+s]; } __syncthreads(); }
  float mu = r1[0] * (1.f / D_);
  float var = r2[0] * (1.f / D_) - mu*mu;
  float rs = rsqrtf(var + 1e-5f);
  out[b*D_ + t]       = (x0 - mu) * rs * g[t]       + bb[t];
  out[b*D_ + t + 256] = (x1 - mu) * rs * g[t + 256] + bb[t + 256];
}

__global__ __launch_bounds__(256) void build_h(const float* h0, const float* cls, float* H){
  int tpos = blockIdx.x, b = blockIdx.y, t = threadIdx.x;
  float* dst = H + ((long long)b * NTOK + tpos) * D_;
  if (tpos == 0){ dst[t] = cls[t]; dst[t + 256] = cls[t + 256]; return; }
  int i = tpos - 1, src;
  if (i < 10)        src = i;
  else if (i < 179){ int j = i - 10;  src = 10  + (j < 160  ? j : j - 160);  }
  else             { int j = i - 179; src = 170 + (j < 6000 ? j : j - 6000); }
  const float* s = h0 + ((long long)b * N0 + src) * D_;
  dst[t] = s[t]; dst[t + 256] = s[t + 256];
}

__global__ __launch_bounds__(256) void cvt_pad_x(const float* x, __hip_bfloat16* Xb){
  int row = blockIdx.x, t = threadIdx.x;
  __hip_bfloat16* o = Xb + (long long)row * 768;
  if (row >= B_*N0){ o[t] = __float2bfloat16(0.f); o[t+256] = __float2bfloat16(0.f); o[t+512] = __float2bfloat16(0.f); return; }
  const float* s = x + (long long)row * 768;
  o[t]     = __float2bfloat16(s[t]);
  o[t+256] = __float2bfloat16(s[t+256]);
  o[t+512] = __float2bfloat16(s[t+512]);
}

__global__ __launch_bounds__(256) void tr_cvt(const void* in, int inbf, int ldin,
    long long iSO, long long iSI, int iIn, __hip_bfloat16* outp, long long oSO,
    int R, int C){
  __shared__ float sm[32][33];
  int z = blockIdx.z;
  long long ib = (long long)(z/iIn)*iSO + (long long)(z%iIn)*iSI;
  int r0 = blockIdx.y*32, c0 = blockIdx.x*32;
  int tx = threadIdx.x & 31, ty = threadIdx.x >> 5;
  for (int rr = ty; rr < 32; rr += 8)
    sm[rr][tx] = gload(in, inbf, ib + (long long)(r0+rr)*ldin + c0 + tx);
  __syncthreads();
  for (int cc = ty; cc < 32; cc += 8)
    outp[z*oSO + (long long)(c0+cc)*R + r0 + tx] = __float2bfloat16(sm[tx][cc]);
}

__global__ __launch_bounds__(256) void landmarks2(const __hip_bfloat16* QKV,
                                                  __hip_bfloat16* QL, __hip_bfloat16* KL){
  int j = blockIdx.x, b = blockIdx.y, t = threadIdx.x;
  const __hip_bfloat16* base = QKV + ((long long)b * NPAD + j*25) * 1536;
  float q0 = 0.f, q1 = 0.f, k0 = 0.f, k1 = 0.f;
  #pragma unroll 5
  for (int i = 0; i < 25; i++){
    const __hip_bfloat16* row = base + (long long)i*1536;
    q0 += __bfloat162float(row[t]);
    q1 += __bfloat162float(row[t + 256]);
    k0 += __bfloat162float(row[512 + t]);
    k1 += __bfloat162float(row[512 + t + 256]);
  }
  int h0 = t >> 6, d0 = t & 63;
  int h1 = (t + 256) >> 6, d1 = (t + 256) & 63;
  QL[((long long)(b*8 + h0) * NLM + j) * 64 + d0] = __float2bfloat16(q0 * 0.005f);
  QL[((long long)(b*8 + h1) * NLM + j) * 64 + d1] = __float2bfloat16(q1 * 0.005f);
  KL[((long long)(b*8 + h0) * NLM + j) * 64 + d0] = __float2bfloat16(k0 * 0.04f);
  KL[((long long)(b*8 + h1) * NLM + j) * 64 + d1] = __float2bfloat16(k1 * 0.04f);
}

__global__ void init_sc(float* sc){ sc[0] = 0.f; sc[1] = 0.f; }
__global__ __launch_bounds__(256) void fillz(float* p, int n){
  int i = blockIdx.x*256 + threadIdx.x; if (i < n) p[i] = 0.f;
}

__global__ __launch_bounds__(256) void colsum_max(const float* A2, float* sc){
  int z = blockIdx.x, t = threadIdx.x;
  const float* a = A2 + (long long)z * 65536;
  float s = 0.f;
  for (int i = 0; i < 256; i++) s += fabsf(a[i*256 + t]);
  __shared__ float red[256];
  red[t] = s; __syncthreads();
  for (int st = 128; st; st >>= 1){ if (t < st) red[t] = fmaxf(red[t], red[t+st]); __syncthreads(); }
  if (t == 0) atomicMaxF(sc + 0, red[0]);
}

__global__ __launch_bounds__(256) void rowsum_max(const float* A2, float* sc){
  int z = blockIdx.x, t = threadIdx.x, w = t >> 6, l = t & 63;
  const float* a = A2 + (long long)z * 65536;
  float mx = 0.f;
  for (int i = w*64; i < (w+1)*64; i++){
    float s = fabsf(a[i*256 + l]) + fabsf(a[i*256 + l + 64])
            + fabsf(a[i*256 + l + 128]) + fabsf(a[i*256 + l + 192]);
    for (int m = 32; m; m >>= 1) s += __shfl_xor(s, m);
    mx = fmaxf(mx, s);
  }
  __shared__ float red[4];
  if (l == 0) red[w] = mx;
  __syncthreads();
  if (t == 0) atomicMaxF(sc + 1, fmaxf(fmaxf(red[0], red[1]), fmaxf(red[2], red[3])));
}

__global__ __launch_bounds__(256) void zinit_split(const float* A2,
    __hip_bfloat16* ZN, __hip_bfloat16* ZT, long long PS, const float* sc){
  int j = blockIdx.x, z = blockIdx.y, i = threadIdx.x;
  float inv = 1.f / (sc[0] * sc[1]);
  float v = A2[(long long)z*65536 + i*256 + j] * inv;
  __hip_bfloat16 hi = __float2bfloat16(v);
  __hip_bfloat16 lo = __float2bfloat16(v - __bfloat162float(hi));
  long long zo = (long long)z*65536;
  ZN[zo + j*256 + i] = hi; ZN[PS + zo + j*256 + i] = lo;
  ZT[zo + i*256 + j] = hi; ZT[PS + zo + i*256 + j] = lo;
}

__global__ __launch_bounds__(256) void dwconv_cvt2(const __hip_bfloat16* QKV, const float* rw,
                                                   const float* OUT1, __hip_bfloat16* OUT1b){
  int t = threadIdx.x;
  int n = blockIdx.x*4 + (t >> 6);
  int b = blockIdx.y;
  int ch0 = (t & 63) * 8;
  int h = (t & 63) >> 3;
  float w[33];
  #pragma unroll
  for (int k = 0; k < 33; k++) w[k] = rw[h*33 + k];
  float acc[8] = {};
  const __hip_bfloat16* Vb = QKV + (long long)b * NPAD * 1536 + 1024 + ch0;
  #pragma unroll
  for (int k = 0; k < 33; k++){
    int nn = n + k - 16;
    if (nn < 0 || nn >= NPAD) continue;
    short8_t v8 = *(const short8_t*)(Vb + (long long)nn * 1536);
    #pragma unroll
    for (int j = 0; j < 8; j++) acc[j] += w[k] * b2f((ushort)v8[j]);
  }
  long long idx = ((long long)b * NPAD + n) * D_ + ch0;
  float4 o0 = *(const float4*)(OUT1 + idx);
  float4 o1 = *(const float4*)(OUT1 + idx + 4);
  short8_t o;
  o[0] = (short)f2b(o0.x + acc[0]); o[1] = (short)f2b(o0.y + acc[1]);
  o[2] = (short)f2b(o0.z + acc[2]); o[3] = (short)f2b(o0.w + acc[3]);
  o[4] = (short)f2b(o1.x + acc[4]); o[5] = (short)f2b(o1.y + acc[5]);
  o[6] = (short)f2b(o1.z + acc[6]); o[7] = (short)f2b(o1.w + acc[7]);
  *(short8_t*)((ushort*)OUT1b + idx) = o;
}

__global__ __launch_bounds__(512) void resid_add(float* H, const float* O2, const float* ob){
  int i = blockIdx.x, b = blockIdx.y, t = threadIdx.x;
  H[((long long)b * NTOK + i) * D_ + t] +=
      O2[((long long)b * NPAD + i + PADF) * D_ + t] + ob[t];
}

// ------------------------------ PPEG (32ch/block) --------------------------
__global__ __launch_bounds__(256) void transpose_w(const float* w, float* wt, int KK){
  int i = blockIdx.x*256 + threadIdx.x;
  if (i < 512*KK){ int ch = i / KK, k = i - ch*KK; wt[(long long)k*512 + ch] = w[i]; }
}

__global__ __launch_bounds__(256) void ppeg_tiled(const float* H, float* P,
    const float* t7, const float* t5, const float* t3,
    const float* b7, const float* b5, const float* b3,
    int base, int W, int tilesX){
  __shared__ float smem[196*32];   // 24.5 KB -> 6 blocks/CU
  int ty0 = (blockIdx.x / tilesX) * 8, tx0 = (blockIdx.x % tilesX) * 8;
  int c0 = blockIdx.y * 32, b = blockIdx.z;
  int t = threadIdx.x, ch = t & 31, pr = t >> 5;   // pr 0..7 = x within tile
  const float* Hb = H + ((long long)b * NTOK + base) * D_ + c0 + ch;
  for (int i = pr; i < 196; i += 8){
    int py = i / 14, px = i - py*14;
    int y = ty0 + py - 3, x = tx0 + px - 3;
    smem[i*32 + ch] = (y >= 0 && y < W && x >= 0 && x < W)
                      ? Hb[(long long)(y*W + x) * D_] : 0.f;
  }
  __syncthreads();
  float acc[8];
  float bsum = b7[c0+ch] + b5[c0+ch] + b3[c0+ch];
  #pragma unroll
  for (int y = 0; y < 8; y++)
    acc[y] = smem[((y+3)*14 + (pr+3))*32 + ch] + bsum;
  for (int ky = 0; ky < 7; ky++)
    for (int kx = 0; kx < 7; kx++){
      float wv = t7[(ky*7 + kx)*512 + c0 + ch];
      #pragma unroll
      for (int y = 0; y < 8; y++)
        acc[y] += wv * smem[((y+ky)*14 + (pr+kx))*32 + ch];
    }
  for (int ky = 0; ky < 5; ky++)
    for (int kx = 0; kx < 5; kx++){
      float wv = t5[(ky*5 + kx)*512 + c0 + ch];
      #pragma unroll
      for (int y = 0; y < 8; y++)
        acc[y] += wv * smem[((y+1+ky)*14 + (pr+1+kx))*32 + ch];
    }
  for (int ky = 0; ky < 3; ky++)
    for (int kx = 0; kx < 3; kx++){
      float wv = t3[(ky*3 + kx)*512 + c0 + ch];
      #pragma unroll
      for (int y = 0; y < 8; y++)
        acc[y] += wv * smem[((y+2+ky)*14 + (pr+2+kx))*32 + ch];
    }
  #pragma unroll
  for (int y = 0; y < 8; y++){
    int gy = ty0 + y, gx = tx0 + pr;
    if (gy < W && gx < W)
      P[((long long)b * W * W + gy*W + gx) * D_ + c0 + ch] = acc[y];
  }
}

__global__ __launch_bounds__(512) void ppeg_copy(float* H, const float* P, int base, int W){
  int pos = blockIdx.x, b = blockIdx.y, t = threadIdx.x;
  H[((long long)b * NTOK + base + pos) * D_ + t] = P[((long long)b * W * W + pos) * D_ + t];
}

// ============================== host side =================================
static void gemmB(hipStream_t st, int BN,
                  const __hip_bfloat16* A, int lda, long long aSO, long long aSI, int aIn,
                  const __hip_bfloat16* Bm, int ldb, long long bSO, long long bSI, int bIn,
                  void* C, int ldc, long long cSO, long long cSI, int cIn, int cbf,
                  int M, int N, int K, int batch,
                  const float* bias, float beta, int relu, int ksp = 1, int klen = 0){
  GB p;
  p.A = A; p.Bm = Bm; p.C = C; p.bias = bias;
  p.M = M; p.N = N; p.K = K; p.lda = lda; p.ldb = ldb; p.ldc = ldc;
  p.aSO = aSO; p.aSI = aSI; p.aIn = aIn;
  p.bSO = bSO; p.bSI = bSI; p.bIn = bIn;
  p.cSO = cSO; p.cSI = cSI; p.cIn = cIn; p.cbf = cbf;
  p.beta = beta; p.relu = relu; p.ksp = ksp; p.klen = (klen > 0) ? klen : K;
  dim3 g(N/BN, (M + 127)/128, batch * ksp), b(256);
  if (BN == 128) gemm_bt<128><<<g, b, 0, st>>>(p);
  else           gemm_bt<64><<<g, b, 0, st>>>(p);
}

static void gemmS(hipStream_t st, const ushort* A, const ushort* B,
                  ushort* oN, ushort* oT, float scale, float alphaT, float sT){
  GS p;
  p.A = (const __hip_bfloat16*)A; p.B = (const __hip_bfloat16*)B;
  p.outN = (__hip_bfloat16*)oN; p.outT = (__hip_bfloat16*)oT;
  p.PS = 2097152; p.scale = scale; p.alphaT = alphaT; p.sT = sT;
  dim3 g(4, 2, 32), b(256);
  gemm_bts<<<g, b, 0, st>>>(p);
}

extern "C" void kernel_launch(void* const* d_in, const int* in_sizes, int n_in,
                              void* d_out, int out_size, void* d_ws, size_t ws_size,
                              hipStream_t stream){
  const float* x      = (const float*)d_in[0];
  const float* fc1_w  = (const float*)d_in[1];
  const float* fc1_b  = (const float*)d_in[2];
  const float* cls    = (const float*)d_in[3];
  const float* l1_ng  = (const float*)d_in[4];
  const float* l1_nb  = (const float*)d_in[5];
  const float* l1_qkv = (const float*)d_in[6];
  const float* l1_ow  = (const float*)d_in[7];
  const float* l1_ob  = (const float*)d_in[8];
  const float* l1_rw  = (const float*)d_in[9];
  const float* ct_w7  = (const float*)d_in[10];
  const float* ct_b7  = (const float*)d_in[11];
  const float* ct_w5  = (const float*)d_in[12];
  const float* ct_b5  = (const float*)d_in[13];
  const float* ct_w3  = (const float*)d_in[14];
  const float* ct_b3  = (const float*)d_in[15];
  const float* pt_w7  = (const float*)d_in[16];
  const float* pt_b7  = (const float*)d_in[17];
  const float* pt_w5  = (const float*)d_in[18];
  const float* pt_b5  = (const float*)d_in[19];
  const float* pt_w3  = (const float*)d_in[20];
  const float* pt_b3  = (const float*)d_in[21];
  const float* l2_ng  = (const float*)d_in[22];
  const float* l2_nb  = (const float*)d_in[23];
  const float* l2_qkv = (const float*)d_in[24];
  const float* l2_ow  = (const float*)d_in[25];
  const float* l2_ob  = (const float*)d_in[26];
  const float* l2_rw  = (const float*)d_in[27];
  const float* nrm_g  = (const float*)d_in[28];
  const float* nrm_b  = (const float*)d_in[29];
  float* out = (float*)d_out;

  // ---- workspace layout (float units); SIMC last (flex-sized) ----
  float* ws    = (float*)d_ws;
  float* H     = ws;                      // 12,828,672
  float* BUF   = H + 12828672;            // 13,107,200
  float* QKVr  = BUF + 13107200;          // 19,660,800
  float* QLf   = QKVr + 19660800;         //    262,144
  float* KLf   = QLf + 262144;            //    262,144
  float* AV    = KLf + 262144;            //    524,288
  float* AVTf  = AV + 524288;             //    262,144
  float* ZVf   = AVTf + 262144;           //    262,144
  float* ZVTf  = ZVf + 262144;            //    262,144
  float* WQf   = ZVTf + 262144;           //    393,216
  float* WFf   = WQf + 393216;            //    196,608
  float* WOf   = WFf + 196608;            //    131,072
  float* PWT   = WOf + 131072;            //     84,992
  float* SC    = PWT + 84992;             //          8 (padded)
  float* SIMC  = SC + 8;                  //    rest of ws
  float* tc7 = PWT, *tc5 = tc7 + 49*512, *tc3 = tc5 + 25*512;
  float* tp7 = tc3 + 9*512, *tp5 = tp7 + 49*512, *tp3 = tp5 + 25*512;

  long long fixedB = (long long)((char*)SIMC - (char*)ws);
  long long availB = (long long)ws_size - fixedB;
  int G = (availB >= 104857600LL) ? 32 : (availB >= 52428800LL) ? 16 : 8;

  // pinv scratch: A2 f32 + hi/lo plane pairs (PS = 2,097,152 bf16 elems)
  float*  A2   = BUF;
  ushort* a2P  = (ushort*)(BUF + 2097152);
  ushort* zn_N = (ushort*)(BUF + 4194304);
  ushort* zn_T = (ushort*)(BUF + 6291456);
  ushort* zc_N = (ushort*)(BUF + 8388608);
  ushort* zc_T = (ushort*)(BUF + 10485760);
  ushort* azP  = (ushort*)SIMC;
  ushort* w1T  = (ushort*)SIMC + 4194304;
  ushort* w2T  = (ushort*)SIMC + 8388608;

  __hip_bfloat16* Xb    = (__hip_bfloat16*)QKVr;
  __hip_bfloat16* QKV   = (__hip_bfloat16*)QKVr;
  float*          PROJ  = QKVr;
  __hip_bfloat16* XLNb  = (__hip_bfloat16*)BUF;
  __hip_bfloat16* VT    = (__hip_bfloat16*)BUF;         // [32][64][6400]
  __hip_bfloat16* SIMCb = (__hip_bfloat16*)SIMC;
  __hip_bfloat16* OUT1b = (__hip_bfloat16*)SIMC;
  __hip_bfloat16* QLb   = (__hip_bfloat16*)QLf;
  __hip_bfloat16* KLb   = (__hip_bfloat16*)KLf;
  __hip_bfloat16* AVT   = (__hip_bfloat16*)AVTf;
  __hip_bfloat16* Zvb   = (__hip_bfloat16*)ZVf;
  __hip_bfloat16* ZVT   = (__hip_bfloat16*)ZVTf;
  __hip_bfloat16* WqkvT = (__hip_bfloat16*)WQf;
  __hip_bfloat16* Wfc1T = (__hip_bfloat16*)WFf;
  __hip_bfloat16* WoutT = (__hip_bfloat16*)WOf;

  // ---- one-time weight prep
  transpose_w<<<(512*49+255)/256, 256, 0, stream>>>(ct_w7, tc7, 49);
  transpose_w<<<(512*25+255)/256, 256, 0, stream>>>(ct_w5, tc5, 25);
  transpose_w<<<(512* 9+255)/256, 256, 0, stream>>>(ct_w3, tc3,  9);
  transpose_w<<<(512*49+255)/256, 256, 0, stream>>>(pt_w7, tp7, 49);
  transpose_w<<<(512*25+255)/256, 256, 0, stream>>>(pt_w5, tp5, 25);
  transpose_w<<<(512* 9+255)/256, 256, 0, stream>>>(pt_w3, tp3,  9);
  tr_cvt<<<dim3(512/32, 768/32, 1), 256, 0, stream>>>(fc1_w, 0, 512, 0,0,1, Wfc1T, 0, 768, 512);

  // ---- fc1 + relu -> h0 (BUF f32); gather into H
  cvt_pad_x<<<MFC1, 256, 0, stream>>>(x, Xb);
  gemmB(stream, 128, Xb, 768, 0,0,1, Wfc1T, 768, 0,0,1, BUF, 512, 0,0,1,0,
        MFC1, 512, 768, 1, fc1_b, 1.f, 1);
  build_h<<<dim3(NTOK, B_), 256, 0, stream>>>(BUF, cls, H);

  auto attn_layer = [&](const float* ng, const float* nb, const float* qkvw,
                        const float* outw, const float* outb, const float* resw){
    tr_cvt<<<dim3(1536/32, 512/32, 1), 256, 0, stream>>>(qkvw, 0, 1536, 0,0,1, WqkvT, 0, 512, 1536);
    tr_cvt<<<dim3(512/32, 512/32, 1), 256, 0, stream>>>(outw, 0, 512, 0,0,1, WoutT, 0, 512, 512);
    ln_pad<<<dim3(NPAD, B_), 256, 0, stream>>>(H, XLNb, ng, nb);
    gemmB(stream, 128, XLNb, 512, 0,0,1, WqkvT, 512, 0,0,1, QKV, 1536, 0,0,1,1,
          B_*NPAD, 1536, 512, 1, nullptr, 1.f, 0);
    landmarks2<<<dim3(NLM, B_), 256, 0, stream>>>(QKV, QLb, KLb);
    // a2 = softmax(q_l @ k_l^T): f32 + hi/lo planes
    gemmB(stream, 128, QLb, 64, 16384,0,1, KLb, 64, 16384,0,1, A2, 256, 65536,0,1,0,
          256, 256, 64, 32, nullptr, 1.f, 0);
    softmax256_split<<<B_*NH*NLM, 256, 0, stream>>>(A2, (__hip_bfloat16*)a2P, 2097152);
    // pinv (Newton-Schulz, 6 iters), fast split GEMMs with fused diag epilogues
    init_sc<<<1, 1, 0, stream>>>(SC);
    colsum_max<<<B_*NH, 256, 0, stream>>>(A2, SC);
    rowsum_max<<<B_*NH, 256, 0, stream>>>(A2, SC);
    zinit_split<<<dim3(256, 32), 256, 0, stream>>>(A2, (__hip_bfloat16*)zc_N,
          (__hip_bfloat16*)zc_T, 2097152, SC);
    ushort *cN = zc_N, *cT = zc_T, *nN = zn_N, *nT = zn_T;
    for (int it = 0; it < 6; it++){
      gemmS(stream, a2P, cT, azP, w1T, 1.f, 7.f, -1.f);
      gemmS(stream, azP, w1T, nullptr, w2T, 1.f, 15.f, -1.f);
      gemmS(stream, azP, w2T, nullptr, w1T, 1.f, 13.f, -1.f);
      gemmS(stream, cN, w1T, nN, nT, 0.25f, 0.f, 1.f);
      ushort* s;
      s = cN; cN = nN; nN = s;
      s = cT; cT = nT; nT = s;
    }
    const __hip_bfloat16* Zcb = (const __hip_bfloat16*)cN;
    // V^T per head into BUF (pinv scratch dead except final Z planes)
    tr_cvt<<<dim3(64/32, NPAD/32, 32), 256, 0, stream>>>(QKV + 1024, 1, 1536,
          QE, 64, 8, VT, (long long)64*NPAD, NPAD, 64);
    fillz<<<2048, 256, 0, stream>>>(AV, 524288);
    // sim3 -> softmax -> AV, G bh per pass
    for (int c0 = 0; c0 < 32; c0 += G){
      int b0 = c0 >> 3;
      const __hip_bfloat16* Kp = QKV + (long long)b0*QE + 512;
      gemmB(stream, 128, QLb + (long long)c0*16384, 64, 16384,0,1,
            Kp, 1536, QE,64,8,
            SIMCb, NPAD, (long long)256*NPAD,0,1,1,
            256, NPAD, 64, G, nullptr, 1.f, 0);
      softmax_rows_b<NPAD><<<G*NLM, 256, 0, stream>>>(SIMCb);
      gemmB(stream, 64, SIMCb, NPAD, (long long)256*NPAD,0,1,
            VT + (long long)c0*64*NPAD, NPAD, (long long)64*NPAD,0,1,
            AV + (long long)c0*16384, 64, 16384,0,1,0,
            256, 64, NPAD, G, nullptr, 1.f, 0, 10, 640);
    }
    // AV^T, ZV = Zc@AV (bf16 out), ZV^T
    tr_cvt<<<dim3(64/32, 256/32, 32), 256, 0, stream>>>(AV, 0, 64, 16384,0,1,
          AVT, 16384, 256, 64);
    gemmB(stream, 64, Zcb, 256, 65536,0,1, AVT, 256, 16384,0,1,
          Zvb, 64, 16384,0,1,1, 256, 64, 256, 32, nullptr, 1.f, 0);
    tr_cvt<<<dim3(64/32, 256/32, 32), 256, 0, stream>>>(Zvb, 1, 64, 16384,0,1,
          ZVT, 16384, 256, 64);
    // fused sim1: OUT1 f32 into BUF (VT/Z dead after ZV)
    sim1_fused<<<dim3(NPAD/64, 32), 256, 0, stream>>>(QKV, KLb, ZVT, BUF);
    // + depthwise conv residual -> bf16, projection, residual add
    dwconv_cvt2<<<dim3(NPAD/4, B_), 256, 0, stream>>>(QKV, resw, BUF, OUT1b);
    gemmB(stream, 128, OUT1b, 512, 0,0,1, WoutT, 512, 0,0,1, PROJ, 512, 0,0,1,0,
          B_*NPAD, 512, 512, 1, nullptr, 1.f, 0);
    resid_add<<<dim3(NTOK, B_), 512, 0, stream>>>(H, PROJ, outb);
  };

  // ---- layer 1
  attn_layer(l1_ng, l1_nb, l1_qkv, l1_ow, l1_ob, l1_rw);

  // ---- PPEG (32-ch blocks)
  ppeg_tiled<<<dim3(4, 16, B_), 256, 0, stream>>>(H, BUF, tc7, tc5, tc3, ct_b7, ct_b5, ct_b3, 11, 13, 2);
  ppeg_copy<<<dim3(169, B_), 512, 0, stream>>>(H, BUF, 11, 13);
  ppeg_tiled<<<dim3(100, 16, B_), 256, 0, stream>>>(H, BUF, tp7, tp5, tp3, pt_b7, pt_b5, pt_b3, 180, 78, 10);
  ppeg_copy<<<dim3(6084, B_), 512, 0, stream>>>(H, BUF, 180, 78);

  // ---- layer 2
  attn_layer(l2_ng, l2_nb, l2_qkv, l2_ow, l2_ob, l2_rw);

  // ---- final LN on cls token
  final_ln<<<B_, 256, 0, stream>>>(H, nrm_g, nrm_b, out);
}

// Round 7
// 2536.790 us; speedup vs baseline: 4.8079x; 1.0510x over previous
//
#include <hip/hip_runtime.h>
#include <hip/hip_bf16.h>
#include <cstdint>

#define B_   4
#define NTOK 6264
#define NPAD 6400
#define D_   512
#define NH   8
#define NLM  256
#define N0   6170
#define PADF (NPAD - NTOK)   // 136
#define MFC1 24704           // B_*N0 padded to x128
#define QE   ((long long)NPAD * 1536)

typedef __attribute__((ext_vector_type(8))) short short8_t;
typedef __attribute__((ext_vector_type(4))) float float4_t;

__device__ __forceinline__ ushort f2b(float x){
  __hip_bfloat16 h = __float2bfloat16(x); return *(ushort*)&h;
}
__device__ __forceinline__ float b2f(ushort u){
  __hip_bfloat16 h = *(__hip_bfloat16*)&u; return __bfloat162float(h);
}
__device__ __forceinline__ float gload(const void* p, int bf, long long i){
  return bf ? __bfloat162float(((const __hip_bfloat16*)p)[i]) : ((const float*)p)[i];
}
__device__ __forceinline__ void atomicMaxF(float* a, float v){
  atomicMax((int*)a, __float_as_int(v));
}
__device__ __forceinline__ void gl_lds16(const void* g, void* l){
  __builtin_amdgcn_global_load_lds(
      (const __attribute__((address_space(1))) void*)g,
      (__attribute__((address_space(3))) void*)l, 16, 0, 0);
}

// ===================== fast bf16 NT GEMM (m97-style) ======================
struct GB {
  const __hip_bfloat16* A; const __hip_bfloat16* Bm; void* C; const float* bias;
  int M, N, K, lda, ldb, ldc;
  long long aSO, aSI; int aIn;
  long long bSO, bSI; int bIn;
  long long cSO, cSI; int cIn;
  float beta; int cbf, relu, ksp, klen;
};

template<int BN>
__global__ __launch_bounds__(256) void gemm_bt(GB p){
  __shared__ __align__(16) __hip_bfloat16 As[128*64];
  __shared__ __align__(16) __hip_bfloat16 Bs[BN*64];
  int zz = blockIdx.z;
  int z = zz / p.ksp, ks = zz - z*p.ksp;
  int k0 = ks * p.klen;
  int kend = k0 + p.klen; if (kend > p.K) kend = p.K;
  const __hip_bfloat16* A  = p.A  + (long long)(z/p.aIn)*p.aSO + (long long)(z%p.aIn)*p.aSI;
  const __hip_bfloat16* Bm = p.Bm + (long long)(z/p.bIn)*p.bSO + (long long)(z%p.bIn)*p.bSI;
  long long cOff = (long long)(z/p.cIn)*p.cSO + (long long)(z%p.cIn)*p.cSI;
  int rowBase = blockIdx.y*128, colBase = blockIdx.x*BN;
  int t = threadIdx.x, lane = t & 63;
  int wv = __builtin_amdgcn_readfirstlane(t >> 6);
  int lm = lane & 15, lq = lane >> 4;
  int dr = lane >> 3, dc = lane & 7;
  constexpr int NF = (BN == 128) ? 4 : 2;
  int wm = (wv >> 1) * 64;
  int wn = (BN == 128) ? (wv & 1) * 64 : (wv & 1) * 32;
  float4_t acc[4][NF];
  #pragma unroll
  for (int mi = 0; mi < 4; mi++)
    #pragma unroll
    for (int nf = 0; nf < NF; nf++) acc[mi][nf] = (float4_t)0.f;

  for (int kb = k0; kb < kend; kb += 64){
    #pragma unroll
    for (int d = 0; d < 4; d++){
      int rg = wv*4 + d;
      int row = rg*8 + dr;
      int cc = dc ^ (row & 7);
      gl_lds16(A + (long long)(rowBase + row)*p.lda + kb + cc*8, &As[rg*8*64]);
    }
    #pragma unroll
    for (int d = 0; d < BN/32; d++){
      int rg = wv*(BN/32) + d;
      int row = rg*8 + dr;
      int cc = dc ^ (row & 7);
      gl_lds16(Bm + (long long)(colBase + row)*p.ldb + kb + cc*8, &Bs[rg*8*64]);
    }
    __syncthreads();
    short8_t af[2][4]; short8_t bfv[2][NF];
    #pragma unroll
    for (int ks2 = 0; ks2 < 2; ks2++){
      #pragma unroll
      for (int mi = 0; mi < 4; mi++){
        int r = wm + mi*16 + lm;
        int s = (ks2*4 + lq) ^ (r & 7);
        af[ks2][mi] = *(const short8_t*)&As[r*64 + s*8];
      }
      #pragma unroll
      for (int nf = 0; nf < NF; nf++){
        int r = wn + nf*16 + lm;
        int s = (ks2*4 + lq) ^ (r & 7);
        bfv[ks2][nf] = *(const short8_t*)&Bs[r*64 + s*8];
      }
    }
    #pragma unroll
    for (int ks2 = 0; ks2 < 2; ks2++)
      #pragma unroll
      for (int mi = 0; mi < 4; mi++)
        #pragma unroll
        for (int nf = 0; nf < NF; nf++)
          acc[mi][nf] = __builtin_amdgcn_mfma_f32_16x16x32_bf16(af[ks2][mi], bfv[ks2][nf], acc[mi][nf], 0, 0, 0);
    __syncthreads();
  }
  #pragma unroll
  for (int mi = 0; mi < 4; mi++){
    #pragma unroll
    for (int nf = 0; nf < NF; nf++){
      int c = colBase + wn + nf*16 + lm;
      #pragma unroll
      for (int r = 0; r < 4; r++){
        int m = rowBase + wm + mi*16 + lq*4 + r;
        if (m >= p.M) continue;
        float v = p.beta * acc[mi][nf][r];
        long long ci = cOff + (long long)m*p.ldc + c;
        if (p.ksp > 1){
          atomicAdd((float*)p.C + ci, v);
        } else {
          if (p.bias) v += p.bias[c];
          if (p.relu) v = fmaxf(v, 0.f);
          if (p.cbf) ((__hip_bfloat16*)p.C)[ci] = __float2bfloat16(v);
          else       ((float*)p.C)[ci] = v;
        }
      }
    }
  }
}

// ============== fast split (hi/lo) GEMM for pinv: 64x64 tiles, batch 32 ====
struct GS {
  const __hip_bfloat16* A; const __hip_bfloat16* B;
  __hip_bfloat16* outN; __hip_bfloat16* outT;
  long long PS;
  float scale, alphaT, sT;
};

__global__ __launch_bounds__(256) void gemm_bts(GS p){
  __shared__ __align__(16) __hip_bfloat16 Ah[64*64];
  __shared__ __align__(16) __hip_bfloat16 Al[64*64];
  __shared__ __align__(16) __hip_bfloat16 Bh[64*64];
  __shared__ __align__(16) __hip_bfloat16 Bl[64*64];
  int z = blockIdx.z;
  long long zo = (long long)z * 65536;
  const __hip_bfloat16* A = p.A + zo;
  const __hip_bfloat16* B = p.B + zo;
  int rowBase = blockIdx.y*64, colBase = blockIdx.x*64;
  int t = threadIdx.x, lane = t & 63;
  int wv = __builtin_amdgcn_readfirstlane(t >> 6);
  int lm = lane & 15, lq = lane >> 4;
  int dr = lane >> 3, dc = lane & 7;
  int wm = (wv >> 1) * 32, wn = (wv & 1) * 32;
  float4_t acc[2][2];
  #pragma unroll
  for (int mi = 0; mi < 2; mi++){ acc[mi][0] = (float4_t)0.f; acc[mi][1] = (float4_t)0.f; }

  for (int kb = 0; kb < 256; kb += 64){
    #pragma unroll
    for (int d = 0; d < 2; d++){
      int rg = wv*2 + d;
      int row = rg*8 + dr;
      int cc = dc ^ (row & 7);
      gl_lds16(A +        (long long)(rowBase + row)*256 + kb + cc*8, &Ah[rg*8*64]);
      gl_lds16(A + p.PS + (long long)(rowBase + row)*256 + kb + cc*8, &Al[rg*8*64]);
      gl_lds16(B +        (long long)(colBase + row)*256 + kb + cc*8, &Bh[rg*8*64]);
      gl_lds16(B + p.PS + (long long)(colBase + row)*256 + kb + cc*8, &Bl[rg*8*64]);
    }
    __syncthreads();
    #pragma unroll
    for (int ks2 = 0; ks2 < 2; ks2++){
      short8_t ah[2], al2[2], bh[2], bl2[2];
      #pragma unroll
      for (int mi = 0; mi < 2; mi++){
        int r = wm + mi*16 + lm;
        int s = (ks2*4 + lq) ^ (r & 7);
        ah[mi]  = *(const short8_t*)&Ah[r*64 + s*8];
        al2[mi] = *(const short8_t*)&Al[r*64 + s*8];
      }
      #pragma unroll
      for (int nf = 0; nf < 2; nf++){
        int r = wn + nf*16 + lm;
        int s = (ks2*4 + lq) ^ (r & 7);
        bh[nf]  = *(const short8_t*)&Bh[r*64 + s*8];
        bl2[nf] = *(const short8_t*)&Bl[r*64 + s*8];
      }
      #pragma unroll
      for (int mi = 0; mi < 2; mi++)
        #pragma unroll
        for (int nf = 0; nf < 2; nf++){
          acc[mi][nf] = __builtin_amdgcn_mfma_f32_16x16x32_bf16(ah[mi],  bh[nf],  acc[mi][nf], 0, 0, 0);
          acc[mi][nf] = __builtin_amdgcn_mfma_f32_16x16x32_bf16(ah[mi],  bl2[nf], acc[mi][nf], 0, 0, 0);
          acc[mi][nf] = __builtin_amdgcn_mfma_f32_16x16x32_bf16(al2[mi], bh[nf],  acc[mi][nf], 0, 0, 0);
        }
    }
    __syncthreads();
  }
  #pragma unroll
  for (int mi = 0; mi < 2; mi++){
    #pragma unroll
    for (int nf = 0; nf < 2; nf++){
      int c = colBase + wn + nf*16 + lm;
      #pragma unroll
      for (int r = 0; r < 4; r++){
        int m = rowBase + wm + mi*16 + lq*4 + r;
        float v = p.scale * acc[mi][nf][r];
        if (p.outN){
          __hip_bfloat16 hi = __float2bfloat16(v);
          p.outN[zo + (long long)m*256 + c] = hi;
          p.outN[p.PS + zo + (long long)m*256 + c] = __float2bfloat16(v - __bfloat162float(hi));
        }
        if (p.outT){
          float w = p.alphaT * (m == c ? 1.f : 0.f) + p.sT * v;
          __hip_bfloat16 hi = __float2bfloat16(w);
          p.outT[zo + (long long)c*256 + m] = hi;
          p.outT[p.PS + zo + (long long)c*256 + m] = __float2bfloat16(w - __bfloat162float(hi));
        }
      }
    }
  }
}

// ================= fused sim1: S=0.125*Q@KL^T, softmax, O=P@ZV ============
__global__ __launch_bounds__(256) void sim1_fused(const __hip_bfloat16* QKV,
    const __hip_bfloat16* KL, const __hip_bfloat16* ZVT, float* OUT1){
  __shared__ __align__(16) __hip_bfloat16 Ps[64*256];
  int z = blockIdx.y, b = z >> 3, h = z & 7;
  int n0 = blockIdx.x * 64;
  int t = threadIdx.x, lane = t & 63;
  int wv = __builtin_amdgcn_readfirstlane(t >> 6);
  int lm = lane & 15, lq = lane >> 4;
  const __hip_bfloat16* Qb = QKV + (long long)b*QE + h*64;
  const __hip_bfloat16* Kb = KL + (long long)z*NLM*64;
  const __hip_bfloat16* Zb = ZVT + (long long)z*64*256;

  float4_t sacc[16];
  #pragma unroll
  for (int nf = 0; nf < 16; nf++) sacc[nf] = (float4_t)0.f;
  int qrow = n0 + wv*16 + lm;
  #pragma unroll
  for (int ks = 0; ks < 2; ks++){
    short8_t a = *(const short8_t*)(Qb + (long long)qrow*1536 + ks*32 + lq*8);
    #pragma unroll
    for (int nf = 0; nf < 16; nf++){
      short8_t bb = *(const short8_t*)(Kb + (nf*16 + lm)*64 + ks*32 + lq*8);
      sacc[nf] = __builtin_amdgcn_mfma_f32_16x16x32_bf16(a, bb, sacc[nf], 0, 0, 0);
    }
  }
  #pragma unroll
  for (int reg = 0; reg < 4; reg++){
    float mx = -1e30f;
    #pragma unroll
    for (int nf = 0; nf < 16; nf++){
      sacc[nf][reg] *= 0.125f;
      mx = fmaxf(mx, sacc[nf][reg]);
    }
    #pragma unroll
    for (int m = 1; m <= 8; m <<= 1) mx = fmaxf(mx, __shfl_xor(mx, m));
    float sum = 0.f;
    #pragma unroll
    for (int nf = 0; nf < 16; nf++){
      float e = __expf(sacc[nf][reg] - mx);
      sacc[nf][reg] = e; sum += e;
    }
    #pragma unroll
    for (int m = 1; m <= 8; m <<= 1) sum += __shfl_xor(sum, m);
    float inv = 1.f / sum;
    int row = wv*16 + lq*4 + reg;
    #pragma unroll
    for (int nf = 0; nf < 16; nf++){
      int col = nf*16 + lm;
      int chunk = (col >> 3) ^ (row & 7);
      Ps[row*256 + chunk*8 + (col & 7)] = __float2bfloat16(sacc[nf][reg] * inv);
    }
  }
  float4_t oacc[4];
  #pragma unroll
  for (int nf = 0; nf < 4; nf++) oacc[nf] = (float4_t)0.f;
  int prow = wv*16 + lm;
  #pragma unroll
  for (int ks = 0; ks < 8; ks++){
    int chunk = (ks*4 + lq) ^ (lm & 7);
    short8_t a = *(const short8_t*)&Ps[prow*256 + chunk*8];
    #pragma unroll
    for (int nf = 0; nf < 4; nf++){
      short8_t bb = *(const short8_t*)(Zb + (nf*16 + lm)*256 + ks*32 + lq*8);
      oacc[nf] = __builtin_amdgcn_mfma_f32_16x16x32_bf16(a, bb, oacc[nf], 0, 0, 0);
    }
  }
  #pragma unroll
  for (int nf = 0; nf < 4; nf++){
    #pragma unroll
    for (int reg = 0; reg < 4; reg++){
      int tok = n0 + wv*16 + lq*4 + reg;
      OUT1[((long long)b*NPAD + tok)*D_ + h*64 + nf*16 + lm] = oacc[nf][reg];
    }
  }
}

// ============================= softmax ====================================
template<int LEN>
__global__ __launch_bounds__(256) void softmax_rows_b(__hip_bfloat16* S){
  constexpr int VPT = LEN / 256;
  __hip_bfloat16* p = S + (long long)blockIdx.x * LEN;
  int t = threadIdx.x;
  float v[VPT]; float m = -1e30f;
  #pragma unroll
  for (int q = 0; q < VPT; q++){ v[q] = __bfloat162float(p[t + 256*q]); m = fmaxf(m, v[q]); }
  __shared__ float red[256];
  red[t] = m; __syncthreads();
  for (int s = 128; s; s >>= 1){ if (t < s) red[t] = fmaxf(red[t], red[t+s]); __syncthreads(); }
  m = red[0]; __syncthreads();
  float sum = 0.f;
  #pragma unroll
  for (int q = 0; q < VPT; q++){ v[q] = __expf(v[q] - m); sum += v[q]; }
  red[t] = sum; __syncthreads();
  for (int s = 128; s; s >>= 1){ if (t < s) red[t] += red[t+s]; __syncthreads(); }
  float inv = 1.f / red[0];
  #pragma unroll
  for (int q = 0; q < VPT; q++) p[t + 256*q] = __float2bfloat16(v[q] * inv);
}

__global__ __launch_bounds__(256) void softmax256_split(float* S, __hip_bfloat16* P, long long PS){
  long long row = blockIdx.x;
  float* p = S + row * 256;
  int t = threadIdx.x;
  float v = p[t];
  __shared__ float red[256];
  red[t] = v; __syncthreads();
  for (int s = 128; s; s >>= 1){ if (t < s) red[t] = fmaxf(red[t], red[t+s]); __syncthreads(); }
  float m = red[0]; __syncthreads();
  float e = __expf(v - m);
  red[t] = e; __syncthreads();
  for (int s = 128; s; s >>= 1){ if (t < s) red[t] += red[t+s]; __syncthreads(); }
  float r = e / red[0];
  p[t] = r;
  __hip_bfloat16 hi = __float2bfloat16(r);
  P[row*256 + t] = hi;
  P[PS + row*256 + t] = __float2bfloat16(r - __bfloat162float(hi));
}

// ============================ LN / misc ===================================
__global__ __launch_bounds__(256) void ln_pad(const float* H, __hip_bfloat16* X,
                                              const float* g, const float* bb){
  int p = blockIdx.x, b = blockIdx.y, t = threadIdx.x;
  __hip_bfloat16* xo = X + ((long long)b * NPAD + p) * D_;
  if (p < PADF){ xo[t] = __float2bfloat16(0.f); xo[t + 256] = __float2bfloat16(0.f); return; }
  const float* hi = H + ((long long)b * NTOK + (p - PADF)) * D_;
  float x0 = hi[t], x1 = hi[t + 256];
  __shared__ float r1[256], r2[256];
  r1[t] = x0 + x1; r2[t] = x0*x0 + x1*x1;
  __syncthreads();
  for (int s = 128; s; s >>= 1){ if (t < s){ r1[t] += r1[t+s]; r2[t] += r2[t+s]; } __syncthreads(); }
  float mu = r1[0] * (1.f / D_);
  float var = r2[0] * (1.f / D_) - mu*mu;
  float rs = rsqrtf(var + 1e-5f);
  xo[t]       = __float2bfloat16((x0 - mu) * rs * g[t]       + bb[t]);
  xo[t + 256] = __float2bfloat16((x1 - mu) * rs * g[t + 256] + bb[t + 256]);
}

__global__ __launch_bounds__(256) void final_ln(const float* H, const float* g,
                                                const float* bb, float* out){
  int b = blockIdx.x, t = threadIdx.x;
  const float* hi = H + (long long)b * NTOK * D_;
  float x0 = hi[t], x1 = hi[t + 256];
  __shared__ float r1[256], r2[256];
  r1[t] = x0 + x1; r2[t] = x0*x0 + x1*x1;
  __syncthreads();
  for (int s = 128; s; s >>= 1){ if (t < s){ r1[t] += r1[t+s]; r2[t] += r2[t+s]; } __syncthreads(); }
  float mu = r1[0] * (1.f / D_);
  float var = r2[0] * (1.f / D_) - mu*mu;
  float rs = rsqrtf(var + 1e-5f);
  out[b*D_ + t]       = (x0 - mu) * rs * g[t]       + bb[t];
  out[b*D_ + t + 256] = (x1 - mu) * rs * g[t + 256] + bb[t + 256];
}

__global__ __launch_bounds__(256) void build_h(const float* h0, const float* cls, float* H){
  int tpos = blockIdx.x, b = blockIdx.y, t = threadIdx.x;
  float* dst = H + ((long long)b * NTOK + tpos) * D_;
  if (tpos == 0){ dst[t] = cls[t]; dst[t + 256] = cls[t + 256]; return; }
  int i = tpos - 1, src;
  if (i < 10)        src = i;
  else if (i < 179){ int j = i - 10;  src = 10  + (j < 160  ? j : j - 160);  }
  else             { int j = i - 179; src = 170 + (j < 6000 ? j : j - 6000); }
  const float* s = h0 + ((long long)b * N0 + src) * D_;
  dst[t] = s[t]; dst[t + 256] = s[t + 256];
}

__global__ __launch_bounds__(256) void cvt_pad_x(const float* x, __hip_bfloat16* Xb){
  int row = blockIdx.x, t = threadIdx.x;
  __hip_bfloat16* o = Xb + (long long)row * 768;
  if (row >= B_*N0){ o[t] = __float2bfloat16(0.f); o[t+256] = __float2bfloat16(0.f); o[t+512] = __float2bfloat16(0.f); return; }
  const float* s = x + (long long)row * 768;
  o[t]     = __float2bfloat16(s[t]);
  o[t+256] = __float2bfloat16(s[t+256]);
  o[t+512] = __float2bfloat16(s[t+512]);
}

__global__ __launch_bounds__(256) void tr_cvt(const void* in, int inbf, int ldin,
    long long iSO, long long iSI, int iIn, __hip_bfloat16* outp, long long oSO,
    int R, int C){
  __shared__ float sm[32][33];
  int z = blockIdx.z;
  long long ib = (long long)(z/iIn)*iSO + (long long)(z%iIn)*iSI;
  int r0 = blockIdx.y*32, c0 = blockIdx.x*32;
  int tx = threadIdx.x & 31, ty = threadIdx.x >> 5;
  for (int rr = ty; rr < 32; rr += 8)
    sm[rr][tx] = gload(in, inbf, ib + (long long)(r0+rr)*ldin + c0 + tx);
  __syncthreads();
  for (int cc = ty; cc < 32; cc += 8)
    outp[z*oSO + (long long)(c0+cc)*R + r0 + tx] = __float2bfloat16(sm[tx][cc]);
}

__global__ __launch_bounds__(256) void landmarks2(const __hip_bfloat16* QKV,
                                                  __hip_bfloat16* QL, __hip_bfloat16* KL){
  int j = blockIdx.x, b = blockIdx.y, t = threadIdx.x;
  const __hip_bfloat16* base = QKV + ((long long)b * NPAD + j*25) * 1536;
  float q0 = 0.f, q1 = 0.f, k0 = 0.f, k1 = 0.f;
  #pragma unroll 5
  for (int i = 0; i < 25; i++){
    const __hip_bfloat16* row = base + (long long)i*1536;
    q0 += __bfloat162float(row[t]);
    q1 += __bfloat162float(row[t + 256]);
    k0 += __bfloat162float(row[512 + t]);
    k1 += __bfloat162float(row[512 + t + 256]);
  }
  int h0 = t >> 6, d0 = t & 63;
  int h1 = (t + 256) >> 6, d1 = (t + 256) & 63;
  QL[((long long)(b*8 + h0) * NLM + j) * 64 + d0] = __float2bfloat16(q0 * 0.005f);
  QL[((long long)(b*8 + h1) * NLM + j) * 64 + d1] = __float2bfloat16(q1 * 0.005f);
  KL[((long long)(b*8 + h0) * NLM + j) * 64 + d0] = __float2bfloat16(k0 * 0.04f);
  KL[((long long)(b*8 + h1) * NLM + j) * 64 + d1] = __float2bfloat16(k1 * 0.04f);
}

__global__ void init_sc(float* sc){ sc[0] = 0.f; sc[1] = 0.f; }
__global__ __launch_bounds__(256) void fillz(float* p, int n){
  int i = blockIdx.x*256 + threadIdx.x; if (i < n) p[i] = 0.f;
}

__global__ __launch_bounds__(256) void colsum_max(const float* A2, float* sc){
  int z = blockIdx.x, t = threadIdx.x;
  const float* a = A2 + (long long)z * 65536;
  float s = 0.f;
  for (int i = 0; i < 256; i++) s += fabsf(a[i*256 + t]);
  __shared__ float red[256];
  red[t] = s; __syncthreads();
  for (int st = 128; st; st >>= 1){ if (t < st) red[t] = fmaxf(red[t], red[t+st]); __syncthreads(); }
  if (t == 0) atomicMaxF(sc + 0, red[0]);
}

__global__ __launch_bounds__(256) void rowsum_max(const float* A2, float* sc){
  int z = blockIdx.x, t = threadIdx.x, w = t >> 6, l = t & 63;
  const float* a = A2 + (long long)z * 65536;
  float mx = 0.f;
  for (int i = w*64; i < (w+1)*64; i++){
    float s = fabsf(a[i*256 + l]) + fabsf(a[i*256 + l + 64])
            + fabsf(a[i*256 + l + 128]) + fabsf(a[i*256 + l + 192]);
    for (int m = 32; m; m >>= 1) s += __shfl_xor(s, m);
    mx = fmaxf(mx, s);
  }
  __shared__ float red[4];
  if (l == 0) red[w] = mx;
  __syncthreads();
  if (t == 0) atomicMaxF(sc + 1, fmaxf(fmaxf(red[0], red[1]), fmaxf(red[2], red[3])));
}

__global__ __launch_bounds__(256) void zinit_split(const float* A2,
    __hip_bfloat16* ZN, __hip_bfloat16* ZT, long long PS, const float* sc){
  int j = blockIdx.x, z = blockIdx.y, i = threadIdx.x;
  float inv = 1.f / (sc[0] * sc[1]);
  float v = A2[(long long)z*65536 + i*256 + j] * inv;
  __hip_bfloat16 hi = __float2bfloat16(v);
  __hip_bfloat16 lo = __float2bfloat16(v - __bfloat162float(hi));
  long long zo = (long long)z*65536;
  ZN[zo + j*256 + i] = hi; ZN[PS + zo + j*256 + i] = lo;
  ZT[zo + i*256 + j] = hi; ZT[PS + zo + i*256 + j] = lo;
}

__global__ __launch_bounds__(256) void dwconv_cvt2(const __hip_bfloat16* QKV, const float* rw,
                                                   const float* OUT1, __hip_bfloat16* OUT1b){
  int t = threadIdx.x;
  int n = blockIdx.x*4 + (t >> 6);
  int b = blockIdx.y;
  int ch0 = (t & 63) * 8;
  int h = (t & 63) >> 3;
  float w[33];
  #pragma unroll
  for (int k = 0; k < 33; k++) w[k] = rw[h*33 + k];
  float acc[8] = {};
  const __hip_bfloat16* Vb = QKV + (long long)b * NPAD * 1536 + 1024 + ch0;
  #pragma unroll
  for (int k = 0; k < 33; k++){
    int nn = n + k - 16;
    if (nn < 0 || nn >= NPAD) continue;
    short8_t v8 = *(const short8_t*)(Vb + (long long)nn * 1536);
    #pragma unroll
    for (int j = 0; j < 8; j++) acc[j] += w[k] * b2f((ushort)v8[j]);
  }
  long long idx = ((long long)b * NPAD + n) * D_ + ch0;
  float4 o0 = *(const float4*)(OUT1 + idx);
  float4 o1 = *(const float4*)(OUT1 + idx + 4);
  short8_t o;
  o[0] = (short)f2b(o0.x + acc[0]); o[1] = (short)f2b(o0.y + acc[1]);
  o[2] = (short)f2b(o0.z + acc[2]); o[3] = (short)f2b(o0.w + acc[3]);
  o[4] = (short)f2b(o1.x + acc[4]); o[5] = (short)f2b(o1.y + acc[5]);
  o[6] = (short)f2b(o1.z + acc[6]); o[7] = (short)f2b(o1.w + acc[7]);
  *(short8_t*)((ushort*)OUT1b + idx) = o;
}

__global__ __launch_bounds__(512) void resid_add(float* H, const float* O2, const float* ob){
  int i = blockIdx.x, b = blockIdx.y, t = threadIdx.x;
  H[((long long)b * NTOK + i) * D_ + t] +=
      O2[((long long)b * NPAD + i + PADF) * D_ + t] + ob[t];
}

// ------------------- PPEG: row-register sliding window --------------------
__global__ __launch_bounds__(256) void transpose_w(const float* w, float* wt, int KK){
  int i = blockIdx.x*256 + threadIdx.x;
  if (i < 512*KK){ int ch = i / KK, k = i - ch*KK; wt[(long long)k*512 + ch] = w[i]; }
}

// thread = (ch 0..31, y 0..7); per patch-row r: 14 LDS reads feed ALL taps of
// 7x7 (ky=r), 5x5 (ky=r-1), 3x3 (ky=r-2) + identity (r==3). 98 reads, 664 FMA.
__global__ __launch_bounds__(256) void ppeg_tiled(const float* H, float* P,
    const float* t7, const float* t5, const float* t3,
    const float* b7, const float* b5, const float* b3,
    int base, int W, int tilesX){
  __shared__ float smem[196*32];   // 24.5 KB
  int ty0 = (blockIdx.x / tilesX) * 8, tx0 = (blockIdx.x % tilesX) * 8;
  int c0 = blockIdx.y * 32, b = blockIdx.z;
  int t = threadIdx.x, ch = t & 31, y = t >> 5;
  int cc = c0 + ch;
  const float* Hb = H + ((long long)b * NTOK + base) * D_ + cc;
  for (int i = y; i < 196; i += 8){
    int py = i / 14, px = i - py*14;
    int yy = ty0 + py - 3, xx = tx0 + px - 3;
    smem[i*32 + ch] = (yy >= 0 && yy < W && xx >= 0 && xx < W)
                      ? Hb[(long long)(yy*W + xx) * D_] : 0.f;
  }
  __syncthreads();
  float acc[8];
  float bsum = b7[cc] + b5[cc] + b3[cc];
  #pragma unroll
  for (int x = 0; x < 8; x++) acc[x] = bsum;
  #pragma unroll
  for (int r = 0; r < 7; r++){
    float v[14];
    #pragma unroll
    for (int xx = 0; xx < 14; xx++) v[xx] = smem[((y + r)*14 + xx)*32 + ch];
    #pragma unroll
    for (int kx = 0; kx < 7; kx++){
      float w = t7[(r*7 + kx)*512 + cc];
      #pragma unroll
      for (int x = 0; x < 8; x++) acc[x] += w * v[x + kx];
    }
    if (r >= 1 && r <= 5){
      #pragma unroll
      for (int kx = 0; kx < 5; kx++){
        float w = t5[((r-1)*5 + kx)*512 + cc];
        #pragma unroll
        for (int x = 0; x < 8; x++) acc[x] += w * v[x + kx + 1];
      }
    }
    if (r >= 2 && r <= 4){
      #pragma unroll
      for (int kx = 0; kx < 3; kx++){
        float w = t3[((r-2)*3 + kx)*512 + cc];
        #pragma unroll
        for (int x = 0; x < 8; x++) acc[x] += w * v[x + kx + 2];
      }
    }
    if (r == 3){
      #pragma unroll
      for (int x = 0; x < 8; x++) acc[x] += v[x + 3];
    }
  }
  int gy = ty0 + y;
  if (gy < W){
    #pragma unroll
    for (int x = 0; x < 8; x++){
      int gx = tx0 + x;
      if (gx < W)
        P[((long long)b * W * W + gy*W + gx) * D_ + cc] = acc[x];
    }
  }
}

__global__ __launch_bounds__(512) void ppeg_copy(float* H, const float* P, int base, int W){
  int pos = blockIdx.x, b = blockIdx.y, t = threadIdx.x;
  H[((long long)b * NTOK + base + pos) * D_ + t] = P[((long long)b * W * W + pos) * D_ + t];
}

// ============================== host side =================================
static void gemmB(hipStream_t st, int BN,
                  const __hip_bfloat16* A, int lda, long long aSO, long long aSI, int aIn,
                  const __hip_bfloat16* Bm, int ldb, long long bSO, long long bSI, int bIn,
                  void* C, int ldc, long long cSO, long long cSI, int cIn, int cbf,
                  int M, int N, int K, int batch,
                  const float* bias, float beta, int relu, int ksp = 1, int klen = 0){
  GB p;
  p.A = A; p.Bm = Bm; p.C = C; p.bias = bias;
  p.M = M; p.N = N; p.K = K; p.lda = lda; p.ldb = ldb; p.ldc = ldc;
  p.aSO = aSO; p.aSI = aSI; p.aIn = aIn;
  p.bSO = bSO; p.bSI = bSI; p.bIn = bIn;
  p.cSO = cSO; p.cSI = cSI; p.cIn = cIn; p.cbf = cbf;
  p.beta = beta; p.relu = relu; p.ksp = ksp; p.klen = (klen > 0) ? klen : K;
  dim3 g(N/BN, (M + 127)/128, batch * ksp), b(256);
  if (BN == 128) gemm_bt<128><<<g, b, 0, st>>>(p);
  else           gemm_bt<64><<<g, b, 0, st>>>(p);
}

static void gemmS(hipStream_t st, const ushort* A, const ushort* B,
                  ushort* oN, ushort* oT, float scale, float alphaT, float sT){
  GS p;
  p.A = (const __hip_bfloat16*)A; p.B = (const __hip_bfloat16*)B;
  p.outN = (__hip_bfloat16*)oN; p.outT = (__hip_bfloat16*)oT;
  p.PS = 2097152; p.scale = scale; p.alphaT = alphaT; p.sT = sT;
  dim3 g(4, 4, 32), b(256);
  gemm_bts<<<g, b, 0, st>>>(p);
}

extern "C" void kernel_launch(void* const* d_in, const int* in_sizes, int n_in,
                              void* d_out, int out_size, void* d_ws, size_t ws_size,
                              hipStream_t stream){
  const float* x      = (const float*)d_in[0];
  const float* fc1_w  = (const float*)d_in[1];
  const float* fc1_b  = (const float*)d_in[2];
  const float* cls    = (const float*)d_in[3];
  const float* l1_ng  = (const float*)d_in[4];
  const float* l1_nb  = (const float*)d_in[5];
  const float* l1_qkv = (const float*)d_in[6];
  const float* l1_ow  = (const float*)d_in[7];
  const float* l1_ob  = (const float*)d_in[8];
  const float* l1_rw  = (const float*)d_in[9];
  const float* ct_w7  = (const float*)d_in[10];
  const float* ct_b7  = (const float*)d_in[11];
  const float* ct_w5  = (const float*)d_in[12];
  const float* ct_b5  = (const float*)d_in[13];
  const float* ct_w3  = (const float*)d_in[14];
  const float* ct_b3  = (const float*)d_in[15];
  const float* pt_w7  = (const float*)d_in[16];
  const float* pt_b7  = (const float*)d_in[17];
  const float* pt_w5  = (const float*)d_in[18];
  const float* pt_b5  = (const float*)d_in[19];
  const float* pt_w3  = (const float*)d_in[20];
  const float* pt_b3  = (const float*)d_in[21];
  const float* l2_ng  = (const float*)d_in[22];
  const float* l2_nb  = (const float*)d_in[23];
  const float* l2_qkv = (const float*)d_in[24];
  const float* l2_ow  = (const float*)d_in[25];
  const float* l2_ob  = (const float*)d_in[26];
  const float* l2_rw  = (const float*)d_in[27];
  const float* nrm_g  = (const float*)d_in[28];
  const float* nrm_b  = (const float*)d_in[29];
  float* out = (float*)d_out;

  // ---- workspace layout (float units); SIMC last (flex-sized) ----
  float* ws    = (float*)d_ws;
  float* H     = ws;                      // 12,828,672
  float* BUF   = H + 12828672;            // 13,107,200
  float* QKVr  = BUF + 13107200;          // 19,660,800
  float* QLf   = QKVr + 19660800;         //    262,144
  float* KLf   = QLf + 262144;            //    262,144
  float* AV    = KLf + 262144;            //    524,288
  float* AVTf  = AV + 524288;             //    262,144
  float* ZVf   = AVTf + 262144;           //    262,144
  float* ZVTf  = ZVf + 262144;            //    262,144
  float* WQf   = ZVTf + 262144;           //    393,216
  float* WFf   = WQf + 393216;            //    196,608
  float* WOf   = WFf + 196608;            //    131,072
  float* PWT   = WOf + 131072;            //     84,992
  float* SC    = PWT + 84992;             //          8 (padded)
  float* SIMC  = SC + 8;                  //    rest of ws
  float* tc7 = PWT, *tc5 = tc7 + 49*512, *tc3 = tc5 + 25*512;
  float* tp7 = tc3 + 9*512, *tp5 = tp7 + 49*512, *tp3 = tp5 + 25*512;

  long long fixedB = (long long)((char*)SIMC - (char*)ws);
  long long availB = (long long)ws_size - fixedB;
  int G = (availB >= 104857600LL) ? 32 : (availB >= 52428800LL) ? 16 : 8;

  // pinv scratch: A2 f32 + hi/lo plane pairs (PS = 2,097,152 bf16 elems)
  float*  A2   = BUF;
  ushort* a2P  = (ushort*)(BUF + 2097152);
  ushort* zn_N = (ushort*)(BUF + 4194304);
  ushort* zn_T = (ushort*)(BUF + 6291456);
  ushort* zc_N = (ushort*)(BUF + 8388608);
  ushort* zc_T = (ushort*)(BUF + 10485760);
  ushort* azP  = (ushort*)SIMC;
  ushort* w1T  = (ushort*)SIMC + 4194304;
  ushort* w2T  = (ushort*)SIMC + 8388608;

  __hip_bfloat16* Xb    = (__hip_bfloat16*)QKVr;
  __hip_bfloat16* QKV   = (__hip_bfloat16*)QKVr;
  float*          PROJ  = QKVr;
  __hip_bfloat16* XLNb  = (__hip_bfloat16*)BUF;
  __hip_bfloat16* VT    = (__hip_bfloat16*)BUF;         // [32][64][6400]
  __hip_bfloat16* SIMCb = (__hip_bfloat16*)SIMC;
  __hip_bfloat16* OUT1b = (__hip_bfloat16*)SIMC;
  __hip_bfloat16* QLb   = (__hip_bfloat16*)QLf;
  __hip_bfloat16* KLb   = (__hip_bfloat16*)KLf;
  __hip_bfloat16* AVT   = (__hip_bfloat16*)AVTf;
  __hip_bfloat16* Zvb   = (__hip_bfloat16*)ZVf;
  __hip_bfloat16* ZVT   = (__hip_bfloat16*)ZVTf;
  __hip_bfloat16* WqkvT = (__hip_bfloat16*)WQf;
  __hip_bfloat16* Wfc1T = (__hip_bfloat16*)WFf;
  __hip_bfloat16* WoutT = (__hip_bfloat16*)WOf;

  // ---- one-time weight prep
  transpose_w<<<(512*49+255)/256, 256, 0, stream>>>(ct_w7, tc7, 49);
  transpose_w<<<(512*25+255)/256, 256, 0, stream>>>(ct_w5, tc5, 25);
  transpose_w<<<(512* 9+255)/256, 256, 0, stream>>>(ct_w3, tc3,  9);
  transpose_w<<<(512*49+255)/256, 256, 0, stream>>>(pt_w7, tp7, 49);
  transpose_w<<<(512*25+255)/256, 256, 0, stream>>>(pt_w5, tp5, 25);
  transpose_w<<<(512* 9+255)/256, 256, 0, stream>>>(pt_w3, tp3,  9);
  tr_cvt<<<dim3(512/32, 768/32, 1), 256, 0, stream>>>(fc1_w, 0, 512, 0,0,1, Wfc1T, 0, 768, 512);

  // ---- fc1 + relu -> h0 (BUF f32); gather into H
  cvt_pad_x<<<MFC1, 256, 0, stream>>>(x, Xb);
  gemmB(stream, 128, Xb, 768, 0,0,1, Wfc1T, 768, 0,0,1, BUF, 512, 0,0,1,0,
        MFC1, 512, 768, 1, fc1_b, 1.f, 1);
  build_h<<<dim3(NTOK, B_), 256, 0, stream>>>(BUF, cls, H);

  auto attn_layer = [&](const float* ng, const float* nb, const float* qkvw,
                        const float* outw, const float* outb, const float* resw){
    tr_cvt<<<dim3(1536/32, 512/32, 1), 256, 0, stream>>>(qkvw, 0, 1536, 0,0,1, WqkvT, 0, 512, 1536);
    tr_cvt<<<dim3(512/32, 512/32, 1), 256, 0, stream>>>(outw, 0, 512, 0,0,1, WoutT, 0, 512, 512);
    ln_pad<<<dim3(NPAD, B_), 256, 0, stream>>>(H, XLNb, ng, nb);
    gemmB(stream, 128, XLNb, 512, 0,0,1, WqkvT, 512, 0,0,1, QKV, 1536, 0,0,1,1,
          B_*NPAD, 1536, 512, 1, nullptr, 1.f, 0);
    landmarks2<<<dim3(NLM, B_), 256, 0, stream>>>(QKV, QLb, KLb);
    // a2 = softmax(q_l @ k_l^T): f32 + hi/lo planes
    gemmB(stream, 128, QLb, 64, 16384,0,1, KLb, 64, 16384,0,1, A2, 256, 65536,0,1,0,
          256, 256, 64, 32, nullptr, 1.f, 0);
    softmax256_split<<<B_*NH*NLM, 256, 0, stream>>>(A2, (__hip_bfloat16*)a2P, 2097152);
    // pinv (Newton-Schulz, 6 iters), 64x64-tile split GEMMs, fused diag epilogues
    init_sc<<<1, 1, 0, stream>>>(SC);
    colsum_max<<<B_*NH, 256, 0, stream>>>(A2, SC);
    rowsum_max<<<B_*NH, 256, 0, stream>>>(A2, SC);
    zinit_split<<<dim3(256, 32), 256, 0, stream>>>(A2, (__hip_bfloat16*)zc_N,
          (__hip_bfloat16*)zc_T, 2097152, SC);
    ushort *cN = zc_N, *cT = zc_T, *nN = zn_N, *nT = zn_T;
    for (int it = 0; it < 6; it++){
      gemmS(stream, a2P, cT, azP, w1T, 1.f, 7.f, -1.f);
      gemmS(stream, azP, w1T, nullptr, w2T, 1.f, 15.f, -1.f);
      gemmS(stream, azP, w2T, nullptr, w1T, 1.f, 13.f, -1.f);
      gemmS(stream, cN, w1T, nN, nT, 0.25f, 0.f, 1.f);
      ushort* s;
      s = cN; cN = nN; nN = s;
      s = cT; cT = nT; nT = s;
    }
    const __hip_bfloat16* Zcb = (const __hip_bfloat16*)cN;
    // V^T per head into BUF (pinv scratch dead except final Z planes)
    tr_cvt<<<dim3(64/32, NPAD/32, 32), 256, 0, stream>>>(QKV + 1024, 1, 1536,
          QE, 64, 8, VT, (long long)64*NPAD, NPAD, 64);
    fillz<<<2048, 256, 0, stream>>>(AV, 524288);
    // sim3 -> softmax -> AV, G bh per pass
    for (int c0 = 0; c0 < 32; c0 += G){
      int b0 = c0 >> 3;
      const __hip_bfloat16* Kp = QKV + (long long)b0*QE + 512;
      gemmB(stream, 128, QLb + (long long)c0*16384, 64, 16384,0,1,
            Kp, 1536, QE,64,8,
            SIMCb, NPAD, (long long)256*NPAD,0,1,1,
            256, NPAD, 64, G, nullptr, 1.f, 0);
      softmax_rows_b<NPAD><<<G*NLM, 256, 0, stream>>>(SIMCb);
      gemmB(stream, 64, SIMCb, NPAD, (long long)256*NPAD,0,1,
            VT + (long long)c0*64*NPAD, NPAD, (long long)64*NPAD,0,1,
            AV + (long long)c0*16384, 64, 16384,0,1,0,
            256, 64, NPAD, G, nullptr, 1.f, 0, 10, 640);
    }
    // AV^T, ZV = Zc@AV (bf16 out), ZV^T
    tr_cvt<<<dim3(64/32, 256/32, 32), 256, 0, stream>>>(AV, 0, 64, 16384,0,1,
          AVT, 16384, 256, 64);
    gemmB(stream, 64, Zcb, 256, 65536,0,1, AVT, 256, 16384,0,1,
          Zvb, 64, 16384,0,1,1, 256, 64, 256, 32, nullptr, 1.f, 0);
    tr_cvt<<<dim3(64/32, 256/32, 32), 256, 0, stream>>>(Zvb, 1, 64, 16384,0,1,
          ZVT, 16384, 256, 64);
    // fused sim1: OUT1 f32 into BUF
    sim1_fused<<<dim3(NPAD/64, 32), 256, 0, stream>>>(QKV, KLb, ZVT, BUF);
    // + depthwise conv residual -> bf16, projection, residual add
    dwconv_cvt2<<<dim3(NPAD/4, B_), 256, 0, stream>>>(QKV, resw, BUF, OUT1b);
    gemmB(stream, 128, OUT1b, 512, 0,0,1, WoutT, 512, 0,0,1, PROJ, 512, 0,0,1,0,
          B_*NPAD, 512, 512, 1, nullptr, 1.f, 0);
    resid_add<<<dim3(NTOK, B_), 512, 0, stream>>>(H, PROJ, outb);
  };

  // ---- layer 1
  attn_layer(l1_ng, l1_nb, l1_qkv, l1_ow, l1_ob, l1_rw);

  // ---- PPEG (sliding-row kernels; 32 ch/block)
  ppeg_tiled<<<dim3(4, 16, B_), 256, 0, stream>>>(H, BUF, tc7, tc5, tc3, ct_b7, ct_b5, ct_b3, 11, 13, 2);
  ppeg_copy<<<dim3(169, B_), 512, 0, stream>>>(H, BUF, 11, 13);
  ppeg_tiled<<<dim3(100, 16, B_), 256, 0, stream>>>(H, BUF, tp7, tp5, tp3, pt_b7, pt_b5, pt_b3, 180, 78, 10);
  ppeg_copy<<<dim3(6084, B_), 512, 0, stream>>>(H, BUF, 180, 78);

  // ---- layer 2
  attn_layer(l2_ng, l2_nb, l2_qkv, l2_ow, l2_ob, l2_rw);

  // ---- final LN on cls token
  final_ln<<<B_, 256, 0, stream>>>(H, nrm_g, nrm_b, out);
}

// Round 8
// 2394.662 us; speedup vs baseline: 5.0933x; 1.0594x over previous
//
#include <hip/hip_runtime.h>
#include <hip/hip_bf16.h>
#include <cstdint>

#define B_   4
#define NTOK 6264
#define NPAD 6400
#define D_   512
#define NH   8
#define NLM  256
#define N0   6170
#define PADF (NPAD - NTOK)   // 136
#define MFC1 24704           // B_*N0 padded to x128
#define QE   ((long long)NPAD * 1536)

typedef __attribute__((ext_vector_type(8))) short short8_t;
typedef __attribute__((ext_vector_type(4))) float float4_t;

__device__ __forceinline__ ushort f2b(float x){
  __hip_bfloat16 h = __float2bfloat16(x); return *(ushort*)&h;
}
__device__ __forceinline__ float b2f(ushort u){
  __hip_bfloat16 h = *(__hip_bfloat16*)&u; return __bfloat162float(h);
}
__device__ __forceinline__ float gload(const void* p, int bf, long long i){
  return bf ? __bfloat162float(((const __hip_bfloat16*)p)[i]) : ((const float*)p)[i];
}
__device__ __forceinline__ void atomicMaxF(float* a, float v){
  atomicMax((int*)a, __float_as_int(v));
}
__device__ __forceinline__ void gl_lds16(const void* g, void* l){
  __builtin_amdgcn_global_load_lds(
      (const __attribute__((address_space(1))) void*)g,
      (__attribute__((address_space(3))) void*)l, 16, 0, 0);
}

// ===================== fast bf16 NT GEMM (m97-style) ======================
struct GB {
  const __hip_bfloat16* A; const __hip_bfloat16* Bm; void* C; const float* bias;
  int M, N, K, lda, ldb, ldc;
  long long aSO, aSI; int aIn;
  long long bSO, bSI; int bIn;
  long long cSO, cSI; int cIn;
  float beta; int cbf, relu, ksp, klen;
};

template<int BN>
__global__ __launch_bounds__(256) void gemm_bt(GB p){
  __shared__ __align__(16) __hip_bfloat16 As[128*64];
  __shared__ __align__(16) __hip_bfloat16 Bs[BN*64];
  int zz = blockIdx.z;
  int z = zz / p.ksp, ks = zz - z*p.ksp;
  int k0 = ks * p.klen;
  int kend = k0 + p.klen; if (kend > p.K) kend = p.K;
  const __hip_bfloat16* A  = p.A  + (long long)(z/p.aIn)*p.aSO + (long long)(z%p.aIn)*p.aSI;
  const __hip_bfloat16* Bm = p.Bm + (long long)(z/p.bIn)*p.bSO + (long long)(z%p.bIn)*p.bSI;
  long long cOff = (long long)(z/p.cIn)*p.cSO + (long long)(z%p.cIn)*p.cSI;
  int rowBase = blockIdx.y*128, colBase = blockIdx.x*BN;
  int t = threadIdx.x, lane = t & 63;
  int wv = __builtin_amdgcn_readfirstlane(t >> 6);
  int lm = lane & 15, lq = lane >> 4;
  int dr = lane >> 3, dc = lane & 7;
  constexpr int NF = (BN == 128) ? 4 : 2;
  int wm = (wv >> 1) * 64;
  int wn = (BN == 128) ? (wv & 1) * 64 : (wv & 1) * 32;
  float4_t acc[4][NF];
  #pragma unroll
  for (int mi = 0; mi < 4; mi++)
    #pragma unroll
    for (int nf = 0; nf < NF; nf++) acc[mi][nf] = (float4_t)0.f;

  for (int kb = k0; kb < kend; kb += 64){
    #pragma unroll
    for (int d = 0; d < 4; d++){
      int rg = wv*4 + d;
      int row = rg*8 + dr;
      int cc = dc ^ (row & 7);
      gl_lds16(A + (long long)(rowBase + row)*p.lda + kb + cc*8, &As[rg*8*64]);
    }
    #pragma unroll
    for (int d = 0; d < BN/32; d++){
      int rg = wv*(BN/32) + d;
      int row = rg*8 + dr;
      int cc = dc ^ (row & 7);
      gl_lds16(Bm + (long long)(colBase + row)*p.ldb + kb + cc*8, &Bs[rg*8*64]);
    }
    __syncthreads();
    short8_t af[2][4]; short8_t bfv[2][NF];
    #pragma unroll
    for (int ks2 = 0; ks2 < 2; ks2++){
      #pragma unroll
      for (int mi = 0; mi < 4; mi++){
        int r = wm + mi*16 + lm;
        int s = (ks2*4 + lq) ^ (r & 7);
        af[ks2][mi] = *(const short8_t*)&As[r*64 + s*8];
      }
      #pragma unroll
      for (int nf = 0; nf < NF; nf++){
        int r = wn + nf*16 + lm;
        int s = (ks2*4 + lq) ^ (r & 7);
        bfv[ks2][nf] = *(const short8_t*)&Bs[r*64 + s*8];
      }
    }
    #pragma unroll
    for (int ks2 = 0; ks2 < 2; ks2++)
      #pragma unroll
      for (int mi = 0; mi < 4; mi++)
        #pragma unroll
        for (int nf = 0; nf < NF; nf++)
          acc[mi][nf] = __builtin_amdgcn_mfma_f32_16x16x32_bf16(af[ks2][mi], bfv[ks2][nf], acc[mi][nf], 0, 0, 0);
    __syncthreads();
  }
  #pragma unroll
  for (int mi = 0; mi < 4; mi++){
    #pragma unroll
    for (int nf = 0; nf < NF; nf++){
      int c = colBase + wn + nf*16 + lm;
      #pragma unroll
      for (int r = 0; r < 4; r++){
        int m = rowBase + wm + mi*16 + lq*4 + r;
        if (m >= p.M) continue;
        float v = p.beta * acc[mi][nf][r];
        long long ci = cOff + (long long)m*p.ldc + c;
        if (p.ksp > 1){
          atomicAdd((float*)p.C + ci, v);
        } else {
          if (p.bias) v += p.bias[c];
          if (p.relu) v = fmaxf(v, 0.f);
          if (p.cbf) ((__hip_bfloat16*)p.C)[ci] = __float2bfloat16(v);
          else       ((float*)p.C)[ci] = v;
        }
      }
    }
  }
}

// ============== fast split (hi/lo) GEMM for pinv: 64x64 tiles, batch 32 ====
struct GS {
  const __hip_bfloat16* A; const __hip_bfloat16* B;
  __hip_bfloat16* outN; __hip_bfloat16* outT;
  long long PS;
  float scale, alphaT, sT;
};

__global__ __launch_bounds__(256) void gemm_bts(GS p){
  __shared__ __align__(16) __hip_bfloat16 Ah[64*64];
  __shared__ __align__(16) __hip_bfloat16 Al[64*64];
  __shared__ __align__(16) __hip_bfloat16 Bh[64*64];
  __shared__ __align__(16) __hip_bfloat16 Bl[64*64];
  int z = blockIdx.z;
  long long zo = (long long)z * 65536;
  const __hip_bfloat16* A = p.A + zo;
  const __hip_bfloat16* B = p.B + zo;
  int rowBase = blockIdx.y*64, colBase = blockIdx.x*64;
  int t = threadIdx.x, lane = t & 63;
  int wv = __builtin_amdgcn_readfirstlane(t >> 6);
  int lm = lane & 15, lq = lane >> 4;
  int dr = lane >> 3, dc = lane & 7;
  int wm = (wv >> 1) * 32, wn = (wv & 1) * 32;
  float4_t acc[2][2];
  #pragma unroll
  for (int mi = 0; mi < 2; mi++){ acc[mi][0] = (float4_t)0.f; acc[mi][1] = (float4_t)0.f; }

  for (int kb = 0; kb < 256; kb += 64){
    #pragma unroll
    for (int d = 0; d < 2; d++){
      int rg = wv*2 + d;
      int row = rg*8 + dr;
      int cc = dc ^ (row & 7);
      gl_lds16(A +        (long long)(rowBase + row)*256 + kb + cc*8, &Ah[rg*8*64]);
      gl_lds16(A + p.PS + (long long)(rowBase + row)*256 + kb + cc*8, &Al[rg*8*64]);
      gl_lds16(B +        (long long)(colBase + row)*256 + kb + cc*8, &Bh[rg*8*64]);
      gl_lds16(B + p.PS + (long long)(colBase + row)*256 + kb + cc*8, &Bl[rg*8*64]);
    }
    __syncthreads();
    #pragma unroll
    for (int ks2 = 0; ks2 < 2; ks2++){
      short8_t ah[2], al2[2], bh[2], bl2[2];
      #pragma unroll
      for (int mi = 0; mi < 2; mi++){
        int r = wm + mi*16 + lm;
        int s = (ks2*4 + lq) ^ (r & 7);
        ah[mi]  = *(const short8_t*)&Ah[r*64 + s*8];
        al2[mi] = *(const short8_t*)&Al[r*64 + s*8];
      }
      #pragma unroll
      for (int nf = 0; nf < 2; nf++){
        int r = wn + nf*16 + lm;
        int s = (ks2*4 + lq) ^ (r & 7);
        bh[nf]  = *(const short8_t*)&Bh[r*64 + s*8];
        bl2[nf] = *(const short8_t*)&Bl[r*64 + s*8];
      }
      #pragma unroll
      for (int mi = 0; mi < 2; mi++)
        #pragma unroll
        for (int nf = 0; nf < 2; nf++){
          acc[mi][nf] = __builtin_amdgcn_mfma_f32_16x16x32_bf16(ah[mi],  bh[nf],  acc[mi][nf], 0, 0, 0);
          acc[mi][nf] = __builtin_amdgcn_mfma_f32_16x16x32_bf16(ah[mi],  bl2[nf], acc[mi][nf], 0, 0, 0);
          acc[mi][nf] = __builtin_amdgcn_mfma_f32_16x16x32_bf16(al2[mi], bh[nf],  acc[mi][nf], 0, 0, 0);
        }
    }
    __syncthreads();
  }
  #pragma unroll
  for (int mi = 0; mi < 2; mi++){
    #pragma unroll
    for (int nf = 0; nf < 2; nf++){
      int c = colBase + wn + nf*16 + lm;
      #pragma unroll
      for (int r = 0; r < 4; r++){
        int m = rowBase + wm + mi*16 + lq*4 + r;
        float v = p.scale * acc[mi][nf][r];
        if (p.outN){
          __hip_bfloat16 hi = __float2bfloat16(v);
          p.outN[zo + (long long)m*256 + c] = hi;
          p.outN[p.PS + zo + (long long)m*256 + c] = __float2bfloat16(v - __bfloat162float(hi));
        }
        if (p.outT){
          float w = p.alphaT * (m == c ? 1.f : 0.f) + p.sT * v;
          __hip_bfloat16 hi = __float2bfloat16(w);
          p.outT[zo + (long long)c*256 + m] = hi;
          p.outT[p.PS + zo + (long long)c*256 + m] = __float2bfloat16(w - __bfloat162float(hi));
        }
      }
    }
  }
}

// ====== fused sim3 (flash-style): S=QL@K^T, online softmax, O=P@V^T =======
// grid (rowtile 4, z 32, ksplit 4); block 256. Partials: unnormalized O + (m,l).
__global__ __launch_bounds__(256) void sim3_fused(const __hip_bfloat16* QKV,
    const __hip_bfloat16* QL, const __hip_bfloat16* VT, float* AVp, float* MLp){
  __shared__ __align__(16) __hip_bfloat16 Ks[64*64];
  __shared__ __align__(16) __hip_bfloat16 Ps[4*16*64];
  int z = blockIdx.y, b = z >> 3, h = z & 7;
  int r0 = blockIdx.x * 64;
  int ksp = blockIdx.z;
  int t = threadIdx.x, lane = t & 63;
  int wv = __builtin_amdgcn_readfirstlane(t >> 6);
  int lm = lane & 15, lq = lane >> 4;
  int dr = lane >> 3, dc = lane & 7;
  const __hip_bfloat16* Kb = QKV + (long long)b*QE + h*64 + 512;
  const __hip_bfloat16* Vb = VT + (long long)z*64*NPAD;

  // QL A-fragments (constant over key loop)
  short8_t aq[2];
  #pragma unroll
  for (int ks = 0; ks < 2; ks++)
    aq[ks] = *(const short8_t*)(QL + (long long)z*NLM*64 + (r0 + wv*16 + lm)*64 + ks*32 + lq*8);

  float m_run[4], l_run[4];
  float4_t oacc[4];
  #pragma unroll
  for (int r = 0; r < 4; r++){ m_run[r] = -1e30f; l_run[r] = 0.f; }
  #pragma unroll
  for (int nf = 0; nf < 4; nf++) oacc[nf] = (float4_t)0.f;

  int kbase = ksp * (NPAD/4);
  for (int kt = 0; kt < (NPAD/4)/64; kt++){
    int k0 = kbase + kt*64;
    __syncthreads();
    // stage K-tile 64 keys x 64 d (swizzled), 2 DMA per wave
    #pragma unroll
    for (int d = 0; d < 2; d++){
      int rg = wv*2 + d;
      int row = rg*8 + dr;
      int cc = dc ^ (row & 7);
      gl_lds16(Kb + (long long)(k0 + row)*1536 + cc*8, &Ks[rg*8*64]);
    }
    __syncthreads();
    // S tile: 16 rows x 64 keys
    float4_t sacc[4];
    #pragma unroll
    for (int nf = 0; nf < 4; nf++) sacc[nf] = (float4_t)0.f;
    #pragma unroll
    for (int ks = 0; ks < 2; ks++){
      #pragma unroll
      for (int nf = 0; nf < 4; nf++){
        int r = nf*16 + lm;
        int s = (ks*4 + lq) ^ (r & 7);
        short8_t bb = *(const short8_t*)&Ks[r*64 + s*8];
        sacc[nf] = __builtin_amdgcn_mfma_f32_16x16x32_bf16(aq[ks], bb, sacc[nf], 0, 0, 0);
      }
    }
    // online softmax per row; write P' to per-wave Ps (same-wave, no barrier)
    #pragma unroll
    for (int reg = 0; reg < 4; reg++){
      float mt = fmaxf(fmaxf(sacc[0][reg], sacc[1][reg]), fmaxf(sacc[2][reg], sacc[3][reg]));
      #pragma unroll
      for (int mm = 1; mm <= 8; mm <<= 1) mt = fmaxf(mt, __shfl_xor(mt, mm));
      float mnew = fmaxf(m_run[reg], mt);
      float alpha = __expf(m_run[reg] - mnew);
      float sum = 0.f;
      #pragma unroll
      for (int nf = 0; nf < 4; nf++){
        float e = __expf(sacc[nf][reg] - mnew);
        sacc[nf][reg] = e; sum += e;
      }
      #pragma unroll
      for (int mm = 1; mm <= 8; mm <<= 1) sum += __shfl_xor(sum, mm);
      l_run[reg] = l_run[reg]*alpha + sum;
      m_run[reg] = mnew;
      #pragma unroll
      for (int nf = 0; nf < 4; nf++) oacc[nf][reg] *= alpha;
      int row = lq*4 + reg;
      #pragma unroll
      for (int nf = 0; nf < 4; nf++){
        int col = nf*16 + lm;
        Ps[(wv*16 + row)*64 + (((col>>3) ^ (row&7))*8) + (col&7)] = __float2bfloat16(sacc[nf][reg]);
      }
    }
    // PV: A = Ps rows (queries), B = VT rows (d), k = keys
    #pragma unroll
    for (int ks = 0; ks < 2; ks++){
      int s = (ks*4 + lq) ^ (lm & 7);
      short8_t ap = *(const short8_t*)&Ps[(wv*16 + lm)*64 + s*8];
      #pragma unroll
      for (int nf = 0; nf < 4; nf++){
        short8_t bb = *(const short8_t*)(Vb + (long long)(nf*16 + lm)*NPAD + k0 + ks*32 + lq*8);
        oacc[nf] = __builtin_amdgcn_mfma_f32_16x16x32_bf16(ap, bb, oacc[nf], 0, 0, 0);
      }
    }
  }
  // epilogue: unnormalized partials + (m,l)
  long long zb = (long long)(ksp*32 + z);
  #pragma unroll
  for (int nf = 0; nf < 4; nf++){
    #pragma unroll
    for (int reg = 0; reg < 4; reg++){
      int row = r0 + wv*16 + lq*4 + reg;
      AVp[zb*16384 + row*64 + nf*16 + lm] = oacc[nf][reg];
    }
  }
  if (lm == 0){
    #pragma unroll
    for (int reg = 0; reg < 4; reg++){
      int row = r0 + wv*16 + lq*4 + reg;
      MLp[(zb*256 + row)*2 + 0] = m_run[reg];
      MLp[(zb*256 + row)*2 + 1] = l_run[reg];
    }
  }
}

// merge 4 key-split partials -> AV [z][256][64] f32
__global__ __launch_bounds__(256) void av_merge(const float* AVp, const float* MLp, float* AV){
  int i = blockIdx.x*256 + threadIdx.x;
  int d = i & 63, row = (i >> 6) & 255, z = i >> 14;
  float M = -1e30f;
  #pragma unroll
  for (int s = 0; s < 4; s++) M = fmaxf(M, MLp[((long long)(s*32+z)*256 + row)*2]);
  float osum = 0.f, lsum = 0.f;
  #pragma unroll
  for (int s = 0; s < 4; s++){
    float m = MLp[((long long)(s*32+z)*256 + row)*2];
    float l = MLp[((long long)(s*32+z)*256 + row)*2 + 1];
    float w = __expf(m - M);
    osum += w * AVp[(long long)(s*32+z)*16384 + row*64 + d];
    lsum += w * l;
  }
  AV[(long long)z*16384 + row*64 + d] = osum / lsum;
}

// ================= fused sim1: S=0.125*Q@KL^T, softmax, O=P@ZV ============
__global__ __launch_bounds__(256) void sim1_fused(const __hip_bfloat16* QKV,
    const __hip_bfloat16* KL, const __hip_bfloat16* ZVT, float* OUT1){
  __shared__ __align__(16) __hip_bfloat16 Ps[64*256];
  int z = blockIdx.y, b = z >> 3, h = z & 7;
  int n0 = blockIdx.x * 64;
  int t = threadIdx.x, lane = t & 63;
  int wv = __builtin_amdgcn_readfirstlane(t >> 6);
  int lm = lane & 15, lq = lane >> 4;
  const __hip_bfloat16* Qb = QKV + (long long)b*QE + h*64;
  const __hip_bfloat16* Kb = KL + (long long)z*NLM*64;
  const __hip_bfloat16* Zb = ZVT + (long long)z*64*256;

  float4_t sacc[16];
  #pragma unroll
  for (int nf = 0; nf < 16; nf++) sacc[nf] = (float4_t)0.f;
  int qrow = n0 + wv*16 + lm;
  #pragma unroll
  for (int ks = 0; ks < 2; ks++){
    short8_t a = *(const short8_t*)(Qb + (long long)qrow*1536 + ks*32 + lq*8);
    #pragma unroll
    for (int nf = 0; nf < 16; nf++){
      short8_t bb = *(const short8_t*)(Kb + (nf*16 + lm)*64 + ks*32 + lq*8);
      sacc[nf] = __builtin_amdgcn_mfma_f32_16x16x32_bf16(a, bb, sacc[nf], 0, 0, 0);
    }
  }
  #pragma unroll
  for (int reg = 0; reg < 4; reg++){
    float mx = -1e30f;
    #pragma unroll
    for (int nf = 0; nf < 16; nf++){
      sacc[nf][reg] *= 0.125f;
      mx = fmaxf(mx, sacc[nf][reg]);
    }
    #pragma unroll
    for (int m = 1; m <= 8; m <<= 1) mx = fmaxf(mx, __shfl_xor(mx, m));
    float sum = 0.f;
    #pragma unroll
    for (int nf = 0; nf < 16; nf++){
      float e = __expf(sacc[nf][reg] - mx);
      sacc[nf][reg] = e; sum += e;
    }
    #pragma unroll
    for (int m = 1; m <= 8; m <<= 1) sum += __shfl_xor(sum, m);
    float inv = 1.f / sum;
    int row = wv*16 + lq*4 + reg;
    #pragma unroll
    for (int nf = 0; nf < 16; nf++){
      int col = nf*16 + lm;
      int chunk = (col >> 3) ^ (row & 7);
      Ps[row*256 + chunk*8 + (col & 7)] = __float2bfloat16(sacc[nf][reg] * inv);
    }
  }
  float4_t oacc[4];
  #pragma unroll
  for (int nf = 0; nf < 4; nf++) oacc[nf] = (float4_t)0.f;
  int prow = wv*16 + lm;
  #pragma unroll
  for (int ks = 0; ks < 8; ks++){
    int chunk = (ks*4 + lq) ^ (lm & 7);
    short8_t a = *(const short8_t*)&Ps[prow*256 + chunk*8];
    #pragma unroll
    for (int nf = 0; nf < 4; nf++){
      short8_t bb = *(const short8_t*)(Zb + (nf*16 + lm)*256 + ks*32 + lq*8);
      oacc[nf] = __builtin_amdgcn_mfma_f32_16x16x32_bf16(a, bb, oacc[nf], 0, 0, 0);
    }
  }
  #pragma unroll
  for (int nf = 0; nf < 4; nf++){
    #pragma unroll
    for (int reg = 0; reg < 4; reg++){
      int tok = n0 + wv*16 + lq*4 + reg;
      OUT1[((long long)b*NPAD + tok)*D_ + h*64 + nf*16 + lm] = oacc[nf][reg];
    }
  }
}

// ============================= softmax ====================================
__global__ __launch_bounds__(256) void softmax256_split(float* S, __hip_bfloat16* P, long long PS){
  long long row = blockIdx.x;
  float* p = S + row * 256;
  int t = threadIdx.x;
  float v = p[t];
  __shared__ float red[256];
  red[t] = v; __syncthreads();
  for (int s = 128; s; s >>= 1){ if (t < s) red[t] = fmaxf(red[t], red[t+s]); __syncthreads(); }
  float m = red[0]; __syncthreads();
  float e = __expf(v - m);
  red[t] = e; __syncthreads();
  for (int s = 128; s; s >>= 1){ if (t < s) red[t] += red[t+s]; __syncthreads(); }
  float r = e / red[0];
  p[t] = r;
  __hip_bfloat16 hi = __float2bfloat16(r);
  P[row*256 + t] = hi;
  P[PS + row*256 + t] = __float2bfloat16(r - __bfloat162float(hi));
}

// ============================ LN / misc ===================================
__global__ __launch_bounds__(256) void ln_pad(const float* H, __hip_bfloat16* X,
                                              const float* g, const float* bb){
  int p = blockIdx.x, b = blockIdx.y, t = threadIdx.x;
  __hip_bfloat16* xo = X + ((long long)b * NPAD + p) * D_;
  if (p < PADF){ xo[t] = __float2bfloat16(0.f); xo[t + 256] = __float2bfloat16(0.f); return; }
  const float* hi = H + ((long long)b * NTOK + (p - PADF)) * D_;
  float x0 = hi[t], x1 = hi[t + 256];
  __shared__ float r1[256], r2[256];
  r1[t] = x0 + x1; r2[t] = x0*x0 + x1*x1;
  __syncthreads();
  for (int s = 128; s; s >>= 1){ if (t < s){ r1[t] += r1[t+s]; r2[t] += r2[t+s]; } __syncthreads(); }
  float mu = r1[0] * (1.f / D_);
  float var = r2[0] * (1.f / D_) - mu*mu;
  float rs = rsqrtf(var + 1e-5f);
  xo[t]       = __float2bfloat16((x0 - mu) * rs * g[t]       + bb[t]);
  xo[t + 256] = __float2bfloat16((x1 - mu) * rs * g[t + 256] + bb[t + 256]);
}

__global__ __launch_bounds__(256) void final_ln(const float* H, const float* g,
                                                const float* bb, float* out){
  int b = blockIdx.x, t = threadIdx.x;
  const float* hi = H + (long long)b * NTOK * D_;
  float x0 = hi[t], x1 = hi[t + 256];
  __shared__ float r1[256], r2[256];
  r1[t] = x0 + x1; r2[t] = x0*x0 + x1*x1;
  __syncthreads();
  for (int s = 128; s; s >>= 1){ if (t < s){ r1[t] += r1[t+s]; r2[t] += r2[t+s]; } __syncthreads(); }
  float mu = r1[0] * (1.f / D_);
  float var = r2[0] * (1.f / D_) - mu*mu;
  float rs = rsqrtf(var + 1e-5f);
  out[b*D_ + t]       = (x0 - mu) * rs * g[t]       + bb[t];
  out[b*D_ + t + 256] = (x1 - mu) * rs * g[t + 256] + bb[t + 256];
}

__global__ __launch_bounds__(256) void build_h(const float* h0, const float* cls, float* H){
  int tpos = blockIdx.x, b = blockIdx.y, t = threadIdx.x;
  float* dst = H + ((long long)b * NTOK + tpos) * D_;
  if (tpos == 0){ dst[t] = cls[t]; dst[t + 256] = cls[t + 256]; return; }
  int i = tpos - 1, src;
  if (i < 10)        src = i;
  else if (i < 179){ int j = i - 10;  src = 10  + (j < 160  ? j : j - 160);  }
  else             { int j = i - 179; src = 170 + (j < 6000 ? j : j - 6000); }
  const float* s = h0 + ((long long)b * N0 + src) * D_;
  dst[t] = s[t]; dst[t + 256] = s[t + 256];
}

__global__ __launch_bounds__(256) void cvt_pad_x(const float* x, __hip_bfloat16* Xb){
  int row = blockIdx.x, t = threadIdx.x;
  __hip_bfloat16* o = Xb + (long long)row * 768;
  if (row >= B_*N0){ o[t] = __float2bfloat16(0.f); o[t+256] = __float2bfloat16(0.f); o[t+512] = __float2bfloat16(0.f); return; }
  const float* s = x + (long long)row * 768;
  o[t]     = __float2bfloat16(s[t]);
  o[t+256] = __float2bfloat16(s[t+256]);
  o[t+512] = __float2bfloat16(s[t+512]);
}

__global__ __launch_bounds__(256) void tr_cvt(const void* in, int inbf, int ldin,
    long long iSO, long long iSI, int iIn, __hip_bfloat16* outp, long long oSO,
    int R, int C){
  __shared__ float sm[32][33];
  int z = blockIdx.z;
  long long ib = (long long)(z/iIn)*iSO + (long long)(z%iIn)*iSI;
  int r0 = blockIdx.y*32, c0 = blockIdx.x*32;
  int tx = threadIdx.x & 31, ty = threadIdx.x >> 5;
  for (int rr = ty; rr < 32; rr += 8)
    sm[rr][tx] = gload(in, inbf, ib + (long long)(r0+rr)*ldin + c0 + tx);
  __syncthreads();
  for (int cc = ty; cc < 32; cc += 8)
    outp[z*oSO + (long long)(c0+cc)*R + r0 + tx] = __float2bfloat16(sm[tx][cc]);
}

__global__ __launch_bounds__(256) void landmarks2(const __hip_bfloat16* QKV,
                                                  __hip_bfloat16* QL, __hip_bfloat16* KL){
  int j = blockIdx.x, b = blockIdx.y, t = threadIdx.x;
  const __hip_bfloat16* base = QKV + ((long long)b * NPAD + j*25) * 1536;
  float q0 = 0.f, q1 = 0.f, k0 = 0.f, k1 = 0.f;
  #pragma unroll 5
  for (int i = 0; i < 25; i++){
    const __hip_bfloat16* row = base + (long long)i*1536;
    q0 += __bfloat162float(row[t]);
    q1 += __bfloat162float(row[t + 256]);
    k0 += __bfloat162float(row[512 + t]);
    k1 += __bfloat162float(row[512 + t + 256]);
  }
  int h0 = t >> 6, d0 = t & 63;
  int h1 = (t + 256) >> 6, d1 = (t + 256) & 63;
  QL[((long long)(b*8 + h0) * NLM + j) * 64 + d0] = __float2bfloat16(q0 * 0.005f);
  QL[((long long)(b*8 + h1) * NLM + j) * 64 + d1] = __float2bfloat16(q1 * 0.005f);
  KL[((long long)(b*8 + h0) * NLM + j) * 64 + d0] = __float2bfloat16(k0 * 0.04f);
  KL[((long long)(b*8 + h1) * NLM + j) * 64 + d1] = __float2bfloat16(k1 * 0.04f);
}

__global__ void init_sc(float* sc){ sc[0] = 0.f; sc[1] = 0.f; }

__global__ __launch_bounds__(256) void colsum_max(const float* A2, float* sc){
  int z = blockIdx.x, t = threadIdx.x;
  const float* a = A2 + (long long)z * 65536;
  float s = 0.f;
  for (int i = 0; i < 256; i++) s += fabsf(a[i*256 + t]);
  __shared__ float red[256];
  red[t] = s; __syncthreads();
  for (int st = 128; st; st >>= 1){ if (t < st) red[t] = fmaxf(red[t], red[t+st]); __syncthreads(); }
  if (t == 0) atomicMaxF(sc + 0, red[0]);
}

__global__ __launch_bounds__(256) void rowsum_max(const float* A2, float* sc){
  int z = blockIdx.x, t = threadIdx.x, w = t >> 6, l = t & 63;
  const float* a = A2 + (long long)z * 65536;
  float mx = 0.f;
  for (int i = w*64; i < (w+1)*64; i++){
    float s = fabsf(a[i*256 + l]) + fabsf(a[i*256 + l + 64])
            + fabsf(a[i*256 + l + 128]) + fabsf(a[i*256 + l + 192]);
    for (int m = 32; m; m >>= 1) s += __shfl_xor(s, m);
    mx = fmaxf(mx, s);
  }
  __shared__ float red[4];
  if (l == 0) red[w] = mx;
  __syncthreads();
  if (t == 0) atomicMaxF(sc + 1, fmaxf(fmaxf(red[0], red[1]), fmaxf(red[2], red[3])));
}

__global__ __launch_bounds__(256) void zinit_split(const float* A2,
    __hip_bfloat16* ZN, __hip_bfloat16* ZT, long long PS, const float* sc){
  int j = blockIdx.x, z = blockIdx.y, i = threadIdx.x;
  float inv = 1.f / (sc[0] * sc[1]);
  float v = A2[(long long)z*65536 + i*256 + j] * inv;
  __hip_bfloat16 hi = __float2bfloat16(v);
  __hip_bfloat16 lo = __float2bfloat16(v - __bfloat162float(hi));
  long long zo = (long long)z*65536;
  ZN[zo + j*256 + i] = hi; ZN[PS + zo + j*256 + i] = lo;
  ZT[zo + i*256 + j] = hi; ZT[PS + zo + i*256 + j] = lo;
}

__global__ __launch_bounds__(256) void dwconv_cvt2(const __hip_bfloat16* QKV, const float* rw,
                                                   const float* OUT1, __hip_bfloat16* OUT1b){
  int t = threadIdx.x;
  int n = blockIdx.x*4 + (t >> 6);
  int b = blockIdx.y;
  int ch0 = (t & 63) * 8;
  int h = (t & 63) >> 3;
  float w[33];
  #pragma unroll
  for (int k = 0; k < 33; k++) w[k] = rw[h*33 + k];
  float acc[8] = {};
  const __hip_bfloat16* Vb = QKV + (long long)b * NPAD * 1536 + 1024 + ch0;
  #pragma unroll
  for (int k = 0; k < 33; k++){
    int nn = n + k - 16;
    if (nn < 0 || nn >= NPAD) continue;
    short8_t v8 = *(const short8_t*)(Vb + (long long)nn * 1536);
    #pragma unroll
    for (int j = 0; j < 8; j++) acc[j] += w[k] * b2f((ushort)v8[j]);
  }
  long long idx = ((long long)b * NPAD + n) * D_ + ch0;
  float4 o0 = *(const float4*)(OUT1 + idx);
  float4 o1 = *(const float4*)(OUT1 + idx + 4);
  short8_t o;
  o[0] = (short)f2b(o0.x + acc[0]); o[1] = (short)f2b(o0.y + acc[1]);
  o[2] = (short)f2b(o0.z + acc[2]); o[3] = (short)f2b(o0.w + acc[3]);
  o[4] = (short)f2b(o1.x + acc[4]); o[5] = (short)f2b(o1.y + acc[5]);
  o[6] = (short)f2b(o1.z + acc[6]); o[7] = (short)f2b(o1.w + acc[7]);
  *(short8_t*)((ushort*)OUT1b + idx) = o;
}

__global__ __launch_bounds__(512) void resid_add(float* H, const float* O2, const float* ob){
  int i = blockIdx.x, b = blockIdx.y, t = threadIdx.x;
  H[((long long)b * NTOK + i) * D_ + t] +=
      O2[((long long)b * NPAD + i + PADF) * D_ + t] + ob[t];
}

// ------------------- PPEG: LDS weights + float4 staging -------------------
__global__ __launch_bounds__(256) void transpose_w(const float* w, float* wt, int KK){
  int i = blockIdx.x*256 + threadIdx.x;
  if (i < 512*KK){ int ch = i / KK, k = i - ch*KK; wt[(long long)k*512 + ch] = w[i]; }
}

__global__ __launch_bounds__(256) void ppeg_tiled(const float* H, float* P,
    const float* t7, const float* t5, const float* t3,
    const float* b7, const float* b5, const float* b3,
    int base, int W, int tilesX){
  __shared__ float smem[196*32];   // 24.5 KB patch
  __shared__ float wsm[83*32 + 32];// 10.5 KB weights + bias-sum
  int ty0 = (blockIdx.x / tilesX) * 8, tx0 = (blockIdx.x % tilesX) * 8;
  int c0 = blockIdx.y * 32, b = blockIdx.z;
  int t = threadIdx.x, ch = t & 31, y = t >> 5;
  int cc = c0 + ch;
  // cooperative weight load (per block)
  for (int i = t; i < 83*32; i += 256){
    int k = i >> 5, c = c0 + (i & 31);
    float w;
    if (k < 49)      w = t7[k*512 + c];
    else if (k < 74) w = t5[(k-49)*512 + c];
    else             w = t3[(k-74)*512 + c];
    wsm[i] = w;
  }
  if (t < 32) wsm[83*32 + t] = b7[c0+t] + b5[c0+t] + b3[c0+t];
  // patch staging (float4 per thread-iter)
  {
    const float* Hb = H + ((long long)b * NTOK + base) * D_ + c0;
    for (int q = t; q < 1568; q += 256){
      int pos = q >> 3, c4 = (q & 7) * 4;
      int py = pos / 14, px = pos - py*14;
      int yy = ty0 + py - 3, xx = tx0 + px - 3;
      float4 v = make_float4(0.f, 0.f, 0.f, 0.f);
      if (yy >= 0 && yy < W && xx >= 0 && xx < W)
        v = *(const float4*)(Hb + (long long)(yy*W + xx)*D_ + c4);
      *(float4*)&smem[pos*32 + c4] = v;
    }
  }
  __syncthreads();
  float acc[8];
  float bsum = wsm[83*32 + ch];
  #pragma unroll
  for (int x = 0; x < 8; x++) acc[x] = bsum;
  #pragma unroll
  for (int r = 0; r < 7; r++){
    float v[14];
    #pragma unroll
    for (int xx = 0; xx < 14; xx++) v[xx] = smem[((y + r)*14 + xx)*32 + ch];
    #pragma unroll
    for (int kx = 0; kx < 7; kx++){
      float w = wsm[(r*7 + kx)*32 + ch];
      #pragma unroll
      for (int x = 0; x < 8; x++) acc[x] += w * v[x + kx];
    }
    if (r >= 1 && r <= 5){
      #pragma unroll
      for (int kx = 0; kx < 5; kx++){
        float w = wsm[(49 + (r-1)*5 + kx)*32 + ch];
        #pragma unroll
        for (int x = 0; x < 8; x++) acc[x] += w * v[x + kx + 1];
      }
    }
    if (r >= 2 && r <= 4){
      #pragma unroll
      for (int kx = 0; kx < 3; kx++){
        float w = wsm[(74 + (r-2)*3 + kx)*32 + ch];
        #pragma unroll
        for (int x = 0; x < 8; x++) acc[x] += w * v[x + kx + 2];
      }
    }
    if (r == 3){
      #pragma unroll
      for (int x = 0; x < 8; x++) acc[x] += v[x + 3];
    }
  }
  int gy = ty0 + y;
  if (gy < W){
    #pragma unroll
    for (int x = 0; x < 8; x++){
      int gx = tx0 + x;
      if (gx < W)
        P[((long long)b * W * W + gy*W + gx) * D_ + cc] = acc[x];
    }
  }
}

__global__ __launch_bounds__(512) void ppeg_copy(float* H, const float* P, int base, int W){
  int pos = blockIdx.x, b = blockIdx.y, t = threadIdx.x;
  H[((long long)b * NTOK + base + pos) * D_ + t] = P[((long long)b * W * W + pos) * D_ + t];
}

// ============================== host side =================================
static void gemmB(hipStream_t st, int BN,
                  const __hip_bfloat16* A, int lda, long long aSO, long long aSI, int aIn,
                  const __hip_bfloat16* Bm, int ldb, long long bSO, long long bSI, int bIn,
                  void* C, int ldc, long long cSO, long long cSI, int cIn, int cbf,
                  int M, int N, int K, int batch,
                  const float* bias, float beta, int relu, int ksp = 1, int klen = 0){
  GB p;
  p.A = A; p.Bm = Bm; p.C = C; p.bias = bias;
  p.M = M; p.N = N; p.K = K; p.lda = lda; p.ldb = ldb; p.ldc = ldc;
  p.aSO = aSO; p.aSI = aSI; p.aIn = aIn;
  p.bSO = bSO; p.bSI = bSI; p.bIn = bIn;
  p.cSO = cSO; p.cSI = cSI; p.cIn = cIn; p.cbf = cbf;
  p.beta = beta; p.relu = relu; p.ksp = ksp; p.klen = (klen > 0) ? klen : K;
  dim3 g(N/BN, (M + 127)/128, batch * ksp), b(256);
  if (BN == 128) gemm_bt<128><<<g, b, 0, st>>>(p);
  else           gemm_bt<64><<<g, b, 0, st>>>(p);
}

static void gemmS(hipStream_t st, const ushort* A, const ushort* B,
                  ushort* oN, ushort* oT, float scale, float alphaT, float sT){
  GS p;
  p.A = (const __hip_bfloat16*)A; p.B = (const __hip_bfloat16*)B;
  p.outN = (__hip_bfloat16*)oN; p.outT = (__hip_bfloat16*)oT;
  p.PS = 2097152; p.scale = scale; p.alphaT = alphaT; p.sT = sT;
  dim3 g(4, 4, 32), b(256);
  gemm_bts<<<g, b, 0, st>>>(p);
}

extern "C" void kernel_launch(void* const* d_in, const int* in_sizes, int n_in,
                              void* d_out, int out_size, void* d_ws, size_t ws_size,
                              hipStream_t stream){
  const float* x      = (const float*)d_in[0];
  const float* fc1_w  = (const float*)d_in[1];
  const float* fc1_b  = (const float*)d_in[2];
  const float* cls    = (const float*)d_in[3];
  const float* l1_ng  = (const float*)d_in[4];
  const float* l1_nb  = (const float*)d_in[5];
  const float* l1_qkv = (const float*)d_in[6];
  const float* l1_ow  = (const float*)d_in[7];
  const float* l1_ob  = (const float*)d_in[8];
  const float* l1_rw  = (const float*)d_in[9];
  const float* ct_w7  = (const float*)d_in[10];
  const float* ct_b7  = (const float*)d_in[11];
  const float* ct_w5  = (const float*)d_in[12];
  const float* ct_b5  = (const float*)d_in[13];
  const float* ct_w3  = (const float*)d_in[14];
  const float* ct_b3  = (const float*)d_in[15];
  const float* pt_w7  = (const float*)d_in[16];
  const float* pt_b7  = (const float*)d_in[17];
  const float* pt_w5  = (const float*)d_in[18];
  const float* pt_b5  = (const float*)d_in[19];
  const float* pt_w3  = (const float*)d_in[20];
  const float* pt_b3  = (const float*)d_in[21];
  const float* l2_ng  = (const float*)d_in[22];
  const float* l2_nb  = (const float*)d_in[23];
  const float* l2_qkv = (const float*)d_in[24];
  const float* l2_ow  = (const float*)d_in[25];
  const float* l2_ob  = (const float*)d_in[26];
  const float* l2_rw  = (const float*)d_in[27];
  const float* nrm_g  = (const float*)d_in[28];
  const float* nrm_b  = (const float*)d_in[29];
  float* out = (float*)d_out;

  // ---- workspace layout (float units); SIMC last ----
  float* ws    = (float*)d_ws;
  float* H     = ws;                      // 12,828,672
  float* BUF   = H + 12828672;            // 13,107,200
  float* QKVr  = BUF + 13107200;          // 19,660,800
  float* QLf   = QKVr + 19660800;         //    262,144
  float* KLf   = QLf + 262144;            //    262,144
  float* AV    = KLf + 262144;            //    524,288
  float* AVTf  = AV + 524288;             //    262,144
  float* ZVf   = AVTf + 262144;           //    262,144
  float* ZVTf  = ZVf + 262144;            //    262,144
  float* WQf   = ZVTf + 262144;           //    393,216
  float* WFf   = WQf + 393216;            //    196,608
  float* WOf   = WFf + 196608;            //    131,072
  float* PWT   = WOf + 131072;            //     84,992
  float* SC    = PWT + 84992;             //          8
  float* SIMC  = SC + 8;                  //  rest (pinv planes / AVp / OUT1b)
  float* tc7 = PWT, *tc5 = tc7 + 49*512, *tc3 = tc5 + 25*512;
  float* tp7 = tc3 + 9*512, *tp5 = tp7 + 49*512, *tp3 = tp5 + 25*512;

  // pinv scratch: A2 f32 + hi/lo plane pairs (PS = 2,097,152 bf16 elems)
  float*  A2   = BUF;
  ushort* a2P  = (ushort*)(BUF + 2097152);
  ushort* zn_N = (ushort*)(BUF + 4194304);
  ushort* zn_T = (ushort*)(BUF + 6291456);
  ushort* zc_N = (ushort*)(BUF + 8388608);
  ushort* zc_T = (ushort*)(BUF + 10485760);
  ushort* azP  = (ushort*)SIMC;
  ushort* w1T  = (ushort*)SIMC + 4194304;
  ushort* w2T  = (ushort*)SIMC + 8388608;
  float*  AVp  = SIMC;                    // 2,097,152 f32 (post-pinv)
  float*  MLp  = SIMC + 2097152;          //    65,536 f32

  __hip_bfloat16* Xb    = (__hip_bfloat16*)QKVr;
  __hip_bfloat16* QKV   = (__hip_bfloat16*)QKVr;
  float*          PROJ  = QKVr;
  __hip_bfloat16* XLNb  = (__hip_bfloat16*)BUF;
  __hip_bfloat16* VT    = (__hip_bfloat16*)BUF;         // [32][64][6400]
  __hip_bfloat16* OUT1b = (__hip_bfloat16*)SIMC;
  __hip_bfloat16* QLb   = (__hip_bfloat16*)QLf;
  __hip_bfloat16* KLb   = (__hip_bfloat16*)KLf;
  __hip_bfloat16* AVT   = (__hip_bfloat16*)AVTf;
  __hip_bfloat16* Zvb   = (__hip_bfloat16*)ZVf;
  __hip_bfloat16* ZVT   = (__hip_bfloat16*)ZVTf;
  __hip_bfloat16* WqkvT = (__hip_bfloat16*)WQf;
  __hip_bfloat16* Wfc1T = (__hip_bfloat16*)WFf;
  __hip_bfloat16* WoutT = (__hip_bfloat16*)WOf;

  // ---- one-time weight prep
  transpose_w<<<(512*49+255)/256, 256, 0, stream>>>(ct_w7, tc7, 49);
  transpose_w<<<(512*25+255)/256, 256, 0, stream>>>(ct_w5, tc5, 25);
  transpose_w<<<(512* 9+255)/256, 256, 0, stream>>>(ct_w3, tc3,  9);
  transpose_w<<<(512*49+255)/256, 256, 0, stream>>>(pt_w7, tp7, 49);
  transpose_w<<<(512*25+255)/256, 256, 0, stream>>>(pt_w5, tp5, 25);
  transpose_w<<<(512* 9+255)/256, 256, 0, stream>>>(pt_w3, tp3,  9);
  tr_cvt<<<dim3(512/32, 768/32, 1), 256, 0, stream>>>(fc1_w, 0, 512, 0,0,1, Wfc1T, 0, 768, 512);

  // ---- fc1 + relu -> h0 (BUF f32); gather into H
  cvt_pad_x<<<MFC1, 256, 0, stream>>>(x, Xb);
  gemmB(stream, 128, Xb, 768, 0,0,1, Wfc1T, 768, 0,0,1, BUF, 512, 0,0,1,0,
        MFC1, 512, 768, 1, fc1_b, 1.f, 1);
  build_h<<<dim3(NTOK, B_), 256, 0, stream>>>(BUF, cls, H);

  auto attn_layer = [&](const float* ng, const float* nb, const float* qkvw,
                        const float* outw, const float* outb, const float* resw){
    tr_cvt<<<dim3(1536/32, 512/32, 1), 256, 0, stream>>>(qkvw, 0, 1536, 0,0,1, WqkvT, 0, 512, 1536);
    tr_cvt<<<dim3(512/32, 512/32, 1), 256, 0, stream>>>(outw, 0, 512, 0,0,1, WoutT, 0, 512, 512);
    ln_pad<<<dim3(NPAD, B_), 256, 0, stream>>>(H, XLNb, ng, nb);
    gemmB(stream, 128, XLNb, 512, 0,0,1, WqkvT, 512, 0,0,1, QKV, 1536, 0,0,1,1,
          B_*NPAD, 1536, 512, 1, nullptr, 1.f, 0);
    landmarks2<<<dim3(NLM, B_), 256, 0, stream>>>(QKV, QLb, KLb);
    // a2 = softmax(q_l @ k_l^T): f32 + hi/lo planes
    gemmB(stream, 128, QLb, 64, 16384,0,1, KLb, 64, 16384,0,1, A2, 256, 65536,0,1,0,
          256, 256, 64, 32, nullptr, 1.f, 0);
    softmax256_split<<<B_*NH*NLM, 256, 0, stream>>>(A2, (__hip_bfloat16*)a2P, 2097152);
    // pinv (Newton-Schulz, 6 iters)
    init_sc<<<1, 1, 0, stream>>>(SC);
    colsum_max<<<B_*NH, 256, 0, stream>>>(A2, SC);
    rowsum_max<<<B_*NH, 256, 0, stream>>>(A2, SC);
    zinit_split<<<dim3(256, 32), 256, 0, stream>>>(A2, (__hip_bfloat16*)zc_N,
          (__hip_bfloat16*)zc_T, 2097152, SC);
    ushort *cN = zc_N, *cT = zc_T, *nN = zn_N, *nT = zn_T;
    for (int it = 0; it < 6; it++){
      gemmS(stream, a2P, cT, azP, w1T, 1.f, 7.f, -1.f);
      gemmS(stream, azP, w1T, nullptr, w2T, 1.f, 15.f, -1.f);
      gemmS(stream, azP, w2T, nullptr, w1T, 1.f, 13.f, -1.f);
      gemmS(stream, cN, w1T, nN, nT, 0.25f, 0.f, 1.f);
      ushort* s;
      s = cN; cN = nN; nN = s;
      s = cT; cT = nT; nT = s;
    }
    const __hip_bfloat16* Zcb = (const __hip_bfloat16*)cN;
    // V^T per head into BUF (pinv scratch dead except final Z planes at zc_*)
    tr_cvt<<<dim3(64/32, NPAD/32, 32), 256, 0, stream>>>(QKV + 1024, 1, 1536,
          QE, 64, 8, VT, (long long)64*NPAD, NPAD, 64);
    // fused sim3 (flash-style, 4-way key split) + merge
    sim3_fused<<<dim3(4, 32, 4), 256, 0, stream>>>(QKV, QLb, VT, AVp, MLp);
    av_merge<<<2048, 256, 0, stream>>>(AVp, MLp, AV);
    // AV^T, ZV = Zc@AV (bf16 out), ZV^T
    tr_cvt<<<dim3(64/32, 256/32, 32), 256, 0, stream>>>(AV, 0, 64, 16384,0,1,
          AVT, 16384, 256, 64);
    gemmB(stream, 64, Zcb, 256, 65536,0,1, AVT, 256, 16384,0,1,
          Zvb, 64, 16384,0,1,1, 256, 64, 256, 32, nullptr, 1.f, 0);
    tr_cvt<<<dim3(64/32, 256/32, 32), 256, 0, stream>>>(Zvb, 1, 64, 16384,0,1,
          ZVT, 16384, 256, 64);
    // fused sim1: OUT1 f32 into BUF
    sim1_fused<<<dim3(NPAD/64, 32), 256, 0, stream>>>(QKV, KLb, ZVT, BUF);
    // + depthwise conv residual -> bf16, projection, residual add
    dwconv_cvt2<<<dim3(NPAD/4, B_), 256, 0, stream>>>(QKV, resw, BUF, OUT1b);
    gemmB(stream, 128, OUT1b, 512, 0,0,1, WoutT, 512, 0,0,1, PROJ, 512, 0,0,1,0,
          B_*NPAD, 512, 512, 1, nullptr, 1.f, 0);
    resid_add<<<dim3(NTOK, B_), 512, 0, stream>>>(H, PROJ, outb);
  };

  // ---- layer 1
  attn_layer(l1_ng, l1_nb, l1_qkv, l1_ow, l1_ob, l1_rw);

  // ---- PPEG
  ppeg_tiled<<<dim3(4, 16, B_), 256, 0, stream>>>(H, BUF, tc7, tc5, tc3, ct_b7, ct_b5, ct_b3, 11, 13, 2);
  ppeg_copy<<<dim3(169, B_), 512, 0, stream>>>(H, BUF, 11, 13);
  ppeg_tiled<<<dim3(100, 16, B_), 256, 0, stream>>>(H, BUF, tp7, tp5, tp3, pt_b7, pt_b5, pt_b3, 180, 78, 10);
  ppeg_copy<<<dim3(6084, B_), 512, 0, stream>>>(H, BUF, 180, 78);

  // ---- layer 2
  attn_layer(l2_ng, l2_nb, l2_qkv, l2_ow, l2_ob, l2_rw);

  // ---- final LN on cls token
  final_ln<<<B_, 256, 0, stream>>>(H, nrm_g, nrm_b, out);
}